// Round 2
// baseline (929.200 us; speedup 1.0000x reference)
//
#include <hip/hip_runtime.h>
#include <hip/hip_bf16.h>
#include <cstddef>

// Problem constants
#define N_NODES 4096
#define DIM     128
#define NHEAD   2
#define DHEAD   64
#define FFDIM   256
#define NEDGE   2048
#define NNZ_E   65536

// ---------------------------------------------------------------------------
// Normalize edge indices to int32, auto-detecting int64 vs int32 source.
// int64 layout (little-endian, values < 2^31): every odd 32-bit word is 0.
__global__ void edge_norm_kernel(const int* __restrict__ edge_raw,
                                 int* __restrict__ nidx, int* __restrict__ hidx) {
    __shared__ int is64_s;
    if (threadIdx.x == 0) {
        int bad = 0;
        for (int j = 0; j < 64; ++j) bad |= edge_raw[2 * j + 1];
        is64_s = (bad == 0) ? 1 : 0;
    }
    __syncthreads();
    const int is64 = is64_s;
    int i = blockIdx.x * 256 + threadIdx.x;
    if (i < NNZ_E) {
        if (is64) {
            nidx[i] = edge_raw[2 * i];
            hidx[i] = edge_raw[2 * NNZ_E + 2 * i];
        } else {
            nidx[i] = edge_raw[i];
            hidx[i] = edge_raw[NNZ_E + i];
        }
    }
}

// ---------------------------------------------------------------------------
// C[M,NC] = act(A[M,K] @ W[K,NC] + bias)   (all fp32)
// ACT: 0=none, 1=sigmoid.  SPLIT=1: write C in [head][M][64] layout (head=col/64).
template<int K, int NC, int ACT, int SPLIT>
__global__ __launch_bounds__(NC) void gemm_k(const float* __restrict__ A,
                                             const float* __restrict__ W,
                                             const float* __restrict__ bias,
                                             float* __restrict__ C, int M) {
    __shared__ __align__(16) float a_s[16][K];
    const int row0 = blockIdx.x * 16;
    const int tid  = threadIdx.x;
    for (int i = tid; i < 16 * (K / 4); i += NC) {
        int r = i / (K / 4), c4 = i % (K / 4);
        ((float4*)a_s[r])[c4] = ((const float4*)(A + (size_t)(row0 + r) * K))[c4];
    }
    __syncthreads();
    const int col = tid;
    float bv = bias ? bias[col] : 0.f;
    float acc[16];
#pragma unroll
    for (int r = 0; r < 16; ++r) acc[r] = bv;
    for (int kk = 0; kk < K; kk += 4) {
        float w0 = W[(kk + 0) * NC + col];
        float w1 = W[(kk + 1) * NC + col];
        float w2 = W[(kk + 2) * NC + col];
        float w3 = W[(kk + 3) * NC + col];
#pragma unroll
        for (int r = 0; r < 16; ++r) {
            float4 a4 = ((const float4*)a_s[r])[kk / 4]; // broadcast read: conflict-free
            acc[r] = fmaf(a4.x, w0, fmaf(a4.y, w1, fmaf(a4.z, w2, fmaf(a4.w, w3, acc[r]))));
        }
    }
#pragma unroll
    for (int r = 0; r < 16; ++r) {
        float v = acc[r];
        if (ACT == 1) v = 1.f / (1.f + __expf(-v));
        if (SPLIT) {
            int hh = col >> 6, d = col & 63;
            C[((size_t)hh * M + row0 + r) * 64 + d] = v;
        } else {
            C[(size_t)(row0 + r) * NC + col] = v;
        }
    }
}

// ---------------------------------------------------------------------------
// Flash-style attention, fp32.  q/k/v in [H][N][64] layout, o in [N][128].
// Block: 256 threads, BM=16 query rows, iterate 64-key tiles with online softmax.
// Thread (r = tid>>4, g = tid&15): 4 scores (c = j*16+g) and 4 output dims (d = g*4+jj).
__global__ __launch_bounds__(256) void attn_kernel(const float* __restrict__ qg_,
                                                   const float* __restrict__ kg_,
                                                   const float* __restrict__ vg_,
                                                   float* __restrict__ og_) {
    __shared__ __align__(16) float k_s[64][68];   // +4 pad: conflict-free b128
    __shared__ __align__(16) float v_s[64][68];
    __shared__ __align__(16) float q_s[16][68];
    __shared__ __align__(16) float p_s[16][68];
    const int hidx = blockIdx.y;
    const int row0 = blockIdx.x * 16;
    const int tid  = threadIdx.x;
    const int r = tid >> 4, g = tid & 15;

    const float* qg = qg_ + ((size_t)hidx * N_NODES + row0) * 64;
    const float* kg = kg_ + (size_t)hidx * N_NODES * 64;
    const float* vg = vg_ + (size_t)hidx * N_NODES * 64;

    { // stage Q tile: 16x64 floats = 256 float4, one per thread
        int rr = tid >> 4, c4 = tid & 15;
        ((float4*)&q_s[rr][0])[c4] = ((const float4*)(qg + rr * 64))[c4];
    }

    float m = -INFINITY, l = 0.f;
    float o0 = 0.f, o1 = 0.f, o2 = 0.f, o3 = 0.f;

    for (int kt = 0; kt < N_NODES / 64; ++kt) {
        const float4* ksrc = (const float4*)(kg + kt * 64 * 64);
        const float4* vsrc = (const float4*)(vg + kt * 64 * 64);
#pragma unroll
        for (int it = 0; it < 4; ++it) {
            int i = tid + it * 256;            // 0..1023
            int rr = i >> 4, c4 = i & 15;
            ((float4*)&k_s[rr][0])[c4] = ksrc[i];
            ((float4*)&v_s[rr][0])[c4] = vsrc[i];
        }
        __syncthreads();

        // scores: 4 per thread
        float sj[4] = {0.f, 0.f, 0.f, 0.f};
        const float4* qrow = (const float4*)&q_s[r][0];
#pragma unroll 8
        for (int kk = 0; kk < 16; ++kk) {
            float4 qv = qrow[kk];
#pragma unroll
            for (int j = 0; j < 4; ++j) {
                float4 kv = ((const float4*)&k_s[j * 16 + g][0])[kk];
                sj[j] = fmaf(qv.x, kv.x, fmaf(qv.y, kv.y, fmaf(qv.z, kv.z, fmaf(qv.w, kv.w, sj[j]))));
            }
        }
#pragma unroll
        for (int j = 0; j < 4; ++j) sj[j] *= 0.125f;  // 1/sqrt(64)

        // online softmax over the 16 lanes owning row r (xor of bits 0..3 stays in row)
        float lm = fmaxf(fmaxf(sj[0], sj[1]), fmaxf(sj[2], sj[3]));
        for (int msk = 1; msk < 16; msk <<= 1) lm = fmaxf(lm, __shfl_xor(lm, msk));
        float mn = fmaxf(m, lm);
        float alpha = __expf(m - mn);          // exp(-inf)=0 on first tile
        float ps = 0.f;
#pragma unroll
        for (int j = 0; j < 4; ++j) {
            float p = __expf(sj[j] - mn);
            ps += p;
            p_s[r][j * 16 + g] = p;
        }
        for (int msk = 1; msk < 16; msk <<= 1) ps += __shfl_xor(ps, msk);
        l = l * alpha + ps;
        m = mn;
        o0 *= alpha; o1 *= alpha; o2 *= alpha; o3 *= alpha;
        __syncthreads();   // p_s visible before PV (also orders vs staging)

        // PV: o[d] += sum_c P[r][c] * V[c][d],  d = g*4 + jj
#pragma unroll 8
        for (int c = 0; c < 64; ++c) {
            float pv = p_s[r][c];
            float4 v4 = *(const float4*)&v_s[c][g * 4];
            o0 = fmaf(pv, v4.x, o0);
            o1 = fmaf(pv, v4.y, o1);
            o2 = fmaf(pv, v4.z, o2);
            o3 = fmaf(pv, v4.w, o3);
        }
        __syncthreads();   // before next tile overwrites k_s/v_s
    }
    float linv = 1.f / l;
    float4 res = make_float4(o0 * linv, o1 * linv, o2 * linv, o3 * linv);
    *(float4*)(og_ + (size_t)(row0 + r) * 128 + hidx * 64 + g * 4) = res;
}

// ---------------------------------------------------------------------------
// h = LayerNorm(h + res) * g + b     (rows of 128, one wave per row)
__global__ __launch_bounds__(256) void ln_res_kernel(float* __restrict__ h,
                                                     const float* __restrict__ res,
                                                     const float* __restrict__ g,
                                                     const float* __restrict__ b) {
    int wave = threadIdx.x >> 6, lane = threadIdx.x & 63;
    int row = blockIdx.x * 4 + wave;
    size_t base = (size_t)row * 128;
    float x0 = h[base + lane]      + res[base + lane];
    float x1 = h[base + 64 + lane] + res[base + 64 + lane];
    float s  = x0 + x1;
    float sq = x0 * x0 + x1 * x1;
    for (int msk = 32; msk; msk >>= 1) { s += __shfl_xor(s, msk); sq += __shfl_xor(sq, msk); }
    float mean = s * (1.f / 128.f);
    float var  = sq * (1.f / 128.f) - mean * mean;
    float rstd = rsqrtf(var + 1e-5f);
    h[base + lane]      = (x0 - mean) * rstd * g[lane]      + b[lane];
    h[base + 64 + lane] = (x1 - mean) * rstd * g[lane + 64] + b[lane + 64];
}

// ---------------------------------------------------------------------------
// Hypergraph conv pieces
__global__ void count_kernel(const int* __restrict__ nidx, const int* __restrict__ hidx,
                             float* __restrict__ bdeg, float* __restrict__ ddeg) {
    int i = blockIdx.x * 256 + threadIdx.x;
    if (i < NNZ_E) {
        atomicAdd(&ddeg[nidx[i]], 1.f);   // node degree
        atomicAdd(&bdeg[hidx[i]], 1.f);   // hyperedge degree
    }
}

__global__ void scatter1_kernel(const int* __restrict__ nidx, const int* __restrict__ hidx,
                                const float* __restrict__ xt, float* __restrict__ e) {
    int idx = blockIdx.x * 256 + threadIdx.x;    // NNZ*128 total
    int i = idx >> 7, d = idx & 127;
    atomicAdd(&e[(size_t)hidx[i] * 128 + d], xt[(size_t)nidx[i] * 128 + d]);
}

__global__ void scatter2_kernel(const int* __restrict__ nidx, const int* __restrict__ hidx,
                                const float* __restrict__ e, const float* __restrict__ bdeg,
                                float* __restrict__ oacc) {
    int idx = blockIdx.x * 256 + threadIdx.x;
    int i = idx >> 7, d = idx & 127;
    int he = hidx[i];
    float deg = bdeg[he];
    float binv = deg > 0.f ? 1.f / deg : 0.f;
    atomicAdd(&oacc[(size_t)nidx[i] * 128 + d], e[(size_t)he * 128 + d] * binv);
}

__global__ void finalize_kernel(const float* __restrict__ oacc, const float* __restrict__ ddeg,
                                const float* __restrict__ bh, float* __restrict__ out) {
    int idx = blockIdx.x * 256 + threadIdx.x;    // N*128 total
    int n = idx >> 7, d = idx & 127;
    float deg = ddeg[n];
    float dinv = deg > 0.f ? 1.f / deg : 0.f;
    float v = oacc[idx] * dinv + bh[d];
    out[idx] = v > 0.f ? v : 0.f;
}

// ---------------------------------------------------------------------------
extern "C" void kernel_launch(void* const* d_in, const int* in_sizes, int n_in,
                              void* d_out, int out_size, void* d_ws, size_t ws_size,
                              hipStream_t stream) {
    (void)in_sizes; (void)n_in; (void)out_size; (void)ws_size;
    const float* x    = (const float*)d_in[0];
    const int*   edge = (const int*)  d_in[1];
    const float* Wq = (const float*)d_in[2];  const float* bq  = (const float*)d_in[3];
    const float* Wk = (const float*)d_in[4];  const float* bk  = (const float*)d_in[5];
    const float* Wv = (const float*)d_in[6];  const float* bv  = (const float*)d_in[7];
    const float* Wo = (const float*)d_in[8];  const float* bo  = (const float*)d_in[9];
    const float* g1 = (const float*)d_in[10]; const float* b1  = (const float*)d_in[11];
    const float* W1 = (const float*)d_in[12]; const float* bf1 = (const float*)d_in[13];
    const float* W2 = (const float*)d_in[14]; const float* bf2 = (const float*)d_in[15];
    const float* g2 = (const float*)d_in[16]; const float* b2  = (const float*)d_in[17];
    const float* Wh = (const float*)d_in[18]; const float* bh  = (const float*)d_in[19];
    float* out = (float*)d_out;

    float* B = (float*)d_ws;
    float* h = B;                       // [N,128]   524288
    float* q = B + 524288;              // [H,N,64]  524288
    float* k = B + 1048576;             // [H,N,64]  524288
    float* v = B + 1572864;             // [H,N,64]  524288
    float* o = B + 2097152;             // [N,128]   524288
    float* t = q;                       // [N,256] aliases q+k (dead when t is live)
    // hypergraph-stage reuse (transformer buffers dead by then)
    float* xt   = q;                    // [N,128]
    float* e    = v;                    // [NE,128] = 262144
    float* oacc = o;                    // [N,128]
    float* bdeg = k;                    // [NE]
    float* ddeg = k + NEDGE;            // [N]
    int*   nidx = (int*)(B + 2621440);  // [NNZ]
    int*   hidx = nidx + NNZ_E;         // [NNZ]
    // peak ws use: (2621440 + 131072) * 4 B ≈ 10.5 MB

    hipMemcpyAsync(h, x, (size_t)N_NODES * DIM * sizeof(float),
                   hipMemcpyDeviceToDevice, stream);
    edge_norm_kernel<<<NNZ_E / 256, 256, 0, stream>>>(edge, nidx, hidx);

    for (int layer = 0; layer < 2; ++layer) {
        gemm_k<128, 128, 0, 1><<<256, 128, 0, stream>>>(h, Wq, bq, q, N_NODES);
        gemm_k<128, 128, 0, 1><<<256, 128, 0, stream>>>(h, Wk, bk, k, N_NODES);
        gemm_k<128, 128, 0, 1><<<256, 128, 0, stream>>>(h, Wv, bv, v, N_NODES);
        attn_kernel<<<dim3(N_NODES / 16, NHEAD), 256, 0, stream>>>(q, k, v, o);
        gemm_k<128, 128, 0, 0><<<256, 128, 0, stream>>>(o, Wo, bo, t, N_NODES);
        ln_res_kernel<<<1024, 256, 0, stream>>>(h, t, g1, b1);
        gemm_k<128, 256, 1, 0><<<256, 256, 0, stream>>>(h, W1, bf1, t, N_NODES);
        gemm_k<256, 128, 0, 0><<<256, 128, 0, stream>>>(t, W2, bf2, o, N_NODES);
        ln_res_kernel<<<1024, 256, 0, stream>>>(h, o, g2, b2);
    }

    gemm_k<128, 128, 0, 0><<<256, 128, 0, stream>>>(h, Wh, nullptr, xt, N_NODES);
    hipMemsetAsync(bdeg, 0, (NEDGE + N_NODES) * sizeof(float), stream);
    hipMemsetAsync(e, 0, (size_t)NEDGE * DIM * sizeof(float), stream);
    hipMemsetAsync(oacc, 0, (size_t)N_NODES * DIM * sizeof(float), stream);
    count_kernel<<<NNZ_E / 256, 256, 0, stream>>>(nidx, hidx, bdeg, ddeg);
    scatter1_kernel<<<NNZ_E * DIM / 256, 256, 0, stream>>>(nidx, hidx, xt, e);
    scatter2_kernel<<<NNZ_E * DIM / 256, 256, 0, stream>>>(nidx, hidx, e, bdeg, oacc);
    finalize_kernel<<<N_NODES * DIM / 256, 256, 0, stream>>>(oacc, ddeg, bh, out);
}

// Round 3
// 652.764 us; speedup vs baseline: 1.4235x; 1.4235x over previous
//
#include <hip/hip_runtime.h>
#include <hip/hip_bf16.h>
#include <cstddef>

// Problem constants
#define N_NODES 4096
#define DIM     128
#define NHEAD   2
#define DHEAD   64
#define FFDIM   256
#define NEDGE   2048
#define NNZ_E   65536

typedef __attribute__((ext_vector_type(8))) short bf16x8;   // 8 bf16 in 4 VGPRs
typedef __attribute__((ext_vector_type(4))) float f32x4;

// float -> bf16 bits, round-to-nearest-even
__device__ __forceinline__ unsigned short f2b(float f) {
    unsigned u = __float_as_uint(f);
    return (unsigned short)((u + 0x7FFFu + ((u >> 16) & 1u)) >> 16);
}

// ---------------------------------------------------------------------------
// Normalize edge indices to int32, auto-detecting int64 vs int32 source.
__global__ void edge_norm_kernel(const int* __restrict__ edge_raw,
                                 int* __restrict__ nidx, int* __restrict__ hidx) {
    __shared__ int is64_s;
    if (threadIdx.x == 0) {
        int bad = 0;
        for (int j = 0; j < 64; ++j) bad |= edge_raw[2 * j + 1];
        is64_s = (bad == 0) ? 1 : 0;
    }
    __syncthreads();
    const int is64 = is64_s;
    int i = blockIdx.x * 256 + threadIdx.x;
    if (i < NNZ_E) {
        if (is64) {
            nidx[i] = edge_raw[2 * i];
            hidx[i] = edge_raw[2 * NNZ_E + 2 * i];
        } else {
            nidx[i] = edge_raw[i];
            hidx[i] = edge_raw[NNZ_E + i];
        }
    }
}

// ---------------------------------------------------------------------------
// C[M,NC] = act(A[M,K] @ W[K,NC] + bias)   (A,W fp32)
// ACT: 0=none, 1=sigmoid.  SPLIT=1: [head][M][64] layout.  OBF=1: bf16 output.
template<int K, int NC, int ACT, int SPLIT, int OBF>
__global__ __launch_bounds__(NC) void gemm_k(const float* __restrict__ A,
                                             const float* __restrict__ W,
                                             const float* __restrict__ bias,
                                             void* __restrict__ Cv, int M) {
    __shared__ __align__(16) float a_s[16][K];
    const int row0 = blockIdx.x * 16;
    const int tid  = threadIdx.x;
    for (int i = tid; i < 16 * (K / 4); i += NC) {
        int r = i / (K / 4), c4 = i % (K / 4);
        ((float4*)a_s[r])[c4] = ((const float4*)(A + (size_t)(row0 + r) * K))[c4];
    }
    __syncthreads();
    const int col = tid;
    float bv = bias ? bias[col] : 0.f;
    float acc[16];
#pragma unroll
    for (int r = 0; r < 16; ++r) acc[r] = bv;
    for (int kk = 0; kk < K; kk += 4) {
        float w0 = W[(kk + 0) * NC + col];
        float w1 = W[(kk + 1) * NC + col];
        float w2 = W[(kk + 2) * NC + col];
        float w3 = W[(kk + 3) * NC + col];
#pragma unroll
        for (int r = 0; r < 16; ++r) {
            float4 a4 = ((const float4*)a_s[r])[kk / 4];
            acc[r] = fmaf(a4.x, w0, fmaf(a4.y, w1, fmaf(a4.z, w2, fmaf(a4.w, w3, acc[r]))));
        }
    }
#pragma unroll
    for (int r = 0; r < 16; ++r) {
        float v = acc[r];
        if (ACT == 1) v = 1.f / (1.f + __expf(-v));
        size_t idx;
        if (SPLIT) {
            int hh = col >> 6, d = col & 63;
            idx = ((size_t)hh * M + row0 + r) * 64 + d;
        } else {
            idx = (size_t)(row0 + r) * NC + col;
        }
        if (OBF) ((unsigned short*)Cv)[idx] = f2b(v);
        else     ((float*)Cv)[idx] = v;
    }
}

// ---------------------------------------------------------------------------
// v32 [H][N][64] fp32 -> vtb [H][64][N] bf16 (LDS tile transpose)
__global__ __launch_bounds__(256) void vtrans_kernel(const float* __restrict__ v32,
                                                     unsigned short* __restrict__ vtb) {
    __shared__ float ts[64][65];
    const int h = blockIdx.y, n0 = blockIdx.x * 64;
    const float* src = v32 + ((size_t)h * N_NODES + n0) * 64;
    for (int e = threadIdx.x; e < 4096; e += 256) {
        int r = e >> 6, d = e & 63;
        ts[r][d] = src[r * 64 + d];
    }
    __syncthreads();
    unsigned short* dst = vtb + (size_t)h * 64 * N_NODES + n0;
    for (int e = threadIdx.x; e < 4096; e += 256) {
        int d = e >> 6, n = e & 63;
        dst[(size_t)d * N_NODES + n] = f2b(ts[n][d]);
    }
}

// ---------------------------------------------------------------------------
// MFMA flash attention (bf16 inputs, fp32 softmax/accum).
// qb,kb [H][N][64] bf16; vtb [H][64][N] bf16; og [N][128] fp32.
// Block 256 = 4 waves; wave w owns 16 q rows. K-tiles of 64 keys.
// S^T = K*Q^T so each lane owns ONE query (q = lane&15): scalar m/l/alpha.
#define ROWP 72   // padded LDS row: 144 B = 9*16 B -> aligned b128, 2-way banks
__global__ __launch_bounds__(256) void attn_mfma(const unsigned short* __restrict__ qb,
                                                 const unsigned short* __restrict__ kb,
                                                 const unsigned short* __restrict__ vtb,
                                                 float* __restrict__ og) {
    __shared__ __align__(16) unsigned short k_s[64 * ROWP];
    __shared__ __align__(16) unsigned short vt_s[64 * ROWP];
    __shared__ __align__(16) unsigned short p_s[4][16 * ROWP];
    const int h = blockIdx.y;
    const int row0 = blockIdx.x * 64;
    const int tid = threadIdx.x;
    const int w = tid >> 6, lane = tid & 63;
    const int qi = lane & 15, gi = lane >> 4;
    const float CE = 0.18033688011f;   // 0.125 * log2(e)

    // Q B-frags (B[k][n=q] = Q[q][k]), held in regs for the whole kernel
    const unsigned short* qrow = qb + ((size_t)h * N_NODES + row0 + w * 16 + qi) * 64 + gi * 8;
    bf16x8 qf0 = *(const bf16x8*)qrow;
    bf16x8 qf1 = *(const bf16x8*)(qrow + 32);

    f32x4 oc[4];
#pragma unroll
    for (int i = 0; i < 4; ++i) oc[i] = (f32x4){0.f, 0.f, 0.f, 0.f};
    float m_run = -INFINITY, l_run = 0.f;

    const unsigned short* kbh = kb + (size_t)h * N_NODES * 64;
    const unsigned short* vth = vtb + (size_t)h * 64 * N_NODES;

    for (int kt = 0; kt < N_NODES / 64; ++kt) {
        // stage K[64 keys][64 dh] and V^T[64 dh][64 keys]
        const unsigned short* ksrc = kbh + kt * 64 * 64;
#pragma unroll
        for (int i = 0; i < 2; ++i) {
            int c = tid + i * 256;            // chunk 0..511 (8 ushorts each)
            int r = c >> 3, s = c & 7;
            *(uint4*)&k_s[r * ROWP + s * 8]  = *(const uint4*)(ksrc + c * 8);
            *(uint4*)&vt_s[r * ROWP + s * 8] = *(const uint4*)(vth + (size_t)r * N_NODES + kt * 64 + s * 8);
        }
        __syncthreads();

        // S^T[key][q]: A = K, B = Q^T.  sc[t][r] = S[q=qi][key = t*16 + gi*4 + r]
        f32x4 sc[4];
#pragma unroll
        for (int t = 0; t < 4; ++t) {
            const unsigned short* krow = &k_s[(t * 16 + qi) * ROWP + gi * 8];
            bf16x8 ka0 = *(const bf16x8*)krow;
            bf16x8 ka1 = *(const bf16x8*)(krow + 32);
            f32x4 z = (f32x4){0.f, 0.f, 0.f, 0.f};
            z = __builtin_amdgcn_mfma_f32_16x16x32_bf16(ka0, qf0, z, 0, 0, 0);
            sc[t] = __builtin_amdgcn_mfma_f32_16x16x32_bf16(ka1, qf1, z, 0, 0, 0);
        }

        // online softmax, scalar per lane (one q per lane)
        float smax = -INFINITY;
#pragma unroll
        for (int t = 0; t < 4; ++t) {
            smax = fmaxf(smax, fmaxf(fmaxf(sc[t][0], sc[t][1]), fmaxf(sc[t][2], sc[t][3])));
        }
        smax = fmaxf(smax, __shfl_xor(smax, 16));
        smax = fmaxf(smax, __shfl_xor(smax, 32));
        float mn = fmaxf(m_run, smax);
        float alpha = exp2f((m_run - mn) * CE);
        m_run = mn;
        float nb = mn * CE;
        float psum = 0.f;
#pragma unroll
        for (int t = 0; t < 4; ++t) {
            ushort4 pw;
            float p0 = exp2f(fmaf(sc[t][0], CE, -nb)); psum += p0; pw.x = f2b(p0);
            float p1 = exp2f(fmaf(sc[t][1], CE, -nb)); psum += p1; pw.y = f2b(p1);
            float p2 = exp2f(fmaf(sc[t][2], CE, -nb)); psum += p2; pw.z = f2b(p2);
            float p3 = exp2f(fmaf(sc[t][3], CE, -nb)); psum += p3; pw.w = f2b(p3);
            *(ushort4*)&p_s[w][qi * ROWP + t * 16 + gi * 4] = pw;   // P[q][key]
        }
        psum += __shfl_xor(psum, 16);
        psum += __shfl_xor(psum, 32);
        l_run = l_run * alpha + psum;

        // rescale O by per-row alpha (O rows are q = gi*4+r; alpha lives at lane q)
        float a0 = __shfl(alpha, gi * 4 + 0);
        float a1 = __shfl(alpha, gi * 4 + 1);
        float a2 = __shfl(alpha, gi * 4 + 2);
        float a3 = __shfl(alpha, gi * 4 + 3);
#pragma unroll
        for (int d = 0; d < 4; ++d) {
            oc[d][0] *= a0; oc[d][1] *= a1; oc[d][2] *= a2; oc[d][3] *= a3;
        }

        // PV: A = P (from wave-private LDS, A-layout), B = V (from V^T rows)
        const unsigned short* prow = &p_s[w][qi * ROWP];
        bf16x8 pa0 = *(const bf16x8*)(prow + gi * 8);
        bf16x8 pa1 = *(const bf16x8*)(prow + 32 + gi * 8);
#pragma unroll
        for (int d = 0; d < 4; ++d) {
            const unsigned short* vrow = &vt_s[(d * 16 + qi) * ROWP + gi * 8];
            bf16x8 vb0 = *(const bf16x8*)vrow;
            bf16x8 vb1 = *(const bf16x8*)(vrow + 32);
            oc[d] = __builtin_amdgcn_mfma_f32_16x16x32_bf16(pa0, vb0, oc[d], 0, 0, 0);
            oc[d] = __builtin_amdgcn_mfma_f32_16x16x32_bf16(pa1, vb1, oc[d], 0, 0, 0);
        }
        __syncthreads();   // before restaging k_s/vt_s
    }

    float li = 1.f / l_run;
    float l0 = __shfl(li, gi * 4 + 0);
    float l1 = __shfl(li, gi * 4 + 1);
    float l2 = __shfl(li, gi * 4 + 2);
    float l3 = __shfl(li, gi * 4 + 3);
#pragma unroll
    for (int d = 0; d < 4; ++d) {
        size_t cb = h * 64 + d * 16 + qi;
        og[(size_t)(row0 + w * 16 + gi * 4 + 0) * 128 + cb] = oc[d][0] * l0;
        og[(size_t)(row0 + w * 16 + gi * 4 + 1) * 128 + cb] = oc[d][1] * l1;
        og[(size_t)(row0 + w * 16 + gi * 4 + 2) * 128 + cb] = oc[d][2] * l2;
        og[(size_t)(row0 + w * 16 + gi * 4 + 3) * 128 + cb] = oc[d][3] * l3;
    }
}

// ---------------------------------------------------------------------------
// h = LayerNorm(h + res) * g + b     (rows of 128, one wave per row)
__global__ __launch_bounds__(256) void ln_res_kernel(float* __restrict__ h,
                                                     const float* __restrict__ res,
                                                     const float* __restrict__ g,
                                                     const float* __restrict__ b) {
    int wave = threadIdx.x >> 6, lane = threadIdx.x & 63;
    int row = blockIdx.x * 4 + wave;
    size_t base = (size_t)row * 128;
    float x0 = h[base + lane]      + res[base + lane];
    float x1 = h[base + 64 + lane] + res[base + 64 + lane];
    float s  = x0 + x1;
    float sq = x0 * x0 + x1 * x1;
    for (int msk = 32; msk; msk >>= 1) { s += __shfl_xor(s, msk); sq += __shfl_xor(sq, msk); }
    float mean = s * (1.f / 128.f);
    float var  = sq * (1.f / 128.f) - mean * mean;
    float rstd = rsqrtf(var + 1e-5f);
    h[base + lane]      = (x0 - mean) * rstd * g[lane]      + b[lane];
    h[base + 64 + lane] = (x1 - mean) * rstd * g[lane + 64] + b[lane + 64];
}

// ---------------------------------------------------------------------------
// Hypergraph conv pieces
__global__ void count_kernel(const int* __restrict__ nidx, const int* __restrict__ hidx,
                             float* __restrict__ bdeg, float* __restrict__ ddeg) {
    int i = blockIdx.x * 256 + threadIdx.x;
    if (i < NNZ_E) {
        atomicAdd(&ddeg[nidx[i]], 1.f);
        atomicAdd(&bdeg[hidx[i]], 1.f);
    }
}

__global__ void scatter1_kernel(const int* __restrict__ nidx, const int* __restrict__ hidx,
                                const float* __restrict__ xt, float* __restrict__ e) {
    int idx = blockIdx.x * 256 + threadIdx.x;
    int i = idx >> 7, d = idx & 127;
    atomicAdd(&e[(size_t)hidx[i] * 128 + d], xt[(size_t)nidx[i] * 128 + d]);
}

__global__ void scatter2_kernel(const int* __restrict__ nidx, const int* __restrict__ hidx,
                                const float* __restrict__ e, const float* __restrict__ bdeg,
                                float* __restrict__ oacc) {
    int idx = blockIdx.x * 256 + threadIdx.x;
    int i = idx >> 7, d = idx & 127;
    int he = hidx[i];
    float deg = bdeg[he];
    float binv = deg > 0.f ? 1.f / deg : 0.f;
    atomicAdd(&oacc[(size_t)nidx[i] * 128 + d], e[(size_t)he * 128 + d] * binv);
}

__global__ void finalize_kernel(const float* __restrict__ oacc, const float* __restrict__ ddeg,
                                const float* __restrict__ bh, float* __restrict__ out) {
    int idx = blockIdx.x * 256 + threadIdx.x;
    int n = idx >> 7, d = idx & 127;
    float deg = ddeg[n];
    float dinv = deg > 0.f ? 1.f / deg : 0.f;
    float v = oacc[idx] * dinv + bh[d];
    out[idx] = v > 0.f ? v : 0.f;
}

// ---------------------------------------------------------------------------
extern "C" void kernel_launch(void* const* d_in, const int* in_sizes, int n_in,
                              void* d_out, int out_size, void* d_ws, size_t ws_size,
                              hipStream_t stream) {
    (void)in_sizes; (void)n_in; (void)out_size; (void)ws_size;
    const float* x    = (const float*)d_in[0];
    const int*   edge = (const int*)  d_in[1];
    const float* Wq = (const float*)d_in[2];  const float* bq  = (const float*)d_in[3];
    const float* Wk = (const float*)d_in[4];  const float* bk  = (const float*)d_in[5];
    const float* Wv = (const float*)d_in[6];  const float* bv  = (const float*)d_in[7];
    const float* Wo = (const float*)d_in[8];  const float* bo  = (const float*)d_in[9];
    const float* g1 = (const float*)d_in[10]; const float* b1  = (const float*)d_in[11];
    const float* W1 = (const float*)d_in[12]; const float* bf1 = (const float*)d_in[13];
    const float* W2 = (const float*)d_in[14]; const float* bf2 = (const float*)d_in[15];
    const float* g2 = (const float*)d_in[16]; const float* b2  = (const float*)d_in[17];
    const float* Wh = (const float*)d_in[18]; const float* bh  = (const float*)d_in[19];
    float* out = (float*)d_out;

    float* B = (float*)d_ws;
    float* h   = B;                      // [N,128]   words 0..524288
    float* o   = B + 524288;             // [N,128]   attn out / FF temp
    float* t   = B + 1048576;            // [N,256]   region, 1048576 words
    float* v32 = B + 2097152;            // [H][N][64] fp32, 524288 words
    // bf16 qkv live inside t's region (t dead during attention)
    unsigned short* qb  = (unsigned short*)(B + 1048576);            // [H][N][64] bf16
    unsigned short* kb  = (unsigned short*)(B + 1048576 + 262144);   // [H][N][64] bf16
    unsigned short* vtb = (unsigned short*)(B + 1048576 + 524288);   // [H][64][N] bf16
    // hypergraph-stage reuse
    float* xt   = o;                     // [N,128]
    float* e    = v32;                   // [NE,128] = 262144 words
    float* bdeg = v32 + 262144;          // [NE]
    float* ddeg = bdeg + NEDGE;          // [N]
    float* oacc = t;                     // [N,128]
    int*   nidx = (int*)(B + 2621440);   // [NNZ]
    int*   hidx = nidx + NNZ_E;          // [NNZ]
    // peak ws: (2621440 + 131072)*4 B ~= 11.0 MB

    hipMemcpyAsync(h, x, (size_t)N_NODES * DIM * sizeof(float),
                   hipMemcpyDeviceToDevice, stream);
    edge_norm_kernel<<<NNZ_E / 256, 256, 0, stream>>>(edge, nidx, hidx);

    for (int layer = 0; layer < 2; ++layer) {
        gemm_k<128, 128, 0, 1, 1><<<256, 128, 0, stream>>>(h, Wq, bq, qb, N_NODES);
        gemm_k<128, 128, 0, 1, 1><<<256, 128, 0, stream>>>(h, Wk, bk, kb, N_NODES);
        gemm_k<128, 128, 0, 1, 0><<<256, 128, 0, stream>>>(h, Wv, bv, v32, N_NODES);
        vtrans_kernel<<<dim3(N_NODES / 64, NHEAD), 256, 0, stream>>>(v32, vtb);
        attn_mfma<<<dim3(N_NODES / 64, NHEAD), 256, 0, stream>>>(qb, kb, vtb, o);
        gemm_k<128, 128, 0, 0, 0><<<256, 128, 0, stream>>>(o, Wo, bo, t, N_NODES);
        ln_res_kernel<<<1024, 256, 0, stream>>>(h, t, g1, b1);
        gemm_k<128, 256, 1, 0, 0><<<256, 256, 0, stream>>>(h, W1, bf1, t, N_NODES);
        gemm_k<256, 128, 0, 0, 0><<<256, 128, 0, stream>>>(t, W2, bf2, o, N_NODES);
        ln_res_kernel<<<1024, 256, 0, stream>>>(h, o, g2, b2);
    }

    gemm_k<128, 128, 0, 0, 0><<<256, 128, 0, stream>>>(h, Wh, nullptr, xt, N_NODES);
    hipMemsetAsync(bdeg, 0, (NEDGE + N_NODES) * sizeof(float), stream);
    hipMemsetAsync(e, 0, (size_t)NEDGE * DIM * sizeof(float), stream);
    hipMemsetAsync(oacc, 0, (size_t)N_NODES * DIM * sizeof(float), stream);
    count_kernel<<<NNZ_E / 256, 256, 0, stream>>>(nidx, hidx, bdeg, ddeg);
    scatter1_kernel<<<NNZ_E * DIM / 256, 256, 0, stream>>>(nidx, hidx, xt, e);
    scatter2_kernel<<<NNZ_E * DIM / 256, 256, 0, stream>>>(nidx, hidx, e, bdeg, oacc);
    finalize_kernel<<<N_NODES * DIM / 256, 256, 0, stream>>>(oacc, ddeg, bh, out);
}

// Round 5
// 372.392 us; speedup vs baseline: 2.4952x; 1.7529x over previous
//
#include <hip/hip_runtime.h>
#include <hip/hip_bf16.h>
#include <cstddef>

// Problem constants
#define N_NODES 4096
#define DIM     128
#define NHEAD   2
#define DHEAD   64
#define FFDIM   256
#define NEDGE   2048
#define NNZ_E   65536
#define NSPLIT  4

typedef __attribute__((ext_vector_type(8))) short bf16x8;   // 8 bf16 in 4 VGPRs
typedef __attribute__((ext_vector_type(4))) float f32x4;

// float -> bf16 bits, round-to-nearest-even
__device__ __forceinline__ unsigned short f2b(float f) {
    unsigned u = __float_as_uint(f);
    return (unsigned short)((u + 0x7FFFu + ((u >> 16) & 1u)) >> 16);
}
__device__ __forceinline__ float b2f_bits(unsigned short h) {
    return __uint_as_float(((unsigned)h) << 16);
}

// ---------------------------------------------------------------------------
// Normalize edge indices to int32, auto-detecting int64 vs int32 source.
__global__ void edge_norm_kernel(const int* __restrict__ edge_raw,
                                 int* __restrict__ nidx, int* __restrict__ hidx) {
    __shared__ int is64_s;
    if (threadIdx.x == 0) {
        int bad = 0;
        for (int j = 0; j < 64; ++j) bad |= edge_raw[2 * j + 1];
        is64_s = (bad == 0) ? 1 : 0;
    }
    __syncthreads();
    const int is64 = is64_s;
    int i = blockIdx.x * 256 + threadIdx.x;
    if (i < NNZ_E) {
        if (is64) {
            nidx[i] = edge_raw[2 * i];
            hidx[i] = edge_raw[2 * NNZ_E + 2 * i];
        } else {
            nidx[i] = edge_raw[i];
            hidx[i] = edge_raw[NNZ_E + i];
        }
    }
}

// ---------------------------------------------------------------------------
// Pack W[K][NC] fp32 -> Wp: [2 planes (hi,lo)][K/8][NC][8] bf16.
__global__ void pack_w(const float* __restrict__ W, unsigned short* __restrict__ Wp,
                       int K, int NC) {
    int i = blockIdx.x * 256 + threadIdx.x;
    if (i < K * NC) {
        int k = i / NC, n = i % NC;
        float f = W[i];
        unsigned short h = f2b(f);
        float lo = f - b2f_bits(h);
        size_t o = ((size_t)(k >> 3) * NC + n) * 8 + (k & 7);
        Wp[o] = h;
        Wp[(size_t)K * NC + o] = f2b(lo);
    }
}

// ---------------------------------------------------------------------------
// Split-bf16 MFMA GEMM: C[M,NC] = act(A[M,K] @ W + bias), fp32-accurate.
// Block 256 = 4 waves; tile 64 rows x 32 cols.
template<int K, int NC, int ACT, int SPLIT, int OBF>
__global__ __launch_bounds__(256) void gemm_mfma(const float* __restrict__ A,
                                                 const unsigned short* __restrict__ Wp,
                                                 const float* __restrict__ bias,
                                                 void* __restrict__ Cv, int M) {
    const int tid = threadIdx.x, w = tid >> 6, lane = tid & 63;
    const int qi = lane & 15, gi = lane >> 4;
    const int row0 = blockIdx.x * 64 + w * 16;
    const int col0 = blockIdx.y * 32;
    const unsigned short* Wlo = Wp + (size_t)K * NC;

    f32x4 acc[2];
    acc[0] = (f32x4){0.f, 0.f, 0.f, 0.f};
    acc[1] = (f32x4){0.f, 0.f, 0.f, 0.f};

#pragma unroll
    for (int kc = 0; kc < K / 32; ++kc) {
        const int k0 = kc * 32;
        const float* arow = A + (size_t)(row0 + qi) * K + k0 + gi * 8;
        float4 a0 = ((const float4*)arow)[0];
        float4 a1 = ((const float4*)arow)[1];
        float av[8] = {a0.x, a0.y, a0.z, a0.w, a1.x, a1.y, a1.z, a1.w};
        bf16x8 ah, al;
#pragma unroll
        for (int j = 0; j < 8; ++j) {
            unsigned short hbits = f2b(av[j]);
            ah[j] = (short)hbits;
            al[j] = (short)f2b(av[j] - b2f_bits(hbits));
        }
#pragma unroll
        for (int c = 0; c < 2; ++c) {
            const size_t wo = ((size_t)(k0 / 8 + gi) * NC + col0 + c * 16 + qi) * 8;
            bf16x8 wh = *(const bf16x8*)(Wp + wo);
            bf16x8 wl = *(const bf16x8*)(Wlo + wo);
            acc[c] = __builtin_amdgcn_mfma_f32_16x16x32_bf16(ah, wh, acc[c], 0, 0, 0);
            acc[c] = __builtin_amdgcn_mfma_f32_16x16x32_bf16(al, wh, acc[c], 0, 0, 0);
            acc[c] = __builtin_amdgcn_mfma_f32_16x16x32_bf16(ah, wl, acc[c], 0, 0, 0);
        }
    }

#pragma unroll
    for (int c = 0; c < 2; ++c) {
        const int col = col0 + c * 16 + qi;
        float bv = bias ? bias[col] : 0.f;
#pragma unroll
        for (int r = 0; r < 4; ++r) {
            const int grow = row0 + gi * 4 + r;      // C-layout: col=lane&15, row=quad*4+r
            float v = acc[c][r] + bv;
            if (ACT == 1) v = 1.f / (1.f + __expf(-v));
            size_t idx;
            if (SPLIT) idx = ((size_t)(col >> 6) * M + grow) * 64 + (col & 63);
            else       idx = (size_t)grow * NC + col;
            if (OBF) ((unsigned short*)Cv)[idx] = f2b(v);
            else     ((float*)Cv)[idx] = v;
        }
    }
}

// ---------------------------------------------------------------------------
// v32 [H][N][64] fp32 -> vtb [H][64][N] bf16 (LDS tile transpose)
__global__ __launch_bounds__(256) void vtrans_kernel(const float* __restrict__ v32,
                                                     unsigned short* __restrict__ vtb) {
    __shared__ float ts[64][65];
    const int h = blockIdx.y, n0 = blockIdx.x * 64;
    const float* src = v32 + ((size_t)h * N_NODES + n0) * 64;
    for (int e = threadIdx.x; e < 4096; e += 256) {
        int r = e >> 6, d = e & 63;
        ts[r][d] = src[r * 64 + d];
    }
    __syncthreads();
    unsigned short* dst = vtb + (size_t)h * 64 * N_NODES + n0;
    for (int e = threadIdx.x; e < 4096; e += 256) {
        int d = e >> 6, n = e & 63;
        dst[(size_t)d * N_NODES + n] = f2b(ts[n][d]);
    }
}

// ---------------------------------------------------------------------------
// Split-K MFMA flash attention. Grid (N/64, H, NSPLIT); block 256 = 4 waves x 16 q rows.
#define ROWP 72
__global__ __launch_bounds__(256) void attn_mfma(const unsigned short* __restrict__ qb,
                                                 const unsigned short* __restrict__ kb,
                                                 const unsigned short* __restrict__ vtb,
                                                 float* __restrict__ op,
                                                 float* __restrict__ mlm,
                                                 float* __restrict__ mll) {
    __shared__ __align__(16) unsigned short k_s[64 * ROWP];
    __shared__ __align__(16) unsigned short vt_s[64 * ROWP];
    __shared__ __align__(16) unsigned short p_s[4][16 * ROWP];
    const int h = blockIdx.y;
    const int s = blockIdx.z;
    const int row0 = blockIdx.x * 64;
    const int tid = threadIdx.x;
    const int w = tid >> 6, lane = tid & 63;
    const int qi = lane & 15, gi = lane >> 4;
    const float CE = 0.18033688011f;   // 0.125 * log2(e)

    const unsigned short* qrow = qb + ((size_t)h * N_NODES + row0 + w * 16 + qi) * 64 + gi * 8;
    bf16x8 qf0 = *(const bf16x8*)qrow;
    bf16x8 qf1 = *(const bf16x8*)(qrow + 32);

    f32x4 oc[4];
#pragma unroll
    for (int i = 0; i < 4; ++i) oc[i] = (f32x4){0.f, 0.f, 0.f, 0.f};
    float m_run = -INFINITY, l_run = 0.f;

    const unsigned short* kbh = kb + (size_t)h * N_NODES * 64;
    const unsigned short* vth = vtb + (size_t)h * 64 * N_NODES;

    for (int kt = s * (N_NODES / 64 / NSPLIT); kt < (s + 1) * (N_NODES / 64 / NSPLIT); ++kt) {
        const unsigned short* ksrc = kbh + kt * 64 * 64;
#pragma unroll
        for (int i = 0; i < 2; ++i) {
            int c = tid + i * 256;
            int r = c >> 3, ss = c & 7;
            *(uint4*)&k_s[r * ROWP + ss * 8]  = *(const uint4*)(ksrc + c * 8);
            *(uint4*)&vt_s[r * ROWP + ss * 8] = *(const uint4*)(vth + (size_t)r * N_NODES + kt * 64 + ss * 8);
        }
        __syncthreads();

        f32x4 sc[4];
#pragma unroll
        for (int t = 0; t < 4; ++t) {
            const unsigned short* krow = &k_s[(t * 16 + qi) * ROWP + gi * 8];
            bf16x8 ka0 = *(const bf16x8*)krow;
            bf16x8 ka1 = *(const bf16x8*)(krow + 32);
            f32x4 z = (f32x4){0.f, 0.f, 0.f, 0.f};
            z = __builtin_amdgcn_mfma_f32_16x16x32_bf16(ka0, qf0, z, 0, 0, 0);
            sc[t] = __builtin_amdgcn_mfma_f32_16x16x32_bf16(ka1, qf1, z, 0, 0, 0);
        }

        float smax = -INFINITY;
#pragma unroll
        for (int t = 0; t < 4; ++t)
            smax = fmaxf(smax, fmaxf(fmaxf(sc[t][0], sc[t][1]), fmaxf(sc[t][2], sc[t][3])));
        smax = fmaxf(smax, __shfl_xor(smax, 16));
        smax = fmaxf(smax, __shfl_xor(smax, 32));
        float mn = fmaxf(m_run, smax);
        float alpha = exp2f((m_run - mn) * CE);
        m_run = mn;
        float nb = mn * CE;
        float psum = 0.f;
#pragma unroll
        for (int t = 0; t < 4; ++t) {
            ushort4 pw;
            float p0 = exp2f(fmaf(sc[t][0], CE, -nb)); psum += p0; pw.x = f2b(p0);
            float p1 = exp2f(fmaf(sc[t][1], CE, -nb)); psum += p1; pw.y = f2b(p1);
            float p2 = exp2f(fmaf(sc[t][2], CE, -nb)); psum += p2; pw.z = f2b(p2);
            float p3 = exp2f(fmaf(sc[t][3], CE, -nb)); psum += p3; pw.w = f2b(p3);
            *(ushort4*)&p_s[w][qi * ROWP + t * 16 + gi * 4] = pw;
        }
        psum += __shfl_xor(psum, 16);
        psum += __shfl_xor(psum, 32);
        l_run = l_run * alpha + psum;

        float a0 = __shfl(alpha, gi * 4 + 0);
        float a1 = __shfl(alpha, gi * 4 + 1);
        float a2 = __shfl(alpha, gi * 4 + 2);
        float a3 = __shfl(alpha, gi * 4 + 3);
#pragma unroll
        for (int d = 0; d < 4; ++d) {
            oc[d][0] *= a0; oc[d][1] *= a1; oc[d][2] *= a2; oc[d][3] *= a3;
        }

        const unsigned short* prow = &p_s[w][qi * ROWP];
        bf16x8 pa0 = *(const bf16x8*)(prow + gi * 8);
        bf16x8 pa1 = *(const bf16x8*)(prow + 32 + gi * 8);
#pragma unroll
        for (int d = 0; d < 4; ++d) {
            const unsigned short* vrow = &vt_s[(d * 16 + qi) * ROWP + gi * 8];
            bf16x8 vb0 = *(const bf16x8*)vrow;
            bf16x8 vb1 = *(const bf16x8*)(vrow + 32);
            oc[d] = __builtin_amdgcn_mfma_f32_16x16x32_bf16(pa0, vb0, oc[d], 0, 0, 0);
            oc[d] = __builtin_amdgcn_mfma_f32_16x16x32_bf16(pa1, vb1, oc[d], 0, 0, 0);
        }
        __syncthreads();
    }

    float* opd = op + (size_t)s * N_NODES * 128;
#pragma unroll
    for (int d = 0; d < 4; ++d) {
        size_t cb = h * 64 + d * 16 + qi;
        opd[(size_t)(row0 + w * 16 + gi * 4 + 0) * 128 + cb] = oc[d][0];
        opd[(size_t)(row0 + w * 16 + gi * 4 + 1) * 128 + cb] = oc[d][1];
        opd[(size_t)(row0 + w * 16 + gi * 4 + 2) * 128 + cb] = oc[d][2];
        opd[(size_t)(row0 + w * 16 + gi * 4 + 3) * 128 + cb] = oc[d][3];
    }
    if (gi == 0) {
        size_t mi = (size_t)s * NHEAD * N_NODES + (size_t)h * N_NODES + row0 + w * 16 + qi;
        mlm[mi] = m_run;
        mll[mi] = l_run;
    }
}

// Combine NSPLIT partials. og may alias op split 0 (per-thread read-before-write).
__global__ __launch_bounds__(256) void attn_combine(const float* __restrict__ op,
                                                    const float* __restrict__ mlm,
                                                    const float* __restrict__ mll,
                                                    float* __restrict__ og) {
    const float CE = 0.18033688011f;
    int idx = blockIdx.x * 256 + threadIdx.x;          // N*128
    int n = idx >> 7, c = idx & 127, h = c >> 6;
    size_t mb = (size_t)h * N_NODES + n;
    float m0 = mlm[mb], m1 = mlm[mb + NHEAD * N_NODES];
    float m2 = mlm[mb + 2 * NHEAD * N_NODES], m3 = mlm[mb + 3 * NHEAD * N_NODES];
    float mx = fmaxf(fmaxf(m0, m1), fmaxf(m2, m3));
    float w0 = exp2f((m0 - mx) * CE), w1 = exp2f((m1 - mx) * CE);
    float w2 = exp2f((m2 - mx) * CE), w3 = exp2f((m3 - mx) * CE);
    float L = w0 * mll[mb] + w1 * mll[mb + NHEAD * N_NODES]
            + w2 * mll[mb + 2 * NHEAD * N_NODES] + w3 * mll[mb + 3 * NHEAD * N_NODES];
    float O = w0 * op[idx] + w1 * op[idx + N_NODES * 128]
            + w2 * op[idx + 2 * N_NODES * 128] + w3 * op[idx + 3 * N_NODES * 128];
    og[idx] = O / L;
}

// ---------------------------------------------------------------------------
// h = LayerNorm(h + res) * g + b     (rows of 128, one wave per row)
__global__ __launch_bounds__(256) void ln_res_kernel(float* __restrict__ h,
                                                     const float* __restrict__ res,
                                                     const float* __restrict__ g,
                                                     const float* __restrict__ b) {
    int wave = threadIdx.x >> 6, lane = threadIdx.x & 63;
    int row = blockIdx.x * 4 + wave;
    size_t base = (size_t)row * 128;
    float x0 = h[base + lane]      + res[base + lane];
    float x1 = h[base + 64 + lane] + res[base + 64 + lane];
    float s  = x0 + x1;
    float sq = x0 * x0 + x1 * x1;
    for (int msk = 32; msk; msk >>= 1) { s += __shfl_xor(s, msk); sq += __shfl_xor(sq, msk); }
    float mean = s * (1.f / 128.f);
    float var  = sq * (1.f / 128.f) - mean * mean;
    float rstd = rsqrtf(var + 1e-5f);
    h[base + lane]      = (x0 - mean) * rstd * g[lane]      + b[lane];
    h[base + 64 + lane] = (x1 - mean) * rstd * g[lane + 64] + b[lane + 64];
}

// ---------------------------------------------------------------------------
// Hypergraph conv pieces (indices masked to valid range: crash-proofing)
__global__ void count_kernel(const int* __restrict__ nidx, const int* __restrict__ hidx,
                             float* __restrict__ bdeg, float* __restrict__ ddeg) {
    int i = blockIdx.x * 256 + threadIdx.x;
    if (i < NNZ_E) {
        atomicAdd(&ddeg[nidx[i] & (N_NODES - 1)], 1.f);
        atomicAdd(&bdeg[hidx[i] & (NEDGE - 1)], 1.f);
    }
}

__global__ void scatter1_kernel(const int* __restrict__ nidx, const int* __restrict__ hidx,
                                const float* __restrict__ xt, float* __restrict__ e) {
    int idx = blockIdx.x * 256 + threadIdx.x;
    int i = idx >> 7, d = idx & 127;
    int ni = nidx[i] & (N_NODES - 1), he = hidx[i] & (NEDGE - 1);
    atomicAdd(&e[(size_t)he * 128 + d], xt[(size_t)ni * 128 + d]);
}

__global__ void scatter2_kernel(const int* __restrict__ nidx, const int* __restrict__ hidx,
                                const float* __restrict__ e, const float* __restrict__ bdeg,
                                float* __restrict__ oacc) {
    int idx = blockIdx.x * 256 + threadIdx.x;
    int i = idx >> 7, d = idx & 127;
    int ni = nidx[i] & (N_NODES - 1), he = hidx[i] & (NEDGE - 1);
    float deg = bdeg[he];
    float binv = deg > 0.f ? 1.f / deg : 0.f;
    atomicAdd(&oacc[(size_t)ni * 128 + d], e[(size_t)he * 128 + d] * binv);
}

__global__ void finalize_kernel(const float* __restrict__ oacc, const float* __restrict__ ddeg,
                                const float* __restrict__ bh, float* __restrict__ out) {
    int idx = blockIdx.x * 256 + threadIdx.x;
    int n = idx >> 7, d = idx & 127;
    float deg = ddeg[n];
    float dinv = deg > 0.f ? 1.f / deg : 0.f;
    float v = oacc[idx] * dinv + bh[d];
    out[idx] = v > 0.f ? v : 0.f;
}

// ---------------------------------------------------------------------------
extern "C" void kernel_launch(void* const* d_in, const int* in_sizes, int n_in,
                              void* d_out, int out_size, void* d_ws, size_t ws_size,
                              hipStream_t stream) {
    (void)in_sizes; (void)n_in; (void)out_size; (void)ws_size;
    const float* x    = (const float*)d_in[0];
    const int*   edge = (const int*)  d_in[1];
    const float* Wq = (const float*)d_in[2];  const float* bq  = (const float*)d_in[3];
    const float* Wk = (const float*)d_in[4];  const float* bk  = (const float*)d_in[5];
    const float* Wv = (const float*)d_in[6];  const float* bv  = (const float*)d_in[7];
    const float* Wo = (const float*)d_in[8];  const float* bo  = (const float*)d_in[9];
    const float* g1 = (const float*)d_in[10]; const float* b1  = (const float*)d_in[11];
    const float* W1 = (const float*)d_in[12]; const float* bf1 = (const float*)d_in[13];
    const float* W2 = (const float*)d_in[14]; const float* bf2 = (const float*)d_in[15];
    const float* g2 = (const float*)d_in[16]; const float* b2  = (const float*)d_in[17];
    const float* Wh = (const float*)d_in[18]; const float* bh  = (const float*)d_in[19];
    float* out = (float*)d_out;

    // ---- workspace layout (word offsets), peak 3,883,008 words = 15.5 MB ----
    // Phase lifetimes verified pairwise; op region is multiply reused:
    //   pre-attn:  v32 = op[0 : 524288)
    //   attn:      op [NSPLIT][N][128]
    //   combine:   o = op[0 : 524288)   (per-thread read-before-write, safe alias)
    //   hypergraph: xt = op0, e = op+524288, nidx/hidx = op+786432 (op dead)
    float* B = (float*)d_ws;
    float* h   = B;                          // [N,128]  persistent
    float* t   = B + 524288;                 // [N,256] region
    unsigned short* qb  = (unsigned short*)(B + 524288);    // [H][N][64] bf16
    unsigned short* kb  = (unsigned short*)(B + 786432);
    unsigned short* vtb = (unsigned short*)(B + 1048576);   // [H][64][N] bf16
    float* op  = B + 1572864;                // [NSPLIT][N][128]
    float* v32 = op;                         // [H][N][64] fp32 (pre-attn)
    float* o   = op;                         // combine output
    float* mlm = B + 3670016;                // [NSPLIT][H][N]
    float* mll = B + 3702784;
    unsigned short* wp_q = (unsigned short*)(B + 3735552);  // 128x128 pack: 16384 words
    unsigned short* wp_k = (unsigned short*)(B + 3751936);
    unsigned short* wp_v = (unsigned short*)(B + 3768320);
    unsigned short* wp_o = (unsigned short*)(B + 3784704);
    unsigned short* wp_1 = (unsigned short*)(B + 3801088);  // 128x256: 32768 words
    unsigned short* wp_2 = (unsigned short*)(B + 3833856);  // 256x128: 32768 words
    unsigned short* wp_h = (unsigned short*)(B + 3866624);  // 16384 -> end 3883008
    // hypergraph phase (transformer temporaries dead):
    float* xt   = op;                        // [N,128]
    float* e    = op + 524288;               // [NE,128] = 262144 words
    int*   nidx = (int*)(op + 786432);       // [NNZ]
    int*   hidx = nidx + NNZ_E;              // [NNZ]  ends at op+917504 < op+2097152
    float* oacc = t;                         // [N,128]
    float* bdeg = t + 524288;                // [NE]
    float* ddeg = bdeg + NEDGE;              // [N]

    hipMemcpyAsync(h, x, (size_t)N_NODES * DIM * sizeof(float),
                   hipMemcpyDeviceToDevice, stream);

    // pre-pack weights to hi/lo bf16 fragment layout
    pack_w<<<64, 256, 0, stream>>>(Wq, wp_q, 128, 128);
    pack_w<<<64, 256, 0, stream>>>(Wk, wp_k, 128, 128);
    pack_w<<<64, 256, 0, stream>>>(Wv, wp_v, 128, 128);
    pack_w<<<64, 256, 0, stream>>>(Wo, wp_o, 128, 128);
    pack_w<<<128, 256, 0, stream>>>(W1, wp_1, 128, 256);
    pack_w<<<128, 256, 0, stream>>>(W2, wp_2, 256, 128);
    pack_w<<<64, 256, 0, stream>>>(Wh, wp_h, 128, 128);

    for (int layer = 0; layer < 2; ++layer) {
        gemm_mfma<128, 128, 0, 1, 1><<<dim3(64, 4), 256, 0, stream>>>(h, wp_q, bq, qb, N_NODES);
        gemm_mfma<128, 128, 0, 1, 1><<<dim3(64, 4), 256, 0, stream>>>(h, wp_k, bk, kb, N_NODES);
        gemm_mfma<128, 128, 0, 1, 0><<<dim3(64, 4), 256, 0, stream>>>(h, wp_v, bv, v32, N_NODES);
        vtrans_kernel<<<dim3(N_NODES / 64, NHEAD), 256, 0, stream>>>(v32, vtb);
        attn_mfma<<<dim3(N_NODES / 64, NHEAD, NSPLIT), 256, 0, stream>>>(qb, kb, vtb, op, mlm, mll);
        attn_combine<<<N_NODES * 128 / 256, 256, 0, stream>>>(op, mlm, mll, o);
        gemm_mfma<128, 128, 0, 0, 0><<<dim3(64, 4), 256, 0, stream>>>(o, wp_o, bo, t, N_NODES);
        ln_res_kernel<<<1024, 256, 0, stream>>>(h, t, g1, b1);
        gemm_mfma<128, 256, 1, 0, 0><<<dim3(64, 8), 256, 0, stream>>>(h, wp_1, bf1, t, N_NODES);
        gemm_mfma<256, 128, 0, 0, 0><<<dim3(64, 4), 256, 0, stream>>>(t, wp_2, bf2, o, N_NODES);
        ln_res_kernel<<<1024, 256, 0, stream>>>(h, o, g2, b2);
    }

    gemm_mfma<128, 128, 0, 0, 0><<<dim3(64, 4), 256, 0, stream>>>(h, wp_h, nullptr, xt, N_NODES);
    // hypergraph phase: indices + degree tables built now (op region is dead)
    edge_norm_kernel<<<NNZ_E / 256, 256, 0, stream>>>(edge, nidx, hidx);
    hipMemsetAsync(bdeg, 0, (NEDGE + N_NODES) * sizeof(float), stream);
    hipMemsetAsync(e, 0, (size_t)NEDGE * DIM * sizeof(float), stream);
    hipMemsetAsync(oacc, 0, (size_t)N_NODES * DIM * sizeof(float), stream);
    count_kernel<<<NNZ_E / 256, 256, 0, stream>>>(nidx, hidx, bdeg, ddeg);
    scatter1_kernel<<<NNZ_E * DIM / 256, 256, 0, stream>>>(nidx, hidx, xt, e);
    scatter2_kernel<<<NNZ_E * DIM / 256, 256, 0, stream>>>(nidx, hidx, e, bdeg, oacc);
    finalize_kernel<<<N_NODES * DIM / 256, 256, 0, stream>>>(oacc, ddeg, bh, out);
}

// Round 6
// 301.276 us; speedup vs baseline: 3.0842x; 1.2361x over previous
//
#include <hip/hip_runtime.h>
#include <hip/hip_bf16.h>
#include <cstddef>

// Problem constants
#define N_NODES 4096
#define DIM     128
#define NHEAD   2
#define DHEAD   64
#define FFDIM   256
#define NEDGE   2048
#define NNZ_E   65536
#define NSPLIT  8

typedef __attribute__((ext_vector_type(8))) short bf16x8;   // 8 bf16 in 4 VGPRs
typedef __attribute__((ext_vector_type(4))) float f32x4;
typedef unsigned short u16;

__device__ __forceinline__ u16 f2b(float f) {               // rne fp32->bf16
    unsigned u = __float_as_uint(f);
    return (u16)((u + 0x7FFFu + ((u >> 16) & 1u)) >> 16);
}
__device__ __forceinline__ float b2f_bits(u16 h) {
    return __uint_as_float(((unsigned)h) << 16);
}

// ---------------------------------------------------------------------------
// x fp32 -> h fp32 + hi/lo bf16 planes (replaces memcpy + per-gemm split)
__global__ void split_x_kernel(const float* __restrict__ x, float* __restrict__ h,
                               u16* __restrict__ hh, u16* __restrict__ hl) {
    int i = blockIdx.x * 256 + threadIdx.x;
    float f = x[i];
    h[i] = f;
    u16 hi = f2b(f);
    hh[i] = hi;
    hl[i] = f2b(f - b2f_bits(hi));
}

// ---------------------------------------------------------------------------
// Pack all 7 weights: W[K][NC] fp32 -> [2 planes][K/8][NC][8] bf16.
__global__ void pack_all(const float* W0, const float* W1, const float* W2,
                         const float* W3, const float* W4, const float* W5,
                         const float* W6,
                         u16* P0, u16* P1, u16* P2, u16* P3, u16* P4, u16* P5, u16* P6) {
    const float* W; u16* P; int K, NC;
    switch (blockIdx.y) {
        case 0: W = W0; P = P0; K = 128; NC = 128; break;
        case 1: W = W1; P = P1; K = 128; NC = 128; break;
        case 2: W = W2; P = P2; K = 128; NC = 128; break;
        case 3: W = W3; P = P3; K = 128; NC = 128; break;
        case 4: W = W4; P = P4; K = 128; NC = 128; break;
        case 5: W = W5; P = P5; K = 128; NC = 256; break;
        default: W = W6; P = P6; K = 256; NC = 128; break;
    }
    int i = blockIdx.x * 256 + threadIdx.x;
    if (i < K * NC) {
        int k = i / NC, n = i % NC;
        float f = W[i];
        u16 h = f2b(f);
        size_t o = ((size_t)(k >> 3) * NC + n) * 8 + (k & 7);
        P[o] = h;
        P[(size_t)K * NC + o] = f2b(f - b2f_bits(h));
    }
}

// ---------------------------------------------------------------------------
// Split-bf16 MFMA GEMM, A pre-split: C = act(A @ W + bias).
// A given as hi/lo bf16 planes [M][K]. 3-term: Ah*Wh + Al*Wh + Ah*Wl (~fp32).
// Block 256 = 4 waves; tile 64 rows x 32 cols. No LDS.
// OBF: 0 = fp32 C0; 1 = bf16 C0; 2 = bf16 hi C0 + lo C1.
template<int K, int NC, int ACT, int SPLIT, int OBF>
__global__ __launch_bounds__(256) void gemm_mfma(const u16* __restrict__ Ah,
                                                 const u16* __restrict__ Al,
                                                 const u16* __restrict__ Wp,
                                                 const float* __restrict__ bias,
                                                 void* __restrict__ C0,
                                                 void* __restrict__ C1, int M) {
    const int tid = threadIdx.x, w = tid >> 6, lane = tid & 63;
    const int qi = lane & 15, gi = lane >> 4;
    const int row0 = blockIdx.x * 64 + w * 16;
    const int col0 = blockIdx.y * 32;
    const u16* Wlo = Wp + (size_t)K * NC;

    f32x4 acc[2];
    acc[0] = (f32x4){0.f, 0.f, 0.f, 0.f};
    acc[1] = (f32x4){0.f, 0.f, 0.f, 0.f};

#pragma unroll 4
    for (int kc = 0; kc < K / 32; ++kc) {
        const int k0 = kc * 32;
        const size_t ao = (size_t)(row0 + qi) * K + k0 + gi * 8;
        bf16x8 ah = *(const bf16x8*)(Ah + ao);
        bf16x8 al = *(const bf16x8*)(Al + ao);
#pragma unroll
        for (int c = 0; c < 2; ++c) {
            const size_t wo = ((size_t)(k0 / 8 + gi) * NC + col0 + c * 16 + qi) * 8;
            bf16x8 wh = *(const bf16x8*)(Wp + wo);
            bf16x8 wl = *(const bf16x8*)(Wlo + wo);
            acc[c] = __builtin_amdgcn_mfma_f32_16x16x32_bf16(ah, wh, acc[c], 0, 0, 0);
            acc[c] = __builtin_amdgcn_mfma_f32_16x16x32_bf16(al, wh, acc[c], 0, 0, 0);
            acc[c] = __builtin_amdgcn_mfma_f32_16x16x32_bf16(ah, wl, acc[c], 0, 0, 0);
        }
    }

#pragma unroll
    for (int c = 0; c < 2; ++c) {
        const int col = col0 + c * 16 + qi;
        float bv = bias ? bias[col] : 0.f;
#pragma unroll
        for (int r = 0; r < 4; ++r) {
            const int grow = row0 + gi * 4 + r;      // C-layout: col=lane&15, row=quad*4+r
            float v = acc[c][r] + bv;
            if (ACT == 1) v = 1.f / (1.f + __expf(-v));
            size_t idx;
            if (SPLIT) idx = ((size_t)(col >> 6) * M + grow) * 64 + (col & 63);
            else       idx = (size_t)grow * NC + col;
            if (OBF == 0) ((float*)C0)[idx] = v;
            else if (OBF == 1) ((u16*)C0)[idx] = f2b(v);
            else {
                u16 hi = f2b(v);
                ((u16*)C0)[idx] = hi;
                ((u16*)C1)[idx] = f2b(v - b2f_bits(hi));
            }
        }
    }
}

// ---------------------------------------------------------------------------
// vb [H][N][64] bf16 -> vtb [H][64][N] bf16 (LDS tile transpose)
__global__ __launch_bounds__(256) void vtrans_kernel(const u16* __restrict__ vb,
                                                     u16* __restrict__ vtb) {
    __shared__ u16 ts[64][68];
    const int h = blockIdx.y, n0 = blockIdx.x * 64;
    const u16* src = vb + ((size_t)h * N_NODES + n0) * 64;
    for (int e = threadIdx.x; e < 4096; e += 256) {
        int r = e >> 6, d = e & 63;
        ts[r][d] = src[e];
    }
    __syncthreads();
    u16* dst = vtb + (size_t)h * 64 * N_NODES + n0;
    for (int e = threadIdx.x; e < 4096; e += 256) {
        int d = e >> 6, n = e & 63;
        dst[(size_t)d * N_NODES + n] = ts[n][d];
    }
}

// ---------------------------------------------------------------------------
// Split-K MFMA flash attention. Grid (N/64, H, NSPLIT); block 256 = 4 waves.
#define ROWP 72
__global__ __launch_bounds__(256) void attn_mfma(const u16* __restrict__ qb,
                                                 const u16* __restrict__ kb,
                                                 const u16* __restrict__ vtb,
                                                 float* __restrict__ op,
                                                 float* __restrict__ mlm,
                                                 float* __restrict__ mll) {
    __shared__ __align__(16) u16 k_s[64 * ROWP];
    __shared__ __align__(16) u16 vt_s[64 * ROWP];
    __shared__ __align__(16) u16 p_s[4][16 * ROWP];
    const int h = blockIdx.y;
    const int s = blockIdx.z;
    const int row0 = blockIdx.x * 64;
    const int tid = threadIdx.x;
    const int w = tid >> 6, lane = tid & 63;
    const int qi = lane & 15, gi = lane >> 4;
    const float CE = 0.18033688011f;   // 0.125 * log2(e)

    const u16* qrow = qb + ((size_t)h * N_NODES + row0 + w * 16 + qi) * 64 + gi * 8;
    bf16x8 qf0 = *(const bf16x8*)qrow;
    bf16x8 qf1 = *(const bf16x8*)(qrow + 32);

    f32x4 oc[4];
#pragma unroll
    for (int i = 0; i < 4; ++i) oc[i] = (f32x4){0.f, 0.f, 0.f, 0.f};
    float m_run = -INFINITY, l_run = 0.f;

    const u16* kbh = kb + (size_t)h * N_NODES * 64;
    const u16* vth = vtb + (size_t)h * 64 * N_NODES;

    for (int kt = s * (N_NODES / 64 / NSPLIT); kt < (s + 1) * (N_NODES / 64 / NSPLIT); ++kt) {
        const u16* ksrc = kbh + kt * 64 * 64;
#pragma unroll
        for (int i = 0; i < 2; ++i) {
            int c = tid + i * 256;
            int r = c >> 3, ss = c & 7;
            *(uint4*)&k_s[r * ROWP + ss * 8]  = *(const uint4*)(ksrc + c * 8);
            *(uint4*)&vt_s[r * ROWP + ss * 8] = *(const uint4*)(vth + (size_t)r * N_NODES + kt * 64 + ss * 8);
        }
        __syncthreads();

        f32x4 sc[4];
#pragma unroll
        for (int t = 0; t < 4; ++t) {
            const u16* krow = &k_s[(t * 16 + qi) * ROWP + gi * 8];
            bf16x8 ka0 = *(const bf16x8*)krow;
            bf16x8 ka1 = *(const bf16x8*)(krow + 32);
            f32x4 z = (f32x4){0.f, 0.f, 0.f, 0.f};
            z = __builtin_amdgcn_mfma_f32_16x16x32_bf16(ka0, qf0, z, 0, 0, 0);
            sc[t] = __builtin_amdgcn_mfma_f32_16x16x32_bf16(ka1, qf1, z, 0, 0, 0);
        }

        float smax = -INFINITY;
#pragma unroll
        for (int t = 0; t < 4; ++t)
            smax = fmaxf(smax, fmaxf(fmaxf(sc[t][0], sc[t][1]), fmaxf(sc[t][2], sc[t][3])));
        smax = fmaxf(smax, __shfl_xor(smax, 16));
        smax = fmaxf(smax, __shfl_xor(smax, 32));
        float mn = fmaxf(m_run, smax);
        float alpha = exp2f((m_run - mn) * CE);
        m_run = mn;
        float nb = mn * CE;
        float psum = 0.f;
#pragma unroll
        for (int t = 0; t < 4; ++t) {
            ushort4 pw;
            float p0 = exp2f(fmaf(sc[t][0], CE, -nb)); psum += p0; pw.x = f2b(p0);
            float p1 = exp2f(fmaf(sc[t][1], CE, -nb)); psum += p1; pw.y = f2b(p1);
            float p2 = exp2f(fmaf(sc[t][2], CE, -nb)); psum += p2; pw.z = f2b(p2);
            float p3 = exp2f(fmaf(sc[t][3], CE, -nb)); psum += p3; pw.w = f2b(p3);
            *(ushort4*)&p_s[w][qi * ROWP + t * 16 + gi * 4] = pw;
        }
        psum += __shfl_xor(psum, 16);
        psum += __shfl_xor(psum, 32);
        l_run = l_run * alpha + psum;

        float a0 = __shfl(alpha, gi * 4 + 0);
        float a1 = __shfl(alpha, gi * 4 + 1);
        float a2 = __shfl(alpha, gi * 4 + 2);
        float a3 = __shfl(alpha, gi * 4 + 3);
#pragma unroll
        for (int d = 0; d < 4; ++d) {
            oc[d][0] *= a0; oc[d][1] *= a1; oc[d][2] *= a2; oc[d][3] *= a3;
        }

        const u16* prow = &p_s[w][qi * ROWP];
        bf16x8 pa0 = *(const bf16x8*)(prow + gi * 8);
        bf16x8 pa1 = *(const bf16x8*)(prow + 32 + gi * 8);
#pragma unroll
        for (int d = 0; d < 4; ++d) {
            const u16* vrow = &vt_s[(d * 16 + qi) * ROWP + gi * 8];
            bf16x8 vb0 = *(const bf16x8*)vrow;
            bf16x8 vb1 = *(const bf16x8*)(vrow + 32);
            oc[d] = __builtin_amdgcn_mfma_f32_16x16x32_bf16(pa0, vb0, oc[d], 0, 0, 0);
            oc[d] = __builtin_amdgcn_mfma_f32_16x16x32_bf16(pa1, vb1, oc[d], 0, 0, 0);
        }
        __syncthreads();
    }

    float* opd = op + (size_t)s * N_NODES * 128;
#pragma unroll
    for (int d = 0; d < 4; ++d) {
        size_t cb = h * 64 + d * 16 + qi;
        opd[(size_t)(row0 + w * 16 + gi * 4 + 0) * 128 + cb] = oc[d][0];
        opd[(size_t)(row0 + w * 16 + gi * 4 + 1) * 128 + cb] = oc[d][1];
        opd[(size_t)(row0 + w * 16 + gi * 4 + 2) * 128 + cb] = oc[d][2];
        opd[(size_t)(row0 + w * 16 + gi * 4 + 3) * 128 + cb] = oc[d][3];
    }
    if (gi == 0) {
        size_t mi = (size_t)s * NHEAD * N_NODES + (size_t)h * N_NODES + row0 + w * 16 + qi;
        mlm[mi] = m_run;
        mll[mi] = l_run;
    }
}

// Combine NSPLIT partials -> hi/lo bf16 planes (feeds Wo gemm directly)
__global__ __launch_bounds__(256) void attn_combine(const float* __restrict__ op,
                                                    const float* __restrict__ mlm,
                                                    const float* __restrict__ mll,
                                                    u16* __restrict__ ohi,
                                                    u16* __restrict__ olo) {
    const float CE = 0.18033688011f;
    int idx = blockIdx.x * 256 + threadIdx.x;          // N*128
    int n = idx >> 7, c = idx & 127, h = c >> 6;
    size_t mb = (size_t)h * N_NODES + n;
    float m[NSPLIT], l[NSPLIT];
    float mx = -INFINITY;
#pragma unroll
    for (int s = 0; s < NSPLIT; ++s) {
        m[s] = mlm[mb + (size_t)s * NHEAD * N_NODES];
        l[s] = mll[mb + (size_t)s * NHEAD * N_NODES];
        mx = fmaxf(mx, m[s]);
    }
    float L = 0.f, O = 0.f;
#pragma unroll
    for (int s = 0; s < NSPLIT; ++s) {
        float ws = exp2f((m[s] - mx) * CE);
        L += ws * l[s];
        O += ws * op[(size_t)s * N_NODES * 128 + idx];
    }
    float v = O / L;
    u16 hi = f2b(v);
    ohi[idx] = hi;
    olo[idx] = f2b(v - b2f_bits(hi));
}

// ---------------------------------------------------------------------------
// h = LayerNorm(h + res) * g + b; also emits hi/lo bf16 planes of the result.
__global__ __launch_bounds__(256) void ln_res_kernel(float* __restrict__ h,
                                                     const float* __restrict__ res,
                                                     const float* __restrict__ g,
                                                     const float* __restrict__ b,
                                                     u16* __restrict__ hh,
                                                     u16* __restrict__ hl) {
    int wave = threadIdx.x >> 6, lane = threadIdx.x & 63;
    int row = blockIdx.x * 4 + wave;
    size_t base = (size_t)row * 128;
    float x0 = h[base + lane]      + res[base + lane];
    float x1 = h[base + 64 + lane] + res[base + 64 + lane];
    float s  = x0 + x1;
    float sq = x0 * x0 + x1 * x1;
    for (int msk = 32; msk; msk >>= 1) { s += __shfl_xor(s, msk); sq += __shfl_xor(sq, msk); }
    float mean = s * (1.f / 128.f);
    float var  = sq * (1.f / 128.f) - mean * mean;
    float rstd = rsqrtf(var + 1e-5f);
    float y0 = (x0 - mean) * rstd * g[lane]      + b[lane];
    float y1 = (x1 - mean) * rstd * g[lane + 64] + b[lane + 64];
    h[base + lane] = y0;  h[base + 64 + lane] = y1;
    u16 hi0 = f2b(y0), hi1 = f2b(y1);
    hh[base + lane] = hi0;           hh[base + 64 + lane] = hi1;
    hl[base + lane] = f2b(y0 - b2f_bits(hi0));
    hl[base + 64 + lane] = f2b(y1 - b2f_bits(hi1));
}

// ---------------------------------------------------------------------------
// Hypergraph: CSR build (counting sort) + atomic-free gathers
__global__ void edge_norm_count(const int* __restrict__ edge_raw,
                                int* __restrict__ nidx, int* __restrict__ hidx,
                                int* __restrict__ cnt_e, int* __restrict__ cnt_n) {
    __shared__ int is64_s;
    if (threadIdx.x == 0) {
        int bad = 0;
        for (int j = 0; j < 64; ++j) bad |= edge_raw[2 * j + 1];
        is64_s = (bad == 0) ? 1 : 0;
    }
    __syncthreads();
    const int is64 = is64_s;
    int i = blockIdx.x * 256 + threadIdx.x;
    if (i < NNZ_E) {
        int ni, he;
        if (is64) { ni = edge_raw[2 * i]; he = edge_raw[2 * NNZ_E + 2 * i]; }
        else      { ni = edge_raw[i];     he = edge_raw[NNZ_E + i]; }
        ni &= (N_NODES - 1); he &= (NEDGE - 1);
        nidx[i] = ni; hidx[i] = he;
        atomicAdd(&cnt_n[ni], 1);
        atomicAdd(&cnt_e[he], 1);
    }
}

// block 0: exclusive-scan cnt_e (NE) -> off_e; block 1: cnt_n (N) -> off_n
__global__ __launch_bounds__(1024) void scan2_kernel(const int* __restrict__ cnt_e,
                                                     int* __restrict__ off_e,
                                                     const int* __restrict__ cnt_n,
                                                     int* __restrict__ off_n) {
    __shared__ int s[N_NODES];
    const int n = (blockIdx.x == 0) ? NEDGE : N_NODES;
    const int* cnt = (blockIdx.x == 0) ? cnt_e : cnt_n;
    int* off = (blockIdx.x == 0) ? off_e : off_n;
    for (int i = threadIdx.x; i < n; i += 1024) s[i] = cnt[i];
    __syncthreads();
    for (int st = 1; st < n; st <<= 1) {
        int v[4]; int nj = 0;
        for (int i = threadIdx.x; i < n; i += 1024) v[nj++] = (i >= st) ? s[i - st] : 0;
        __syncthreads();
        nj = 0;
        for (int i = threadIdx.x; i < n; i += 1024) s[i] += v[nj++];
        __syncthreads();
    }
    for (int i = threadIdx.x; i < n; i += 1024) off[i + 1] = s[i];
    if (threadIdx.x == 0) off[0] = 0;
}

__global__ void fill_csr(const int* __restrict__ nidx, const int* __restrict__ hidx,
                         const int* __restrict__ off_e, const int* __restrict__ off_n,
                         int* __restrict__ cur_e, int* __restrict__ cur_n,
                         int* __restrict__ csr_e, int* __restrict__ csr_n) {
    int i = blockIdx.x * 256 + threadIdx.x;
    if (i < NNZ_E) {
        int ni = nidx[i], he = hidx[i];
        int p = atomicAdd(&cur_e[he], 1);
        csr_e[off_e[he] + p] = ni;
        int q = atomicAdd(&cur_n[ni], 1);
        csr_n[off_n[ni] + q] = he;
    }
}

// e_sc[he] = (1/deg) * sum_{members} xt[member]    (one block of 128 per hyperedge)
__global__ __launch_bounds__(128) void gather_e(const int* __restrict__ off_e,
                                                const int* __restrict__ csr_e,
                                                const float* __restrict__ xt,
                                                float* __restrict__ e_sc) {
    __shared__ int ms[128];
    const int he = blockIdx.x, d = threadIdx.x;
    const int beg = off_e[he], end = off_e[he + 1];
    float acc = 0.f;
    for (int c = beg; c < end; c += 128) {
        int nl = min(128, end - c);
        if (d < nl) ms[d] = csr_e[c + d];
        __syncthreads();
        for (int j = 0; j < nl; ++j) acc += xt[(size_t)ms[j] * 128 + d];
        __syncthreads();
    }
    float binv = (end > beg) ? 1.f / (float)(end - beg) : 0.f;
    e_sc[(size_t)he * 128 + d] = acc * binv;
}

// out[n] = relu((1/deg) * sum_{incident he} e_sc[he] + bh)   (block per node; fuses finalize)
__global__ __launch_bounds__(128) void gather_n(const int* __restrict__ off_n,
                                                const int* __restrict__ csr_n,
                                                const float* __restrict__ e_sc,
                                                const float* __restrict__ bh,
                                                float* __restrict__ out) {
    __shared__ int ms[128];
    const int nn = blockIdx.x, d = threadIdx.x;
    const int beg = off_n[nn], end = off_n[nn + 1];
    float acc = 0.f;
    for (int c = beg; c < end; c += 128) {
        int nl = min(128, end - c);
        if (d < nl) ms[d] = csr_n[c + d];
        __syncthreads();
        for (int j = 0; j < nl; ++j) acc += e_sc[(size_t)ms[j] * 128 + d];
        __syncthreads();
    }
    float dinv = (end > beg) ? 1.f / (float)(end - beg) : 0.f;
    float v = acc * dinv + bh[d];
    out[(size_t)nn * 128 + d] = v > 0.f ? v : 0.f;
}

// ---------------------------------------------------------------------------
extern "C" void kernel_launch(void* const* d_in, const int* in_sizes, int n_in,
                              void* d_out, int out_size, void* d_ws, size_t ws_size,
                              hipStream_t stream) {
    (void)in_sizes; (void)n_in; (void)out_size; (void)ws_size;
    const float* x    = (const float*)d_in[0];
    const int*   edge = (const int*)  d_in[1];
    const float* Wq = (const float*)d_in[2];  const float* bq  = (const float*)d_in[3];
    const float* Wk = (const float*)d_in[4];  const float* bk  = (const float*)d_in[5];
    const float* Wv = (const float*)d_in[6];  const float* bv  = (const float*)d_in[7];
    const float* Wo = (const float*)d_in[8];  const float* bo  = (const float*)d_in[9];
    const float* g1 = (const float*)d_in[10]; const float* b1  = (const float*)d_in[11];
    const float* W1 = (const float*)d_in[12]; const float* bf1 = (const float*)d_in[13];
    const float* W2 = (const float*)d_in[14]; const float* bf2 = (const float*)d_in[15];
    const float* g2 = (const float*)d_in[16]; const float* b2  = (const float*)d_in[17];
    const float* Wh = (const float*)d_in[18]; const float* bh  = (const float*)d_in[19];
    float* out = (float*)d_out;

    // ---- workspace layout (fp32-word offsets), all regions DISJOINT; peak ~38.9 MB ----
    float* B = (float*)d_ws;
    float* h    = B;                          // [N,128] fp32
    u16*   h_hi = (u16*)(B + 524288);         // [N,128] bf16
    u16*   h_lo = (u16*)(B + 786432);
    u16*   qb   = (u16*)(B + 1048576);        // [H][N][64] bf16
    u16*   kb   = (u16*)(B + 1310720);
    u16*   vb   = (u16*)(B + 1572864);
    u16*   vtb  = (u16*)(B + 1835008);        // [H][64][N] bf16
    float* op   = B + 2097152;                // [NSPLIT][N][128] fp32 -> end 6291456
    float* mlm  = B + 6291456;                // [NSPLIT][H][N]
    float* mll  = B + 6356992;                // -> end 6422528
    u16*   o_hi = (u16*)(B + 6422528);        // [N,128] bf16
    u16*   o_lo = (u16*)(B + 6684672);
    u16*   t_hi = (u16*)(B + 6946816);        // [N,256] bf16 (524288 words)
    u16*   t_lo = (u16*)(B + 7471104);
    float* res32 = B + 7995392;               // [N,128] fp32 -> end 8519680
    u16*   wp_q = (u16*)(B + 8519680);        // packs: 16384 w each (128x128)
    u16*   wp_k = (u16*)(B + 8536064);
    u16*   wp_v = (u16*)(B + 8552448);
    u16*   wp_o = (u16*)(B + 8568832);
    u16*   wp_h = (u16*)(B + 8585216);
    u16*   wp_1 = (u16*)(B + 8601600);        // 128x256: 32768 w
    u16*   wp_2 = (u16*)(B + 8634368);        // 256x128: 32768 w -> end 8667136
    float* xt   = B + 8667136;                // [N,128] fp32 -> end 9191424
    int*   nidx = (int*)(B + 9191424);        // [NNZ]
    int*   hidx = (int*)(B + 9256960);        // [NNZ]
    int*   cnt_e = (int*)(B + 9322496);       // [NE]   } one 48KB memset covers
    int*   cnt_n = (int*)(B + 9324544);       // [N]    } cnt_e..cur_n
    int*   cur_e = (int*)(B + 9328640);       // [NE]
    int*   cur_n = (int*)(B + 9330688);       // [N]    -> end 9334784
    int*   off_e = (int*)(B + 9334784);       // [NE+1]
    int*   off_n = (int*)(B + 9336840);       // [N+1]
    int*   csr_e = (int*)(B + 9340944);       // [NNZ]
    int*   csr_n = (int*)(B + 9406480);       // [NNZ]
    float* e_sc  = B + 9472016;               // [NE,128] -> end 9734160 (~38.9 MB)

    split_x_kernel<<<2048, 256, 0, stream>>>(x, h, h_hi, h_lo);
    pack_all<<<dim3(128, 7), 256, 0, stream>>>(Wq, Wk, Wv, Wo, Wh, W1, W2,
                                               wp_q, wp_k, wp_v, wp_o, wp_h, wp_1, wp_2);

    for (int layer = 0; layer < 2; ++layer) {
        gemm_mfma<128, 128, 0, 1, 1><<<dim3(64, 4), 256, 0, stream>>>(h_hi, h_lo, wp_q, bq, qb, nullptr, N_NODES);
        gemm_mfma<128, 128, 0, 1, 1><<<dim3(64, 4), 256, 0, stream>>>(h_hi, h_lo, wp_k, bk, kb, nullptr, N_NODES);
        gemm_mfma<128, 128, 0, 1, 1><<<dim3(64, 4), 256, 0, stream>>>(h_hi, h_lo, wp_v, bv, vb, nullptr, N_NODES);
        vtrans_kernel<<<dim3(N_NODES / 64, NHEAD), 256, 0, stream>>>(vb, vtb);
        attn_mfma<<<dim3(N_NODES / 64, NHEAD, NSPLIT), 256, 0, stream>>>(qb, kb, vtb, op, mlm, mll);
        attn_combine<<<N_NODES * 128 / 256, 256, 0, stream>>>(op, mlm, mll, o_hi, o_lo);
        gemm_mfma<128, 128, 0, 0, 0><<<dim3(64, 4), 256, 0, stream>>>(o_hi, o_lo, wp_o, bo, res32, nullptr, N_NODES);
        ln_res_kernel<<<1024, 256, 0, stream>>>(h, res32, g1, b1, h_hi, h_lo);
        gemm_mfma<128, 256, 1, 0, 2><<<dim3(64, 8), 256, 0, stream>>>(h_hi, h_lo, wp_1, bf1, t_hi, t_lo, N_NODES);
        gemm_mfma<256, 128, 0, 0, 0><<<dim3(64, 4), 256, 0, stream>>>(t_hi, t_lo, wp_2, bf2, res32, nullptr, N_NODES);
        ln_res_kernel<<<1024, 256, 0, stream>>>(h, res32, g2, b2, h_hi, h_lo);
    }

    gemm_mfma<128, 128, 0, 0, 0><<<dim3(64, 4), 256, 0, stream>>>(h_hi, h_lo, wp_h, nullptr, xt, nullptr, N_NODES);

    // hypergraph phase (atomic-free gathers via CSR)
    hipMemsetAsync(cnt_e, 0, (2 * NEDGE + 2 * N_NODES) * sizeof(int), stream);
    edge_norm_count<<<NNZ_E / 256, 256, 0, stream>>>(edge, nidx, hidx, cnt_e, cnt_n);
    scan2_kernel<<<2, 1024, 0, stream>>>(cnt_e, off_e, cnt_n, off_n);
    fill_csr<<<NNZ_E / 256, 256, 0, stream>>>(nidx, hidx, off_e, off_n, cur_e, cur_n, csr_e, csr_n);
    gather_e<<<NEDGE, 128, 0, stream>>>(off_e, csr_e, xt, e_sc);
    gather_n<<<N_NODES, 128, 0, stream>>>(off_n, csr_n, e_sc, bh, out);
}

// Round 7
// 287.907 us; speedup vs baseline: 3.2274x; 1.0464x over previous
//
#include <hip/hip_runtime.h>
#include <hip/hip_bf16.h>
#include <cstddef>

// Problem constants
#define N_NODES 4096
#define DIM     128
#define NHEAD   2
#define DHEAD   64
#define FFDIM   256
#define NEDGE   2048
#define NNZ_E   65536
#define NSPLIT  8

typedef __attribute__((ext_vector_type(8))) short bf16x8;   // 8 bf16 in 4 VGPRs
typedef __attribute__((ext_vector_type(4))) float f32x4;
typedef unsigned short u16;

__device__ __forceinline__ u16 f2b(float f) {               // rne fp32->bf16
    unsigned u = __float_as_uint(f);
    return (u16)((u + 0x7FFFu + ((u >> 16) & 1u)) >> 16);
}
__device__ __forceinline__ float b2f_bits(u16 h) {
    return __uint_as_float(((unsigned)h) << 16);
}

// ---------------------------------------------------------------------------
// x fp32 -> h fp32 + hi/lo bf16 planes
__global__ void split_x_kernel(const float* __restrict__ x, float* __restrict__ h,
                               u16* __restrict__ hh, u16* __restrict__ hl) {
    int i = blockIdx.x * 256 + threadIdx.x;
    float f = x[i];
    h[i] = f;
    u16 hi = f2b(f);
    hh[i] = hi;
    hl[i] = f2b(f - b2f_bits(hi));
}

// ---------------------------------------------------------------------------
// Pack all 7 weights: W[K][NC] fp32 -> [2 planes][K/8][NC][8] bf16.
__global__ void pack_all(const float* W0, const float* W1, const float* W2,
                         const float* W3, const float* W4, const float* W5,
                         const float* W6,
                         u16* P0, u16* P1, u16* P2, u16* P3, u16* P4, u16* P5, u16* P6) {
    const float* W; u16* P; int K, NC;
    switch (blockIdx.y) {
        case 0: W = W0; P = P0; K = 128; NC = 128; break;
        case 1: W = W1; P = P1; K = 128; NC = 128; break;
        case 2: W = W2; P = P2; K = 128; NC = 128; break;
        case 3: W = W3; P = P3; K = 128; NC = 128; break;
        case 4: W = W4; P = P4; K = 128; NC = 128; break;
        case 5: W = W5; P = P5; K = 128; NC = 256; break;
        default: W = W6; P = P6; K = 256; NC = 128; break;
    }
    int i = blockIdx.x * 256 + threadIdx.x;
    if (i < K * NC) {
        int k = i / NC, n = i % NC;
        float f = W[i];
        u16 h = f2b(f);
        size_t o = ((size_t)(k >> 3) * NC + n) * 8 + (k & 7);
        P[o] = h;
        P[(size_t)K * NC + o] = f2b(f - b2f_bits(h));
    }
}

// ---------------------------------------------------------------------------
// Generic split-bf16 MFMA GEMM (3-term ~fp32). Block 256 = 4 waves, tile 64x32.
// OBF: 0 = fp32 C0; 1 = bf16 C0; 2 = bf16 hi C0 + lo C1.
template<int K, int NC, int ACT, int OBF>
__global__ __launch_bounds__(256) void gemm_mfma(const u16* __restrict__ Ah,
                                                 const u16* __restrict__ Al,
                                                 const u16* __restrict__ Wp,
                                                 const float* __restrict__ bias,
                                                 void* __restrict__ C0,
                                                 void* __restrict__ C1, int M) {
    const int tid = threadIdx.x, w = tid >> 6, lane = tid & 63;
    const int qi = lane & 15, gi = lane >> 4;
    const int row0 = blockIdx.x * 64 + w * 16;
    const int col0 = blockIdx.y * 32;
    const u16* Wlo = Wp + (size_t)K * NC;

    f32x4 acc[2];
    acc[0] = (f32x4){0.f, 0.f, 0.f, 0.f};
    acc[1] = (f32x4){0.f, 0.f, 0.f, 0.f};

#pragma unroll 4
    for (int kc = 0; kc < K / 32; ++kc) {
        const int k0 = kc * 32;
        const size_t ao = (size_t)(row0 + qi) * K + k0 + gi * 8;
        bf16x8 ah = *(const bf16x8*)(Ah + ao);
        bf16x8 al = *(const bf16x8*)(Al + ao);
#pragma unroll
        for (int c = 0; c < 2; ++c) {
            const size_t wo = ((size_t)(k0 / 8 + gi) * NC + col0 + c * 16 + qi) * 8;
            bf16x8 wh = *(const bf16x8*)(Wp + wo);
            bf16x8 wl = *(const bf16x8*)(Wlo + wo);
            acc[c] = __builtin_amdgcn_mfma_f32_16x16x32_bf16(ah, wh, acc[c], 0, 0, 0);
            acc[c] = __builtin_amdgcn_mfma_f32_16x16x32_bf16(al, wh, acc[c], 0, 0, 0);
            acc[c] = __builtin_amdgcn_mfma_f32_16x16x32_bf16(ah, wl, acc[c], 0, 0, 0);
        }
    }

#pragma unroll
    for (int c = 0; c < 2; ++c) {
        const int col = col0 + c * 16 + qi;
        float bv = bias ? bias[col] : 0.f;
#pragma unroll
        for (int r = 0; r < 4; ++r) {
            const int grow = row0 + gi * 4 + r;      // C-layout: col=lane&15, row=quad*4+r
            float v = acc[c][r] + bv;
            if (ACT == 1) v = 1.f / (1.f + __expf(-v));
            size_t idx = (size_t)grow * NC + col;
            if (OBF == 0) ((float*)C0)[idx] = v;
            else if (OBF == 1) ((u16*)C0)[idx] = f2b(v);
            else {
                u16 hi = f2b(v);
                ((u16*)C0)[idx] = hi;
                ((u16*)C1)[idx] = f2b(v - b2f_bits(hi));
            }
        }
    }
}

// ---------------------------------------------------------------------------
// Fused QKV GEMM. Grid (64, 12): sel = y>>2 (0=Q,1=K,2=V), col0 = (y&3)*32.
// Q,K -> [H][N][64] bf16.  V -> written TRANSPOSED to vtb [H][64][N] bf16.
__global__ __launch_bounds__(256) void qkv_mfma(const u16* __restrict__ Ah,
                                                const u16* __restrict__ Al,
                                                const u16* __restrict__ Wq,
                                                const u16* __restrict__ Wk,
                                                const u16* __restrict__ Wv,
                                                const float* __restrict__ bq,
                                                const float* __restrict__ bk,
                                                const float* __restrict__ bv,
                                                u16* __restrict__ qb,
                                                u16* __restrict__ kb,
                                                u16* __restrict__ vtb) {
    const int K = 128, NC = 128;
    const int tid = threadIdx.x, w = tid >> 6, lane = tid & 63;
    const int qi = lane & 15, gi = lane >> 4;
    const int row0 = blockIdx.x * 64 + w * 16;
    const int sel = blockIdx.y >> 2;
    const int col0 = (blockIdx.y & 3) * 32;
    const u16* Wp = (sel == 0) ? Wq : (sel == 1) ? Wk : Wv;
    const float* bias = (sel == 0) ? bq : (sel == 1) ? bk : bv;
    const u16* Wlo = Wp + (size_t)K * NC;

    f32x4 acc[2];
    acc[0] = (f32x4){0.f, 0.f, 0.f, 0.f};
    acc[1] = (f32x4){0.f, 0.f, 0.f, 0.f};

#pragma unroll 4
    for (int kc = 0; kc < K / 32; ++kc) {
        const int k0 = kc * 32;
        const size_t ao = (size_t)(row0 + qi) * K + k0 + gi * 8;
        bf16x8 ah = *(const bf16x8*)(Ah + ao);
        bf16x8 al = *(const bf16x8*)(Al + ao);
#pragma unroll
        for (int c = 0; c < 2; ++c) {
            const size_t wo = ((size_t)(k0 / 8 + gi) * NC + col0 + c * 16 + qi) * 8;
            bf16x8 wh = *(const bf16x8*)(Wp + wo);
            bf16x8 wl = *(const bf16x8*)(Wlo + wo);
            acc[c] = __builtin_amdgcn_mfma_f32_16x16x32_bf16(ah, wh, acc[c], 0, 0, 0);
            acc[c] = __builtin_amdgcn_mfma_f32_16x16x32_bf16(al, wh, acc[c], 0, 0, 0);
            acc[c] = __builtin_amdgcn_mfma_f32_16x16x32_bf16(ah, wl, acc[c], 0, 0, 0);
        }
    }

#pragma unroll
    for (int c = 0; c < 2; ++c) {
        const int col = col0 + c * 16 + qi;
        const int hh = col >> 6, d = col & 63;
        float bv_ = bias[col];
        if (sel < 2) {                 // Q or K: [H][N][64]
            u16* dst = (sel == 0) ? qb : kb;
#pragma unroll
            for (int r = 0; r < 4; ++r) {
                const int grow = row0 + gi * 4 + r;
                dst[((size_t)hh * N_NODES + grow) * 64 + d] = f2b(acc[c][r] + bv_);
            }
        } else {                       // V: transposed [H][64][N], 4 consecutive n
            const int grow0 = row0 + gi * 4;
            ushort4 pw;
            pw.x = f2b(acc[c][0] + bv_);
            pw.y = f2b(acc[c][1] + bv_);
            pw.z = f2b(acc[c][2] + bv_);
            pw.w = f2b(acc[c][3] + bv_);
            *(ushort4*)&vtb[((size_t)hh * 64 + d) * N_NODES + grow0] = pw;
        }
    }
}

// ---------------------------------------------------------------------------
// Split-K MFMA flash attention. Grid (N/64, H, NSPLIT); block 256 = 4 waves.
#define ROWP 72
__global__ __launch_bounds__(256) void attn_mfma(const u16* __restrict__ qb,
                                                 const u16* __restrict__ kb,
                                                 const u16* __restrict__ vtb,
                                                 float* __restrict__ op,
                                                 float* __restrict__ mlm,
                                                 float* __restrict__ mll) {
    __shared__ __align__(16) u16 k_s[64 * ROWP];
    __shared__ __align__(16) u16 vt_s[64 * ROWP];
    __shared__ __align__(16) u16 p_s[4][16 * ROWP];
    const int h = blockIdx.y;
    const int s = blockIdx.z;
    const int row0 = blockIdx.x * 64;
    const int tid = threadIdx.x;
    const int w = tid >> 6, lane = tid & 63;
    const int qi = lane & 15, gi = lane >> 4;
    const float CE = 0.18033688011f;   // 0.125 * log2(e)

    const u16* qrow = qb + ((size_t)h * N_NODES + row0 + w * 16 + qi) * 64 + gi * 8;
    bf16x8 qf0 = *(const bf16x8*)qrow;
    bf16x8 qf1 = *(const bf16x8*)(qrow + 32);

    f32x4 oc[4];
#pragma unroll
    for (int i = 0; i < 4; ++i) oc[i] = (f32x4){0.f, 0.f, 0.f, 0.f};
    float m_run = -INFINITY, l_run = 0.f;

    const u16* kbh = kb + (size_t)h * N_NODES * 64;
    const u16* vth = vtb + (size_t)h * 64 * N_NODES;

    for (int kt = s * (N_NODES / 64 / NSPLIT); kt < (s + 1) * (N_NODES / 64 / NSPLIT); ++kt) {
        const u16* ksrc = kbh + kt * 64 * 64;
#pragma unroll
        for (int i = 0; i < 2; ++i) {
            int c = tid + i * 256;
            int r = c >> 3, ss = c & 7;
            *(uint4*)&k_s[r * ROWP + ss * 8]  = *(const uint4*)(ksrc + c * 8);
            *(uint4*)&vt_s[r * ROWP + ss * 8] = *(const uint4*)(vth + (size_t)r * N_NODES + kt * 64 + ss * 8);
        }
        __syncthreads();

        f32x4 sc[4];
#pragma unroll
        for (int t = 0; t < 4; ++t) {
            const u16* krow = &k_s[(t * 16 + qi) * ROWP + gi * 8];
            bf16x8 ka0 = *(const bf16x8*)krow;
            bf16x8 ka1 = *(const bf16x8*)(krow + 32);
            f32x4 z = (f32x4){0.f, 0.f, 0.f, 0.f};
            z = __builtin_amdgcn_mfma_f32_16x16x32_bf16(ka0, qf0, z, 0, 0, 0);
            sc[t] = __builtin_amdgcn_mfma_f32_16x16x32_bf16(ka1, qf1, z, 0, 0, 0);
        }

        float smax = -INFINITY;
#pragma unroll
        for (int t = 0; t < 4; ++t)
            smax = fmaxf(smax, fmaxf(fmaxf(sc[t][0], sc[t][1]), fmaxf(sc[t][2], sc[t][3])));
        smax = fmaxf(smax, __shfl_xor(smax, 16));
        smax = fmaxf(smax, __shfl_xor(smax, 32));
        float mn = fmaxf(m_run, smax);
        float alpha = exp2f((m_run - mn) * CE);
        m_run = mn;
        float nb = mn * CE;
        float psum = 0.f;
#pragma unroll
        for (int t = 0; t < 4; ++t) {
            ushort4 pw;
            float p0 = exp2f(fmaf(sc[t][0], CE, -nb)); psum += p0; pw.x = f2b(p0);
            float p1 = exp2f(fmaf(sc[t][1], CE, -nb)); psum += p1; pw.y = f2b(p1);
            float p2 = exp2f(fmaf(sc[t][2], CE, -nb)); psum += p2; pw.z = f2b(p2);
            float p3 = exp2f(fmaf(sc[t][3], CE, -nb)); psum += p3; pw.w = f2b(p3);
            *(ushort4*)&p_s[w][qi * ROWP + t * 16 + gi * 4] = pw;
        }
        psum += __shfl_xor(psum, 16);
        psum += __shfl_xor(psum, 32);
        l_run = l_run * alpha + psum;

        float a0 = __shfl(alpha, gi * 4 + 0);
        float a1 = __shfl(alpha, gi * 4 + 1);
        float a2 = __shfl(alpha, gi * 4 + 2);
        float a3 = __shfl(alpha, gi * 4 + 3);
#pragma unroll
        for (int d = 0; d < 4; ++d) {
            oc[d][0] *= a0; oc[d][1] *= a1; oc[d][2] *= a2; oc[d][3] *= a3;
        }

        const u16* prow = &p_s[w][qi * ROWP];
        bf16x8 pa0 = *(const bf16x8*)(prow + gi * 8);
        bf16x8 pa1 = *(const bf16x8*)(prow + 32 + gi * 8);
#pragma unroll
        for (int d = 0; d < 4; ++d) {
            const u16* vrow = &vt_s[(d * 16 + qi) * ROWP + gi * 8];
            bf16x8 vb0 = *(const bf16x8*)vrow;
            bf16x8 vb1 = *(const bf16x8*)(vrow + 32);
            oc[d] = __builtin_amdgcn_mfma_f32_16x16x32_bf16(pa0, vb0, oc[d], 0, 0, 0);
            oc[d] = __builtin_amdgcn_mfma_f32_16x16x32_bf16(pa1, vb1, oc[d], 0, 0, 0);
        }
        __syncthreads();
    }

    float* opd = op + (size_t)s * N_NODES * 128;
#pragma unroll
    for (int d = 0; d < 4; ++d) {
        size_t cb = h * 64 + d * 16 + qi;
        opd[(size_t)(row0 + w * 16 + gi * 4 + 0) * 128 + cb] = oc[d][0];
        opd[(size_t)(row0 + w * 16 + gi * 4 + 1) * 128 + cb] = oc[d][1];
        opd[(size_t)(row0 + w * 16 + gi * 4 + 2) * 128 + cb] = oc[d][2];
        opd[(size_t)(row0 + w * 16 + gi * 4 + 3) * 128 + cb] = oc[d][3];
    }
    if (gi == 0) {
        size_t mi = (size_t)s * NHEAD * N_NODES + (size_t)h * N_NODES + row0 + w * 16 + qi;
        mlm[mi] = m_run;
        mll[mi] = l_run;
    }
}

// Combine NSPLIT partials -> hi/lo bf16 planes (feeds Wo gemm directly)
__global__ __launch_bounds__(256) void attn_combine(const float* __restrict__ op,
                                                    const float* __restrict__ mlm,
                                                    const float* __restrict__ mll,
                                                    u16* __restrict__ ohi,
                                                    u16* __restrict__ olo) {
    const float CE = 0.18033688011f;
    int idx = blockIdx.x * 256 + threadIdx.x;          // N*128
    int n = idx >> 7, c = idx & 127, h = c >> 6;
    size_t mb = (size_t)h * N_NODES + n;
    float m[NSPLIT], l[NSPLIT];
    float mx = -INFINITY;
#pragma unroll
    for (int s = 0; s < NSPLIT; ++s) {
        m[s] = mlm[mb + (size_t)s * NHEAD * N_NODES];
        l[s] = mll[mb + (size_t)s * NHEAD * N_NODES];
        mx = fmaxf(mx, m[s]);
    }
    float L = 0.f, O = 0.f;
#pragma unroll
    for (int s = 0; s < NSPLIT; ++s) {
        float ws = exp2f((m[s] - mx) * CE);
        L += ws * l[s];
        O += ws * op[(size_t)s * N_NODES * 128 + idx];
    }
    float v = O / L;
    u16 hi = f2b(v);
    ohi[idx] = hi;
    olo[idx] = f2b(v - b2f_bits(hi));
}

// ---------------------------------------------------------------------------
// h = LayerNorm(h + res) * g + b; also emits hi/lo bf16 planes.
__global__ __launch_bounds__(256) void ln_res_kernel(float* __restrict__ h,
                                                     const float* __restrict__ res,
                                                     const float* __restrict__ g,
                                                     const float* __restrict__ b,
                                                     u16* __restrict__ hh,
                                                     u16* __restrict__ hl) {
    int wave = threadIdx.x >> 6, lane = threadIdx.x & 63;
    int row = blockIdx.x * 4 + wave;
    size_t base = (size_t)row * 128;
    float x0 = h[base + lane]      + res[base + lane];
    float x1 = h[base + 64 + lane] + res[base + 64 + lane];
    float s  = x0 + x1;
    float sq = x0 * x0 + x1 * x1;
    for (int msk = 32; msk; msk >>= 1) { s += __shfl_xor(s, msk); sq += __shfl_xor(sq, msk); }
    float mean = s * (1.f / 128.f);
    float var  = sq * (1.f / 128.f) - mean * mean;
    float rstd = rsqrtf(var + 1e-5f);
    float y0 = (x0 - mean) * rstd * g[lane]      + b[lane];
    float y1 = (x1 - mean) * rstd * g[lane + 64] + b[lane + 64];
    h[base + lane] = y0;  h[base + 64 + lane] = y1;
    u16 hi0 = f2b(y0), hi1 = f2b(y1);
    hh[base + lane] = hi0;           hh[base + 64 + lane] = hi1;
    hl[base + lane] = f2b(y0 - b2f_bits(hi0));
    hl[base + 64 + lane] = f2b(y1 - b2f_bits(hi1));
}

// ---------------------------------------------------------------------------
// Hypergraph: normalize indices (parallel is64 probe), count+scan in one kernel,
// CSR fill, atomic-free gathers.
__global__ void edge_norm(const int* __restrict__ edge_raw,
                          int* __restrict__ nidx, int* __restrict__ hidx) {
    __shared__ int is64_s;
    if (threadIdx.x < 64) {
        int v = edge_raw[2 * threadIdx.x + 1];
        unsigned long long bal = __ballot(v != 0);
        if (threadIdx.x == 0) is64_s = (bal == 0ull) ? 1 : 0;
    }
    __syncthreads();
    const int is64 = is64_s;
    int i = blockIdx.x * 256 + threadIdx.x;
    if (i < NNZ_E) {
        int ni, he;
        if (is64) { ni = edge_raw[2 * i]; he = edge_raw[2 * NNZ_E + 2 * i]; }
        else      { ni = edge_raw[i];     he = edge_raw[NNZ_E + i]; }
        nidx[i] = ni & (N_NODES - 1);
        hidx[i] = he & (NEDGE - 1);
    }
}

// Block 0: hist+scan hidx over NEDGE bins -> off_e, zero cur_e.
// Block 1: hist+scan nidx over N_NODES bins -> off_n, zero cur_n.
__global__ __launch_bounds__(1024) void count_scan(const int* __restrict__ nidx,
                                                   const int* __restrict__ hidx,
                                                   int* __restrict__ off_e,
                                                   int* __restrict__ off_n,
                                                   int* __restrict__ cur_e,
                                                   int* __restrict__ cur_n) {
    __shared__ int s[N_NODES];
    const int n = (blockIdx.x == 0) ? NEDGE : N_NODES;
    const int* idxarr = (blockIdx.x == 0) ? hidx : nidx;
    int* off = (blockIdx.x == 0) ? off_e : off_n;
    int* cur = (blockIdx.x == 0) ? cur_e : cur_n;
    for (int i = threadIdx.x; i < n; i += 1024) s[i] = 0;
    __syncthreads();
    for (int i = threadIdx.x; i < NNZ_E; i += 1024) atomicAdd(&s[idxarr[i]], 1);
    __syncthreads();
    for (int st = 1; st < n; st <<= 1) {
        int v[4]; int nj = 0;
        for (int i = threadIdx.x; i < n; i += 1024) v[nj++] = (i >= st) ? s[i - st] : 0;
        __syncthreads();
        nj = 0;
        for (int i = threadIdx.x; i < n; i += 1024) s[i] += v[nj++];
        __syncthreads();
    }
    for (int i = threadIdx.x; i < n; i += 1024) { off[i + 1] = s[i]; cur[i] = 0; }
    if (threadIdx.x == 0) off[0] = 0;
}

__global__ void fill_csr(const int* __restrict__ nidx, const int* __restrict__ hidx,
                         const int* __restrict__ off_e, const int* __restrict__ off_n,
                         int* __restrict__ cur_e, int* __restrict__ cur_n,
                         int* __restrict__ csr_e, int* __restrict__ csr_n) {
    int i = blockIdx.x * 256 + threadIdx.x;
    if (i < NNZ_E) {
        int ni = nidx[i], he = hidx[i];
        int p = atomicAdd(&cur_e[he], 1);
        csr_e[off_e[he] + p] = ni;
        int q = atomicAdd(&cur_n[ni], 1);
        csr_n[off_n[ni] + q] = he;
    }
}

// e_sc[he] = (1/deg) * sum_{members} xt[member]
__global__ __launch_bounds__(128) void gather_e(const int* __restrict__ off_e,
                                                const int* __restrict__ csr_e,
                                                const float* __restrict__ xt,
                                                float* __restrict__ e_sc) {
    __shared__ int ms[128];
    const int he = blockIdx.x, d = threadIdx.x;
    const int beg = off_e[he], end = off_e[he + 1];
    float acc = 0.f;
    for (int c = beg; c < end; c += 128) {
        int nl = min(128, end - c);
        if (d < nl) ms[d] = csr_e[c + d];
        __syncthreads();
        for (int j = 0; j < nl; ++j) acc += xt[(size_t)ms[j] * 128 + d];
        __syncthreads();
    }
    float binv = (end > beg) ? 1.f / (float)(end - beg) : 0.f;
    e_sc[(size_t)he * 128 + d] = acc * binv;
}

// out[n] = relu((1/deg) * sum_{incident he} e_sc[he] + bh)
__global__ __launch_bounds__(128) void gather_n(const int* __restrict__ off_n,
                                                const int* __restrict__ csr_n,
                                                const float* __restrict__ e_sc,
                                                const float* __restrict__ bh,
                                                float* __restrict__ out) {
    __shared__ int ms[128];
    const int nn = blockIdx.x, d = threadIdx.x;
    const int beg = off_n[nn], end = off_n[nn + 1];
    float acc = 0.f;
    for (int c = beg; c < end; c += 128) {
        int nl = min(128, end - c);
        if (d < nl) ms[d] = csr_n[c + d];
        __syncthreads();
        for (int j = 0; j < nl; ++j) acc += e_sc[(size_t)ms[j] * 128 + d];
        __syncthreads();
    }
    float dinv = (end > beg) ? 1.f / (float)(end - beg) : 0.f;
    float v = acc * dinv + bh[d];
    out[(size_t)nn * 128 + d] = v > 0.f ? v : 0.f;
}

// ---------------------------------------------------------------------------
extern "C" void kernel_launch(void* const* d_in, const int* in_sizes, int n_in,
                              void* d_out, int out_size, void* d_ws, size_t ws_size,
                              hipStream_t stream) {
    (void)in_sizes; (void)n_in; (void)out_size; (void)ws_size;
    const float* x    = (const float*)d_in[0];
    const int*   edge = (const int*)  d_in[1];
    const float* Wq = (const float*)d_in[2];  const float* bq  = (const float*)d_in[3];
    const float* Wk = (const float*)d_in[4];  const float* bk  = (const float*)d_in[5];
    const float* Wv = (const float*)d_in[6];  const float* bv  = (const float*)d_in[7];
    const float* Wo = (const float*)d_in[8];  const float* bo  = (const float*)d_in[9];
    const float* g1 = (const float*)d_in[10]; const float* b1  = (const float*)d_in[11];
    const float* W1 = (const float*)d_in[12]; const float* bf1 = (const float*)d_in[13];
    const float* W2 = (const float*)d_in[14]; const float* bf2 = (const float*)d_in[15];
    const float* g2 = (const float*)d_in[16]; const float* b2  = (const float*)d_in[17];
    const float* Wh = (const float*)d_in[18]; const float* bh  = (const float*)d_in[19];
    float* out = (float*)d_out;

    // ---- workspace layout (fp32-word offsets), all regions DISJOINT; ~38.9 MB ----
    float* B = (float*)d_ws;
    float* h    = B;                          // [N,128] fp32
    u16*   h_hi = (u16*)(B + 524288);         // [N,128] bf16
    u16*   h_lo = (u16*)(B + 786432);
    u16*   qb   = (u16*)(B + 1048576);        // [H][N][64] bf16
    u16*   kb   = (u16*)(B + 1310720);
    u16*   vtb  = (u16*)(B + 1835008);        // [H][64][N] bf16
    float* op   = B + 2097152;                // [NSPLIT][N][128] fp32 -> end 6291456
    float* mlm  = B + 6291456;                // [NSPLIT][H][N]
    float* mll  = B + 6356992;                // -> end 6422528
    u16*   o_hi = (u16*)(B + 6422528);        // [N,128] bf16
    u16*   o_lo = (u16*)(B + 6684672);
    u16*   t_hi = (u16*)(B + 6946816);        // [N,256] bf16
    u16*   t_lo = (u16*)(B + 7471104);
    float* res32 = B + 7995392;               // [N,128] fp32 -> end 8519680
    u16*   wp_q = (u16*)(B + 8519680);        // packs: 16384 w each (128x128)
    u16*   wp_k = (u16*)(B + 8536064);
    u16*   wp_v = (u16*)(B + 8552448);
    u16*   wp_o = (u16*)(B + 8568832);
    u16*   wp_h = (u16*)(B + 8585216);
    u16*   wp_1 = (u16*)(B + 8601600);        // 128x256: 32768 w
    u16*   wp_2 = (u16*)(B + 8634368);        // 256x128: 32768 w -> end 8667136
    float* xt   = B + 8667136;                // [N,128] fp32 -> end 9191424
    int*   nidx = (int*)(B + 9191424);        // [NNZ]
    int*   hidx = (int*)(B + 9256960);        // [NNZ]
    int*   cur_e = (int*)(B + 9328640);       // [NE]
    int*   cur_n = (int*)(B + 9330688);       // [N]
    int*   off_e = (int*)(B + 9334784);       // [NE+1]
    int*   off_n = (int*)(B + 9336840);       // [N+1]
    int*   csr_e = (int*)(B + 9340944);       // [NNZ]
    int*   csr_n = (int*)(B + 9406480);       // [NNZ]
    float* e_sc  = B + 9472016;               // [NE,128] -> end 9734160

    split_x_kernel<<<2048, 256, 0, stream>>>(x, h, h_hi, h_lo);
    pack_all<<<dim3(128, 7), 256, 0, stream>>>(Wq, Wk, Wv, Wo, Wh, W1, W2,
                                               wp_q, wp_k, wp_v, wp_o, wp_h, wp_1, wp_2);

    for (int layer = 0; layer < 2; ++layer) {
        qkv_mfma<<<dim3(64, 12), 256, 0, stream>>>(h_hi, h_lo, wp_q, wp_k, wp_v,
                                                   bq, bk, bv, qb, kb, vtb);
        attn_mfma<<<dim3(N_NODES / 64, NHEAD, NSPLIT), 256, 0, stream>>>(qb, kb, vtb, op, mlm, mll);
        attn_combine<<<N_NODES * 128 / 256, 256, 0, stream>>>(op, mlm, mll, o_hi, o_lo);
        gemm_mfma<128, 128, 0, 0><<<dim3(64, 4), 256, 0, stream>>>(o_hi, o_lo, wp_o, bo, res32, nullptr, N_NODES);
        ln_res_kernel<<<1024, 256, 0, stream>>>(h, res32, g1, b1, h_hi, h_lo);
        gemm_mfma<128, 256, 1, 2><<<dim3(64, 8), 256, 0, stream>>>(h_hi, h_lo, wp_1, bf1, t_hi, t_lo, N_NODES);
        gemm_mfma<256, 128, 0, 0><<<dim3(64, 4), 256, 0, stream>>>(t_hi, t_lo, wp_2, bf2, res32, nullptr, N_NODES);
        ln_res_kernel<<<1024, 256, 0, stream>>>(h, res32, g2, b2, h_hi, h_lo);
    }

    gemm_mfma<128, 128, 0, 0><<<dim3(64, 4), 256, 0, stream>>>(h_hi, h_lo, wp_h, nullptr, xt, nullptr, N_NODES);

    // hypergraph phase (atomic-free gathers via CSR; no memsets needed)
    edge_norm<<<NNZ_E / 256, 256, 0, stream>>>(edge, nidx, hidx);
    count_scan<<<2, 1024, 0, stream>>>(nidx, hidx, off_e, off_n, cur_e, cur_n);
    fill_csr<<<NNZ_E / 256, 256, 0, stream>>>(nidx, hidx, off_e, off_n, cur_e, cur_n, csr_e, csr_n);
    gather_e<<<NEDGE, 128, 0, stream>>>(off_e, csr_e, xt, e_sc);
    gather_n<<<N_NODES, 128, 0, stream>>>(off_n, csr_n, e_sc, bh, out);
}

// Round 8
// 273.133 us; speedup vs baseline: 3.4020x; 1.0541x over previous
//
#include <hip/hip_runtime.h>
#include <hip/hip_bf16.h>
#include <cstddef>

// Problem constants
#define N_NODES 4096
#define DIM     128
#define NHEAD   2
#define DHEAD   64
#define FFDIM   256
#define NEDGE   2048
#define NNZ_E   65536
#define NSPLIT  8

typedef __attribute__((ext_vector_type(8))) short bf16x8;   // 8 bf16 in 4 VGPRs
typedef __attribute__((ext_vector_type(4))) float f32x4;
typedef unsigned short u16;

__device__ __forceinline__ u16 f2b(float f) {               // rne fp32->bf16
    unsigned u = __float_as_uint(f);
    return (u16)((u + 0x7FFFu + ((u >> 16) & 1u)) >> 16);
}
__device__ __forceinline__ float b2f_bits(u16 h) {
    return __uint_as_float(((unsigned)h) << 16);
}

// ---------------------------------------------------------------------------
// x fp32 -> h fp32 + hi/lo bf16 planes
__global__ void split_x_kernel(const float* __restrict__ x, float* __restrict__ h,
                               u16* __restrict__ hh, u16* __restrict__ hl) {
    int i = blockIdx.x * 256 + threadIdx.x;
    float f = x[i];
    h[i] = f;
    u16 hi = f2b(f);
    hh[i] = hi;
    hl[i] = f2b(f - b2f_bits(hi));
}

// ---------------------------------------------------------------------------
// Pack all 7 weights: W[K][NC] fp32 -> [2 planes][K/8][NC][8] bf16.
__global__ void pack_all(const float* W0, const float* W1, const float* W2,
                         const float* W3, const float* W4, const float* W5,
                         const float* W6,
                         u16* P0, u16* P1, u16* P2, u16* P3, u16* P4, u16* P5, u16* P6) {
    const float* W; u16* P; int K, NC;
    switch (blockIdx.y) {
        case 0: W = W0; P = P0; K = 128; NC = 128; break;
        case 1: W = W1; P = P1; K = 128; NC = 128; break;
        case 2: W = W2; P = P2; K = 128; NC = 128; break;
        case 3: W = W3; P = P3; K = 128; NC = 128; break;
        case 4: W = W4; P = P4; K = 128; NC = 128; break;
        case 5: W = W5; P = P5; K = 128; NC = 256; break;
        default: W = W6; P = P6; K = 256; NC = 128; break;
    }
    int i = blockIdx.x * 256 + threadIdx.x;
    if (i < K * NC) {
        int k = i / NC, n = i % NC;
        float f = W[i];
        u16 h = f2b(f);
        size_t o = ((size_t)(k >> 3) * NC + n) * 8 + (k & 7);
        P[o] = h;
        P[(size_t)K * NC + o] = f2b(f - b2f_bits(h));
    }
}

// ---------------------------------------------------------------------------
// Generic split-bf16 MFMA GEMM (3-term ~fp32). Block 256 = 4 waves, tile 64x32.
// OBF: 0 = fp32 C0; 2 = bf16 hi C0 + lo C1.
template<int K, int NC, int ACT, int OBF>
__global__ __launch_bounds__(256) void gemm_mfma(const u16* __restrict__ Ah,
                                                 const u16* __restrict__ Al,
                                                 const u16* __restrict__ Wp,
                                                 const float* __restrict__ bias,
                                                 void* __restrict__ C0,
                                                 void* __restrict__ C1, int M) {
    const int tid = threadIdx.x, w = tid >> 6, lane = tid & 63;
    const int qi = lane & 15, gi = lane >> 4;
    const int row0 = blockIdx.x * 64 + w * 16;
    const int col0 = blockIdx.y * 32;
    const u16* Wlo = Wp + (size_t)K * NC;

    f32x4 acc[2];
    acc[0] = (f32x4){0.f, 0.f, 0.f, 0.f};
    acc[1] = (f32x4){0.f, 0.f, 0.f, 0.f};

#pragma unroll 4
    for (int kc = 0; kc < K / 32; ++kc) {
        const int k0 = kc * 32;
        const size_t ao = (size_t)(row0 + qi) * K + k0 + gi * 8;
        bf16x8 ah = *(const bf16x8*)(Ah + ao);
        bf16x8 al = *(const bf16x8*)(Al + ao);
#pragma unroll
        for (int c = 0; c < 2; ++c) {
            const size_t wo = ((size_t)(k0 / 8 + gi) * NC + col0 + c * 16 + qi) * 8;
            bf16x8 wh = *(const bf16x8*)(Wp + wo);
            bf16x8 wl = *(const bf16x8*)(Wlo + wo);
            acc[c] = __builtin_amdgcn_mfma_f32_16x16x32_bf16(ah, wh, acc[c], 0, 0, 0);
            acc[c] = __builtin_amdgcn_mfma_f32_16x16x32_bf16(al, wh, acc[c], 0, 0, 0);
            acc[c] = __builtin_amdgcn_mfma_f32_16x16x32_bf16(ah, wl, acc[c], 0, 0, 0);
        }
    }

#pragma unroll
    for (int c = 0; c < 2; ++c) {
        const int col = col0 + c * 16 + qi;
        float bv = bias ? bias[col] : 0.f;
#pragma unroll
        for (int r = 0; r < 4; ++r) {
            const int grow = row0 + gi * 4 + r;      // C-layout: col=lane&15, row=quad*4+r
            float v = acc[c][r] + bv;
            if (ACT == 1) v = 1.f / (1.f + __expf(-v));
            size_t idx = (size_t)grow * NC + col;
            if (OBF == 0) ((float*)C0)[idx] = v;
            else {
                u16 hi = f2b(v);
                ((u16*)C0)[idx] = hi;
                ((u16*)C1)[idx] = f2b(v - b2f_bits(hi));
            }
        }
    }
}

// ---------------------------------------------------------------------------
// Fused QKV GEMM. Grid (64, 12): sel = y>>2 (0=Q,1=K,2=V), col0 = (y&3)*32.
// Q,K -> [H][N][64] bf16.  V -> written TRANSPOSED to vtb [H][64][N] bf16.
__global__ __launch_bounds__(256) void qkv_mfma(const u16* __restrict__ Ah,
                                                const u16* __restrict__ Al,
                                                const u16* __restrict__ Wq,
                                                const u16* __restrict__ Wk,
                                                const u16* __restrict__ Wv,
                                                const float* __restrict__ bq,
                                                const float* __restrict__ bk,
                                                const float* __restrict__ bv,
                                                u16* __restrict__ qb,
                                                u16* __restrict__ kb,
                                                u16* __restrict__ vtb) {
    const int K = 128, NC = 128;
    const int tid = threadIdx.x, w = tid >> 6, lane = tid & 63;
    const int qi = lane & 15, gi = lane >> 4;
    const int row0 = blockIdx.x * 64 + w * 16;
    const int sel = blockIdx.y >> 2;
    const int col0 = (blockIdx.y & 3) * 32;
    const u16* Wp = (sel == 0) ? Wq : (sel == 1) ? Wk : Wv;
    const float* bias = (sel == 0) ? bq : (sel == 1) ? bk : bv;
    const u16* Wlo = Wp + (size_t)K * NC;

    f32x4 acc[2];
    acc[0] = (f32x4){0.f, 0.f, 0.f, 0.f};
    acc[1] = (f32x4){0.f, 0.f, 0.f, 0.f};

#pragma unroll 4
    for (int kc = 0; kc < K / 32; ++kc) {
        const int k0 = kc * 32;
        const size_t ao = (size_t)(row0 + qi) * K + k0 + gi * 8;
        bf16x8 ah = *(const bf16x8*)(Ah + ao);
        bf16x8 al = *(const bf16x8*)(Al + ao);
#pragma unroll
        for (int c = 0; c < 2; ++c) {
            const size_t wo = ((size_t)(k0 / 8 + gi) * NC + col0 + c * 16 + qi) * 8;
            bf16x8 wh = *(const bf16x8*)(Wp + wo);
            bf16x8 wl = *(const bf16x8*)(Wlo + wo);
            acc[c] = __builtin_amdgcn_mfma_f32_16x16x32_bf16(ah, wh, acc[c], 0, 0, 0);
            acc[c] = __builtin_amdgcn_mfma_f32_16x16x32_bf16(al, wh, acc[c], 0, 0, 0);
            acc[c] = __builtin_amdgcn_mfma_f32_16x16x32_bf16(ah, wl, acc[c], 0, 0, 0);
        }
    }

#pragma unroll
    for (int c = 0; c < 2; ++c) {
        const int col = col0 + c * 16 + qi;
        const int hh = col >> 6, d = col & 63;
        float bv_ = bias[col];
        if (sel < 2) {                 // Q or K: [H][N][64]
            u16* dst = (sel == 0) ? qb : kb;
#pragma unroll
            for (int r = 0; r < 4; ++r) {
                const int grow = row0 + gi * 4 + r;
                dst[((size_t)hh * N_NODES + grow) * 64 + d] = f2b(acc[c][r] + bv_);
            }
        } else {                       // V: transposed [H][64][N], 4 consecutive n
            const int grow0 = row0 + gi * 4;
            ushort4 pw;
            pw.x = f2b(acc[c][0] + bv_);
            pw.y = f2b(acc[c][1] + bv_);
            pw.z = f2b(acc[c][2] + bv_);
            pw.w = f2b(acc[c][3] + bv_);
            *(ushort4*)&vtb[((size_t)hh * 64 + d) * N_NODES + grow0] = pw;
        }
    }
}

// ---------------------------------------------------------------------------
// Split-K MFMA flash attention. Grid (N/64, H, NSPLIT); block 256 = 4 waves.
#define ROWP 72
__global__ __launch_bounds__(256) void attn_mfma(const u16* __restrict__ qb,
                                                 const u16* __restrict__ kb,
                                                 const u16* __restrict__ vtb,
                                                 float* __restrict__ op,
                                                 float* __restrict__ mlm,
                                                 float* __restrict__ mll) {
    __shared__ __align__(16) u16 k_s[64 * ROWP];
    __shared__ __align__(16) u16 vt_s[64 * ROWP];
    __shared__ __align__(16) u16 p_s[4][16 * ROWP];
    const int h = blockIdx.y;
    const int s = blockIdx.z;
    const int row0 = blockIdx.x * 64;
    const int tid = threadIdx.x;
    const int w = tid >> 6, lane = tid & 63;
    const int qi = lane & 15, gi = lane >> 4;
    const float CE = 0.18033688011f;   // 0.125 * log2(e)

    const u16* qrow = qb + ((size_t)h * N_NODES + row0 + w * 16 + qi) * 64 + gi * 8;
    bf16x8 qf0 = *(const bf16x8*)qrow;
    bf16x8 qf1 = *(const bf16x8*)(qrow + 32);

    f32x4 oc[4];
#pragma unroll
    for (int i = 0; i < 4; ++i) oc[i] = (f32x4){0.f, 0.f, 0.f, 0.f};
    float m_run = -INFINITY, l_run = 0.f;

    const u16* kbh = kb + (size_t)h * N_NODES * 64;
    const u16* vth = vtb + (size_t)h * 64 * N_NODES;

    for (int kt = s * (N_NODES / 64 / NSPLIT); kt < (s + 1) * (N_NODES / 64 / NSPLIT); ++kt) {
        const u16* ksrc = kbh + kt * 64 * 64;
#pragma unroll
        for (int i = 0; i < 2; ++i) {
            int c = tid + i * 256;
            int r = c >> 3, ss = c & 7;
            *(uint4*)&k_s[r * ROWP + ss * 8]  = *(const uint4*)(ksrc + c * 8);
            *(uint4*)&vt_s[r * ROWP + ss * 8] = *(const uint4*)(vth + (size_t)r * N_NODES + kt * 64 + ss * 8);
        }
        __syncthreads();

        f32x4 sc[4];
#pragma unroll
        for (int t = 0; t < 4; ++t) {
            const u16* krow = &k_s[(t * 16 + qi) * ROWP + gi * 8];
            bf16x8 ka0 = *(const bf16x8*)krow;
            bf16x8 ka1 = *(const bf16x8*)(krow + 32);
            f32x4 z = (f32x4){0.f, 0.f, 0.f, 0.f};
            z = __builtin_amdgcn_mfma_f32_16x16x32_bf16(ka0, qf0, z, 0, 0, 0);
            sc[t] = __builtin_amdgcn_mfma_f32_16x16x32_bf16(ka1, qf1, z, 0, 0, 0);
        }

        float smax = -INFINITY;
#pragma unroll
        for (int t = 0; t < 4; ++t)
            smax = fmaxf(smax, fmaxf(fmaxf(sc[t][0], sc[t][1]), fmaxf(sc[t][2], sc[t][3])));
        smax = fmaxf(smax, __shfl_xor(smax, 16));
        smax = fmaxf(smax, __shfl_xor(smax, 32));
        float mn = fmaxf(m_run, smax);
        float alpha = exp2f((m_run - mn) * CE);
        m_run = mn;
        float nb = mn * CE;
        float psum = 0.f;
#pragma unroll
        for (int t = 0; t < 4; ++t) {
            ushort4 pw;
            float p0 = exp2f(fmaf(sc[t][0], CE, -nb)); psum += p0; pw.x = f2b(p0);
            float p1 = exp2f(fmaf(sc[t][1], CE, -nb)); psum += p1; pw.y = f2b(p1);
            float p2 = exp2f(fmaf(sc[t][2], CE, -nb)); psum += p2; pw.z = f2b(p2);
            float p3 = exp2f(fmaf(sc[t][3], CE, -nb)); psum += p3; pw.w = f2b(p3);
            *(ushort4*)&p_s[w][qi * ROWP + t * 16 + gi * 4] = pw;
        }
        psum += __shfl_xor(psum, 16);
        psum += __shfl_xor(psum, 32);
        l_run = l_run * alpha + psum;

        float a0 = __shfl(alpha, gi * 4 + 0);
        float a1 = __shfl(alpha, gi * 4 + 1);
        float a2 = __shfl(alpha, gi * 4 + 2);
        float a3 = __shfl(alpha, gi * 4 + 3);
#pragma unroll
        for (int d = 0; d < 4; ++d) {
            oc[d][0] *= a0; oc[d][1] *= a1; oc[d][2] *= a2; oc[d][3] *= a3;
        }

        const u16* prow = &p_s[w][qi * ROWP];
        bf16x8 pa0 = *(const bf16x8*)(prow + gi * 8);
        bf16x8 pa1 = *(const bf16x8*)(prow + 32 + gi * 8);
#pragma unroll
        for (int d = 0; d < 4; ++d) {
            const u16* vrow = &vt_s[(d * 16 + qi) * ROWP + gi * 8];
            bf16x8 vb0 = *(const bf16x8*)vrow;
            bf16x8 vb1 = *(const bf16x8*)(vrow + 32);
            oc[d] = __builtin_amdgcn_mfma_f32_16x16x32_bf16(pa0, vb0, oc[d], 0, 0, 0);
            oc[d] = __builtin_amdgcn_mfma_f32_16x16x32_bf16(pa1, vb1, oc[d], 0, 0, 0);
        }
        __syncthreads();
    }

    float* opd = op + (size_t)s * N_NODES * 128;
#pragma unroll
    for (int d = 0; d < 4; ++d) {
        size_t cb = h * 64 + d * 16 + qi;
        opd[(size_t)(row0 + w * 16 + gi * 4 + 0) * 128 + cb] = oc[d][0];
        opd[(size_t)(row0 + w * 16 + gi * 4 + 1) * 128 + cb] = oc[d][1];
        opd[(size_t)(row0 + w * 16 + gi * 4 + 2) * 128 + cb] = oc[d][2];
        opd[(size_t)(row0 + w * 16 + gi * 4 + 3) * 128 + cb] = oc[d][3];
    }
    if (gi == 0) {
        size_t mi = (size_t)s * NHEAD * N_NODES + (size_t)h * N_NODES + row0 + w * 16 + qi;
        mlm[mi] = m_run;
        mll[mi] = l_run;
    }
}

// ---------------------------------------------------------------------------
// FUSED: split-K combine -> Wo GEMM -> +bias -> +residual(h) -> LayerNorm ->
// h fp32 + hi/lo planes.  Tile 16 rows x 128 cols, grid N/16 = 256 blocks.
#define ROWA 136   // 16x128 LDS planes padded: 272 B row = 17*16 B (2-way banks)
__global__ __launch_bounds__(256) void gemm_wo_ln(const float* __restrict__ op,
                                                  const float* __restrict__ mlm,
                                                  const float* __restrict__ mll,
                                                  const u16* __restrict__ Wp,
                                                  const float* __restrict__ bo,
                                                  float* __restrict__ h,
                                                  const float* __restrict__ g,
                                                  const float* __restrict__ b,
                                                  u16* __restrict__ hh,
                                                  u16* __restrict__ hl) {
    const int K = 128, NC = 128;
    __shared__ __align__(16) u16 a_hi[16 * ROWA];
    __shared__ __align__(16) u16 a_lo[16 * ROWA];
    __shared__ float ws_s[NSPLIT][32];     // [split][row*2+head]
    __shared__ float Linv_s[32];
    __shared__ float wsum[4][16], wsq[4][16];
    const float CE = 0.18033688011f;
    const int tid = threadIdx.x, w = tid >> 6, lane = tid & 63;
    const int qi = lane & 15, gi = lane >> 4;
    const int row0 = blockIdx.x * 16;
    const u16* Wlo = Wp + (size_t)K * NC;

    // phase A: per (row, head) combine weights
    if (tid < 32) {
        int r = tid >> 1, hd = tid & 1;
        size_t mb = (size_t)hd * N_NODES + row0 + r;
        float m[NSPLIT], l[NSPLIT], mx = -INFINITY;
#pragma unroll
        for (int s = 0; s < NSPLIT; ++s) {
            m[s] = mlm[mb + (size_t)s * NHEAD * N_NODES];
            l[s] = mll[mb + (size_t)s * NHEAD * N_NODES];
            mx = fmaxf(mx, m[s]);
        }
        float L = 0.f;
#pragma unroll
        for (int s = 0; s < NSPLIT; ++s) {
            float ws = exp2f((m[s] - mx) * CE);
            ws_s[s][tid] = ws;
            L += ws * l[s];
        }
        Linv_s[tid] = 1.f / L;
    }
    __syncthreads();

    // phase B: combine partial O -> LDS bf16 hi/lo A-planes
    for (int e = tid; e < 16 * 128; e += 256) {
        int r = e >> 7, c = e & 127, hd = c >> 6;
        size_t idx = (size_t)(row0 + r) * 128 + c;
        float O = 0.f;
#pragma unroll
        for (int s = 0; s < NSPLIT; ++s)
            O += ws_s[s][r * 2 + hd] * op[(size_t)s * N_NODES * 128 + idx];
        float v = O * Linv_s[r * 2 + hd];
        u16 hi = f2b(v);
        a_hi[r * ROWA + c] = hi;
        a_lo[r * ROWA + c] = f2b(v - b2f_bits(hi));
    }
    __syncthreads();

    // phase C: MFMA. wave w owns cols w*32..+31; A rows shared from LDS.
    f32x4 acc[2];
    acc[0] = (f32x4){0.f, 0.f, 0.f, 0.f};
    acc[1] = (f32x4){0.f, 0.f, 0.f, 0.f};
    const int col0 = w * 32;
#pragma unroll
    for (int kc = 0; kc < 4; ++kc) {
        const int k0 = kc * 32;
        bf16x8 ah = *(const bf16x8*)&a_hi[qi * ROWA + k0 + gi * 8];
        bf16x8 al = *(const bf16x8*)&a_lo[qi * ROWA + k0 + gi * 8];
#pragma unroll
        for (int c = 0; c < 2; ++c) {
            const size_t wo = ((size_t)(k0 / 8 + gi) * NC + col0 + c * 16 + qi) * 8;
            bf16x8 wh = *(const bf16x8*)(Wp + wo);
            bf16x8 wl = *(const bf16x8*)(Wlo + wo);
            acc[c] = __builtin_amdgcn_mfma_f32_16x16x32_bf16(ah, wh, acc[c], 0, 0, 0);
            acc[c] = __builtin_amdgcn_mfma_f32_16x16x32_bf16(al, wh, acc[c], 0, 0, 0);
            acc[c] = __builtin_amdgcn_mfma_f32_16x16x32_bf16(ah, wl, acc[c], 0, 0, 0);
        }
    }

    // phase D: +bias +residual, per-row LN stats (shuffle + cross-wave LDS)
    float y[2][4];
    float rs[4], rq[4];
#pragma unroll
    for (int r = 0; r < 4; ++r) { rs[r] = 0.f; rq[r] = 0.f; }
#pragma unroll
    for (int c = 0; c < 2; ++c) {
        const int col = col0 + c * 16 + qi;
        float bv = bo[col];
#pragma unroll
        for (int r = 0; r < 4; ++r) {
            const int grow = row0 + gi * 4 + r;
            float v = acc[c][r] + bv + h[(size_t)grow * 128 + col];
            y[c][r] = v;
            rs[r] += v;
            rq[r] += v * v;
        }
    }
#pragma unroll
    for (int r = 0; r < 4; ++r) {
        for (int msk = 1; msk < 16; msk <<= 1) {
            rs[r] += __shfl_xor(rs[r], msk);
            rq[r] += __shfl_xor(rq[r], msk);
        }
    }
    if (qi == 0) {
#pragma unroll
        for (int r = 0; r < 4; ++r) { wsum[w][gi * 4 + r] = rs[r]; wsq[w][gi * 4 + r] = rq[r]; }
    }
    __syncthreads();
#pragma unroll
    for (int r = 0; r < 4; ++r) {
        const int lr = gi * 4 + r;
        float ts = wsum[0][lr] + wsum[1][lr] + wsum[2][lr] + wsum[3][lr];
        float tq = wsq[0][lr] + wsq[1][lr] + wsq[2][lr] + wsq[3][lr];
        float mean = ts * (1.f / 128.f);
        float var  = tq * (1.f / 128.f) - mean * mean;
        float rstd = rsqrtf(var + 1e-5f);
        const int grow = row0 + lr;
#pragma unroll
        for (int c = 0; c < 2; ++c) {
            const int col = col0 + c * 16 + qi;
            float yn = (y[c][r] - mean) * rstd * g[col] + b[col];
            size_t idx = (size_t)grow * 128 + col;
            h[idx] = yn;
            u16 hi = f2b(yn);
            hh[idx] = hi;
            hl[idx] = f2b(yn - b2f_bits(hi));
        }
    }
}

// ---------------------------------------------------------------------------
// FUSED: W2 GEMM (K=256, A = t planes) -> +bias -> +residual(h) -> LayerNorm.
// Tile 16 rows x 128 cols, grid 256 blocks.
__global__ __launch_bounds__(256) void gemm_w2_ln(const u16* __restrict__ Ah,
                                                  const u16* __restrict__ Al,
                                                  const u16* __restrict__ Wp,
                                                  const float* __restrict__ bf2,
                                                  float* __restrict__ h,
                                                  const float* __restrict__ g,
                                                  const float* __restrict__ b,
                                                  u16* __restrict__ hh,
                                                  u16* __restrict__ hl) {
    const int K = 256, NC = 128;
    __shared__ float wsum[4][16], wsq[4][16];
    const int tid = threadIdx.x, w = tid >> 6, lane = tid & 63;
    const int qi = lane & 15, gi = lane >> 4;
    const int row0 = blockIdx.x * 16;
    const int col0 = w * 32;
    const u16* Wlo = Wp + (size_t)K * NC;

    f32x4 acc[2];
    acc[0] = (f32x4){0.f, 0.f, 0.f, 0.f};
    acc[1] = (f32x4){0.f, 0.f, 0.f, 0.f};
#pragma unroll 4
    for (int kc = 0; kc < K / 32; ++kc) {
        const int k0 = kc * 32;
        const size_t ao = (size_t)(row0 + qi) * K + k0 + gi * 8;
        bf16x8 ah = *(const bf16x8*)(Ah + ao);
        bf16x8 al = *(const bf16x8*)(Al + ao);
#pragma unroll
        for (int c = 0; c < 2; ++c) {
            const size_t wo = ((size_t)(k0 / 8 + gi) * NC + col0 + c * 16 + qi) * 8;
            bf16x8 wh = *(const bf16x8*)(Wp + wo);
            bf16x8 wl = *(const bf16x8*)(Wlo + wo);
            acc[c] = __builtin_amdgcn_mfma_f32_16x16x32_bf16(ah, wh, acc[c], 0, 0, 0);
            acc[c] = __builtin_amdgcn_mfma_f32_16x16x32_bf16(al, wh, acc[c], 0, 0, 0);
            acc[c] = __builtin_amdgcn_mfma_f32_16x16x32_bf16(ah, wl, acc[c], 0, 0, 0);
        }
    }

    float y[2][4];
    float rs[4], rq[4];
#pragma unroll
    for (int r = 0; r < 4; ++r) { rs[r] = 0.f; rq[r] = 0.f; }
#pragma unroll
    for (int c = 0; c < 2; ++c) {
        const int col = col0 + c * 16 + qi;
        float bv = bf2[col];
#pragma unroll
        for (int r = 0; r < 4; ++r) {
            const int grow = row0 + gi * 4 + r;
            float v = acc[c][r] + bv + h[(size_t)grow * 128 + col];
            y[c][r] = v;
            rs[r] += v;
            rq[r] += v * v;
        }
    }
#pragma unroll
    for (int r = 0; r < 4; ++r) {
        for (int msk = 1; msk < 16; msk <<= 1) {
            rs[r] += __shfl_xor(rs[r], msk);
            rq[r] += __shfl_xor(rq[r], msk);
        }
    }
    if (qi == 0) {
#pragma unroll
        for (int r = 0; r < 4; ++r) { wsum[w][gi * 4 + r] = rs[r]; wsq[w][gi * 4 + r] = rq[r]; }
    }
    __syncthreads();
#pragma unroll
    for (int r = 0; r < 4; ++r) {
        const int lr = gi * 4 + r;
        float ts = wsum[0][lr] + wsum[1][lr] + wsum[2][lr] + wsum[3][lr];
        float tq = wsq[0][lr] + wsq[1][lr] + wsq[2][lr] + wsq[3][lr];
        float mean = ts * (1.f / 128.f);
        float var  = tq * (1.f / 128.f) - mean * mean;
        float rstd = rsqrtf(var + 1e-5f);
        const int grow = row0 + lr;
#pragma unroll
        for (int c = 0; c < 2; ++c) {
            const int col = col0 + c * 16 + qi;
            float yn = (y[c][r] - mean) * rstd * g[col] + b[col];
            size_t idx = (size_t)grow * 128 + col;
            h[idx] = yn;
            u16 hi = f2b(yn);
            hh[idx] = hi;
            hl[idx] = f2b(yn - b2f_bits(hi));
        }
    }
}

// ---------------------------------------------------------------------------
// Hypergraph: normalize indices, count+scan, CSR fill, atomic-free gathers.
__global__ void edge_norm(const int* __restrict__ edge_raw,
                          int* __restrict__ nidx, int* __restrict__ hidx) {
    __shared__ int is64_s;
    if (threadIdx.x < 64) {
        int v = edge_raw[2 * threadIdx.x + 1];
        unsigned long long bal = __ballot(v != 0);
        if (threadIdx.x == 0) is64_s = (bal == 0ull) ? 1 : 0;
    }
    __syncthreads();
    const int is64 = is64_s;
    int i = blockIdx.x * 256 + threadIdx.x;
    if (i < NNZ_E) {
        int ni, he;
        if (is64) { ni = edge_raw[2 * i]; he = edge_raw[2 * NNZ_E + 2 * i]; }
        else      { ni = edge_raw[i];     he = edge_raw[NNZ_E + i]; }
        nidx[i] = ni & (N_NODES - 1);
        hidx[i] = he & (NEDGE - 1);
    }
}

__global__ __launch_bounds__(1024) void count_scan(const int* __restrict__ nidx,
                                                   const int* __restrict__ hidx,
                                                   int* __restrict__ off_e,
                                                   int* __restrict__ off_n,
                                                   int* __restrict__ cur_e,
                                                   int* __restrict__ cur_n) {
    __shared__ int s[N_NODES];
    const int n = (blockIdx.x == 0) ? NEDGE : N_NODES;
    const int* idxarr = (blockIdx.x == 0) ? hidx : nidx;
    int* off = (blockIdx.x == 0) ? off_e : off_n;
    int* cur = (blockIdx.x == 0) ? cur_e : cur_n;
    for (int i = threadIdx.x; i < n; i += 1024) s[i] = 0;
    __syncthreads();
    for (int i = threadIdx.x; i < NNZ_E; i += 1024) atomicAdd(&s[idxarr[i]], 1);
    __syncthreads();
    for (int st = 1; st < n; st <<= 1) {
        int v[4]; int nj = 0;
        for (int i = threadIdx.x; i < n; i += 1024) v[nj++] = (i >= st) ? s[i - st] : 0;
        __syncthreads();
        nj = 0;
        for (int i = threadIdx.x; i < n; i += 1024) s[i] += v[nj++];
        __syncthreads();
    }
    for (int i = threadIdx.x; i < n; i += 1024) { off[i + 1] = s[i]; cur[i] = 0; }
    if (threadIdx.x == 0) off[0] = 0;
}

__global__ void fill_csr(const int* __restrict__ nidx, const int* __restrict__ hidx,
                         const int* __restrict__ off_e, const int* __restrict__ off_n,
                         int* __restrict__ cur_e, int* __restrict__ cur_n,
                         int* __restrict__ csr_e, int* __restrict__ csr_n) {
    int i = blockIdx.x * 256 + threadIdx.x;
    if (i < NNZ_E) {
        int ni = nidx[i], he = hidx[i];
        int p = atomicAdd(&cur_e[he], 1);
        csr_e[off_e[he] + p] = ni;
        int q = atomicAdd(&cur_n[ni], 1);
        csr_n[off_n[ni] + q] = he;
    }
}

__global__ __launch_bounds__(128) void gather_e(const int* __restrict__ off_e,
                                                const int* __restrict__ csr_e,
                                                const float* __restrict__ xt,
                                                float* __restrict__ e_sc) {
    __shared__ int ms[128];
    const int he = blockIdx.x, d = threadIdx.x;
    const int beg = off_e[he], end = off_e[he + 1];
    float acc = 0.f;
    for (int c = beg; c < end; c += 128) {
        int nl = min(128, end - c);
        if (d < nl) ms[d] = csr_e[c + d];
        __syncthreads();
        for (int j = 0; j < nl; ++j) acc += xt[(size_t)ms[j] * 128 + d];
        __syncthreads();
    }
    float binv = (end > beg) ? 1.f / (float)(end - beg) : 0.f;
    e_sc[(size_t)he * 128 + d] = acc * binv;
}

__global__ __launch_bounds__(128) void gather_n(const int* __restrict__ off_n,
                                                const int* __restrict__ csr_n,
                                                const float* __restrict__ e_sc,
                                                const float* __restrict__ bh,
                                                float* __restrict__ out) {
    __shared__ int ms[128];
    const int nn = blockIdx.x, d = threadIdx.x;
    const int beg = off_n[nn], end = off_n[nn + 1];
    float acc = 0.f;
    for (int c = beg; c < end; c += 128) {
        int nl = min(128, end - c);
        if (d < nl) ms[d] = csr_n[c + d];
        __syncthreads();
        for (int j = 0; j < nl; ++j) acc += e_sc[(size_t)ms[j] * 128 + d];
        __syncthreads();
    }
    float dinv = (end > beg) ? 1.f / (float)(end - beg) : 0.f;
    float v = acc * dinv + bh[d];
    out[(size_t)nn * 128 + d] = v > 0.f ? v : 0.f;
}

// ---------------------------------------------------------------------------
extern "C" void kernel_launch(void* const* d_in, const int* in_sizes, int n_in,
                              void* d_out, int out_size, void* d_ws, size_t ws_size,
                              hipStream_t stream) {
    (void)in_sizes; (void)n_in; (void)out_size; (void)ws_size;
    const float* x    = (const float*)d_in[0];
    const int*   edge = (const int*)  d_in[1];
    const float* Wq = (const float*)d_in[2];  const float* bq  = (const float*)d_in[3];
    const float* Wk = (const float*)d_in[4];  const float* bk  = (const float*)d_in[5];
    const float* Wv = (const float*)d_in[6];  const float* bv  = (const float*)d_in[7];
    const float* Wo = (const float*)d_in[8];  const float* bo  = (const float*)d_in[9];
    const float* g1 = (const float*)d_in[10]; const float* b1  = (const float*)d_in[11];
    const float* W1 = (const float*)d_in[12]; const float* bf1 = (const float*)d_in[13];
    const float* W2 = (const float*)d_in[14]; const float* bf2 = (const float*)d_in[15];
    const float* g2 = (const float*)d_in[16]; const float* b2  = (const float*)d_in[17];
    const float* Wh = (const float*)d_in[18]; const float* bh  = (const float*)d_in[19];
    float* out = (float*)d_out;

    // ---- workspace layout (fp32-word offsets), all regions DISJOINT ----
    float* B = (float*)d_ws;
    float* h    = B;                          // [N,128] fp32
    u16*   h_hi = (u16*)(B + 524288);         // [N,128] bf16
    u16*   h_lo = (u16*)(B + 786432);
    u16*   qb   = (u16*)(B + 1048576);        // [H][N][64] bf16
    u16*   kb   = (u16*)(B + 1310720);
    u16*   vtb  = (u16*)(B + 1835008);        // [H][64][N] bf16
    float* op   = B + 2097152;                // [NSPLIT][N][128] fp32 -> end 6291456
    float* mlm  = B + 6291456;                // [NSPLIT][H][N]
    float* mll  = B + 6356992;                // -> end 6422528
    u16*   t_hi = (u16*)(B + 6946816);        // [N,256] bf16
    u16*   t_lo = (u16*)(B + 7471104);
    u16*   wp_q = (u16*)(B + 8519680);        // packs: 16384 w each (128x128)
    u16*   wp_k = (u16*)(B + 8536064);
    u16*   wp_v = (u16*)(B + 8552448);
    u16*   wp_o = (u16*)(B + 8568832);
    u16*   wp_h = (u16*)(B + 8585216);
    u16*   wp_1 = (u16*)(B + 8601600);        // 128x256: 32768 w
    u16*   wp_2 = (u16*)(B + 8634368);        // 256x128: 32768 w -> end 8667136
    float* xt   = B + 8667136;                // [N,128] fp32 -> end 9191424
    int*   nidx = (int*)(B + 9191424);        // [NNZ]
    int*   hidx = (int*)(B + 9256960);        // [NNZ]
    int*   cur_e = (int*)(B + 9328640);       // [NE]
    int*   cur_n = (int*)(B + 9330688);       // [N]
    int*   off_e = (int*)(B + 9334784);       // [NE+1]
    int*   off_n = (int*)(B + 9336840);       // [N+1]
    int*   csr_e = (int*)(B + 9340944);       // [NNZ]
    int*   csr_n = (int*)(B + 9406480);       // [NNZ]
    float* e_sc  = B + 9472016;               // [NE,128] -> end 9734160

    split_x_kernel<<<2048, 256, 0, stream>>>(x, h, h_hi, h_lo);
    pack_all<<<dim3(128, 7), 256, 0, stream>>>(Wq, Wk, Wv, Wo, Wh, W1, W2,
                                               wp_q, wp_k, wp_v, wp_o, wp_h, wp_1, wp_2);

    for (int layer = 0; layer < 2; ++layer) {
        qkv_mfma<<<dim3(64, 12), 256, 0, stream>>>(h_hi, h_lo, wp_q, wp_k, wp_v,
                                                   bq, bk, bv, qb, kb, vtb);
        attn_mfma<<<dim3(N_NODES / 64, NHEAD, NSPLIT), 256, 0, stream>>>(qb, kb, vtb, op, mlm, mll);
        gemm_wo_ln<<<N_NODES / 16, 256, 0, stream>>>(op, mlm, mll, wp_o, bo,
                                                     h, g1, b1, h_hi, h_lo);
        gemm_mfma<128, 256, 1, 2><<<dim3(64, 8), 256, 0, stream>>>(h_hi, h_lo, wp_1, bf1, t_hi, t_lo, N_NODES);
        gemm_w2_ln<<<N_NODES / 16, 256, 0, stream>>>(t_hi, t_lo, wp_2, bf2,
                                                     h, g2, b2, h_hi, h_lo);
    }

    gemm_mfma<128, 128, 0, 0><<<dim3(64, 4), 256, 0, stream>>>(h_hi, h_lo, wp_h, nullptr, xt, nullptr, N_NODES);

    // hypergraph phase (atomic-free gathers via CSR)
    edge_norm<<<NNZ_E / 256, 256, 0, stream>>>(edge, nidx, hidx);
    count_scan<<<2, 1024, 0, stream>>>(nidx, hidx, off_e, off_n, cur_e, cur_n);
    fill_csr<<<NNZ_E / 256, 256, 0, stream>>>(nidx, hidx, off_e, off_n, cur_e, cur_n, csr_e, csr_n);
    gather_e<<<NEDGE, 128, 0, stream>>>(off_e, csr_e, xt, e_sc);
    gather_n<<<N_NODES, 128, 0, stream>>>(off_n, csr_n, e_sc, bh, out);
}

// Round 9
// 268.040 us; speedup vs baseline: 3.4666x; 1.0190x over previous
//
#include <hip/hip_runtime.h>
#include <hip/hip_bf16.h>
#include <cstddef>

// Problem constants
#define N_NODES 4096
#define DIM     128
#define NHEAD   2
#define DHEAD   64
#define FFDIM   256
#define NEDGE   2048
#define NNZ_E   65536
#define NSPLIT  8

typedef __attribute__((ext_vector_type(8))) short bf16x8;   // 8 bf16 in 4 VGPRs
typedef __attribute__((ext_vector_type(4))) float f32x4;
typedef unsigned short u16;

__device__ __forceinline__ u16 f2b(float f) {               // rne fp32->bf16
    unsigned u = __float_as_uint(f);
    return (u16)((u + 0x7FFFu + ((u >> 16) & 1u)) >> 16);
}
__device__ __forceinline__ float b2f_bits(u16 h) {
    return __uint_as_float(((unsigned)h) << 16);
}

// ---------------------------------------------------------------------------
// prep: blocks [0,2048) split x into h + hi/lo planes; blocks [2048,2944) pack
// the 7 weights into [2 planes][K/8][NC][8] bf16 fragment layout.
__global__ void prep(const float* __restrict__ x, float* __restrict__ h,
                     u16* __restrict__ hh, u16* __restrict__ hl,
                     const float* W0, const float* W1, const float* W2,
                     const float* W3, const float* W4, const float* W5,
                     const float* W6,
                     u16* P0, u16* P1, u16* P2, u16* P3, u16* P4, u16* P5, u16* P6) {
    const int bx = blockIdx.x;
    if (bx < 2048) {
        int i = bx * 256 + threadIdx.x;
        float f = x[i];
        h[i] = f;
        u16 hi = f2b(f);
        hh[i] = hi;
        hl[i] = f2b(f - b2f_bits(hi));
        return;
    }
    const int p = bx - 2048;
    const int sel = p >> 7;
    const float* W; u16* P; int K, NC;
    switch (sel) {
        case 0: W = W0; P = P0; K = 128; NC = 128; break;
        case 1: W = W1; P = P1; K = 128; NC = 128; break;
        case 2: W = W2; P = P2; K = 128; NC = 128; break;
        case 3: W = W3; P = P3; K = 128; NC = 128; break;
        case 4: W = W4; P = P4; K = 128; NC = 128; break;
        case 5: W = W5; P = P5; K = 128; NC = 256; break;
        default: W = W6; P = P6; K = 256; NC = 128; break;
    }
    int i = (p & 127) * 256 + threadIdx.x;
    if (i < K * NC) {
        int k = i / NC, n = i % NC;
        float f = W[i];
        u16 hb = f2b(f);
        size_t o = ((size_t)(k >> 3) * NC + n) * 8 + (k & 7);
        P[o] = hb;
        P[(size_t)K * NC + o] = f2b(f - b2f_bits(hb));
    }
}

// ---------------------------------------------------------------------------
// Generic split-bf16 MFMA GEMM (3-term ~fp32). Block 256 = 4 waves, tile 64x32.
template<int K, int NC>
__global__ __launch_bounds__(256) void gemm_mfma(const u16* __restrict__ Ah,
                                                 const u16* __restrict__ Al,
                                                 const u16* __restrict__ Wp,
                                                 float* __restrict__ C0) {
    const int tid = threadIdx.x, w = tid >> 6, lane = tid & 63;
    const int qi = lane & 15, gi = lane >> 4;
    const int row0 = blockIdx.x * 64 + w * 16;
    const int col0 = blockIdx.y * 32;
    const u16* Wlo = Wp + (size_t)K * NC;

    f32x4 acc[2];
    acc[0] = (f32x4){0.f, 0.f, 0.f, 0.f};
    acc[1] = (f32x4){0.f, 0.f, 0.f, 0.f};

#pragma unroll 4
    for (int kc = 0; kc < K / 32; ++kc) {
        const int k0 = kc * 32;
        const size_t ao = (size_t)(row0 + qi) * K + k0 + gi * 8;
        bf16x8 ah = *(const bf16x8*)(Ah + ao);
        bf16x8 al = *(const bf16x8*)(Al + ao);
#pragma unroll
        for (int c = 0; c < 2; ++c) {
            const size_t wo = ((size_t)(k0 / 8 + gi) * NC + col0 + c * 16 + qi) * 8;
            bf16x8 wh = *(const bf16x8*)(Wp + wo);
            bf16x8 wl = *(const bf16x8*)(Wlo + wo);
            acc[c] = __builtin_amdgcn_mfma_f32_16x16x32_bf16(ah, wh, acc[c], 0, 0, 0);
            acc[c] = __builtin_amdgcn_mfma_f32_16x16x32_bf16(al, wh, acc[c], 0, 0, 0);
            acc[c] = __builtin_amdgcn_mfma_f32_16x16x32_bf16(ah, wl, acc[c], 0, 0, 0);
        }
    }

#pragma unroll
    for (int c = 0; c < 2; ++c) {
        const int col = col0 + c * 16 + qi;
#pragma unroll
        for (int r = 0; r < 4; ++r) {
            const int grow = row0 + gi * 4 + r;
            C0[(size_t)grow * NC + col] = acc[c][r];
        }
    }
}

// ---------------------------------------------------------------------------
// Fused QKV GEMM. Grid (64, 12): sel = y>>2 (0=Q,1=K,2=V), col0 = (y&3)*32.
// Q,K -> [H][N][64] bf16.  V -> written TRANSPOSED to vtb [H][64][N] bf16.
__global__ __launch_bounds__(256) void qkv_mfma(const u16* __restrict__ Ah,
                                                const u16* __restrict__ Al,
                                                const u16* __restrict__ Wq,
                                                const u16* __restrict__ Wk,
                                                const u16* __restrict__ Wv,
                                                const float* __restrict__ bq,
                                                const float* __restrict__ bk,
                                                const float* __restrict__ bv,
                                                u16* __restrict__ qb,
                                                u16* __restrict__ kb,
                                                u16* __restrict__ vtb) {
    const int K = 128, NC = 128;
    const int tid = threadIdx.x, w = tid >> 6, lane = tid & 63;
    const int qi = lane & 15, gi = lane >> 4;
    const int row0 = blockIdx.x * 64 + w * 16;
    const int sel = blockIdx.y >> 2;
    const int col0 = (blockIdx.y & 3) * 32;
    const u16* Wp = (sel == 0) ? Wq : (sel == 1) ? Wk : Wv;
    const float* bias = (sel == 0) ? bq : (sel == 1) ? bk : bv;
    const u16* Wlo = Wp + (size_t)K * NC;

    f32x4 acc[2];
    acc[0] = (f32x4){0.f, 0.f, 0.f, 0.f};
    acc[1] = (f32x4){0.f, 0.f, 0.f, 0.f};

#pragma unroll 4
    for (int kc = 0; kc < K / 32; ++kc) {
        const int k0 = kc * 32;
        const size_t ao = (size_t)(row0 + qi) * K + k0 + gi * 8;
        bf16x8 ah = *(const bf16x8*)(Ah + ao);
        bf16x8 al = *(const bf16x8*)(Al + ao);
#pragma unroll
        for (int c = 0; c < 2; ++c) {
            const size_t wo = ((size_t)(k0 / 8 + gi) * NC + col0 + c * 16 + qi) * 8;
            bf16x8 wh = *(const bf16x8*)(Wp + wo);
            bf16x8 wl = *(const bf16x8*)(Wlo + wo);
            acc[c] = __builtin_amdgcn_mfma_f32_16x16x32_bf16(ah, wh, acc[c], 0, 0, 0);
            acc[c] = __builtin_amdgcn_mfma_f32_16x16x32_bf16(al, wh, acc[c], 0, 0, 0);
            acc[c] = __builtin_amdgcn_mfma_f32_16x16x32_bf16(ah, wl, acc[c], 0, 0, 0);
        }
    }

#pragma unroll
    for (int c = 0; c < 2; ++c) {
        const int col = col0 + c * 16 + qi;
        const int hh = col >> 6, d = col & 63;
        float bv_ = bias[col];
        if (sel < 2) {                 // Q or K: [H][N][64]
            u16* dst = (sel == 0) ? qb : kb;
#pragma unroll
            for (int r = 0; r < 4; ++r) {
                const int grow = row0 + gi * 4 + r;
                dst[((size_t)hh * N_NODES + grow) * 64 + d] = f2b(acc[c][r] + bv_);
            }
        } else {                       // V: transposed [H][64][N], 4 consecutive n
            const int grow0 = row0 + gi * 4;
            ushort4 pw;
            pw.x = f2b(acc[c][0] + bv_);
            pw.y = f2b(acc[c][1] + bv_);
            pw.z = f2b(acc[c][2] + bv_);
            pw.w = f2b(acc[c][3] + bv_);
            *(ushort4*)&vtb[((size_t)hh * 64 + d) * N_NODES + grow0] = pw;
        }
    }
}

// ---------------------------------------------------------------------------
// Split-K MFMA flash attention. Grid (N/64, H, NSPLIT); block 256 = 4 waves.
#define ROWP 72
__global__ __launch_bounds__(256) void attn_mfma(const u16* __restrict__ qb,
                                                 const u16* __restrict__ kb,
                                                 const u16* __restrict__ vtb,
                                                 float* __restrict__ op,
                                                 float* __restrict__ mlm,
                                                 float* __restrict__ mll) {
    __shared__ __align__(16) u16 k_s[64 * ROWP];
    __shared__ __align__(16) u16 vt_s[64 * ROWP];
    __shared__ __align__(16) u16 p_s[4][16 * ROWP];
    const int h = blockIdx.y;
    const int s = blockIdx.z;
    const int row0 = blockIdx.x * 64;
    const int tid = threadIdx.x;
    const int w = tid >> 6, lane = tid & 63;
    const int qi = lane & 15, gi = lane >> 4;
    const float CE = 0.18033688011f;   // 0.125 * log2(e)

    const u16* qrow = qb + ((size_t)h * N_NODES + row0 + w * 16 + qi) * 64 + gi * 8;
    bf16x8 qf0 = *(const bf16x8*)qrow;
    bf16x8 qf1 = *(const bf16x8*)(qrow + 32);

    f32x4 oc[4];
#pragma unroll
    for (int i = 0; i < 4; ++i) oc[i] = (f32x4){0.f, 0.f, 0.f, 0.f};
    float m_run = -INFINITY, l_run = 0.f;

    const u16* kbh = kb + (size_t)h * N_NODES * 64;
    const u16* vth = vtb + (size_t)h * 64 * N_NODES;

    for (int kt = s * (N_NODES / 64 / NSPLIT); kt < (s + 1) * (N_NODES / 64 / NSPLIT); ++kt) {
        const u16* ksrc = kbh + kt * 64 * 64;
#pragma unroll
        for (int i = 0; i < 2; ++i) {
            int c = tid + i * 256;
            int r = c >> 3, ss = c & 7;
            *(uint4*)&k_s[r * ROWP + ss * 8]  = *(const uint4*)(ksrc + c * 8);
            *(uint4*)&vt_s[r * ROWP + ss * 8] = *(const uint4*)(vth + (size_t)r * N_NODES + kt * 64 + ss * 8);
        }
        __syncthreads();

        f32x4 sc[4];
#pragma unroll
        for (int t = 0; t < 4; ++t) {
            const u16* krow = &k_s[(t * 16 + qi) * ROWP + gi * 8];
            bf16x8 ka0 = *(const bf16x8*)krow;
            bf16x8 ka1 = *(const bf16x8*)(krow + 32);
            f32x4 z = (f32x4){0.f, 0.f, 0.f, 0.f};
            z = __builtin_amdgcn_mfma_f32_16x16x32_bf16(ka0, qf0, z, 0, 0, 0);
            sc[t] = __builtin_amdgcn_mfma_f32_16x16x32_bf16(ka1, qf1, z, 0, 0, 0);
        }

        float smax = -INFINITY;
#pragma unroll
        for (int t = 0; t < 4; ++t)
            smax = fmaxf(smax, fmaxf(fmaxf(sc[t][0], sc[t][1]), fmaxf(sc[t][2], sc[t][3])));
        smax = fmaxf(smax, __shfl_xor(smax, 16));
        smax = fmaxf(smax, __shfl_xor(smax, 32));
        float mn = fmaxf(m_run, smax);
        float alpha = exp2f((m_run - mn) * CE);
        m_run = mn;
        float nb = mn * CE;
        float psum = 0.f;
#pragma unroll
        for (int t = 0; t < 4; ++t) {
            ushort4 pw;
            float p0 = exp2f(fmaf(sc[t][0], CE, -nb)); psum += p0; pw.x = f2b(p0);
            float p1 = exp2f(fmaf(sc[t][1], CE, -nb)); psum += p1; pw.y = f2b(p1);
            float p2 = exp2f(fmaf(sc[t][2], CE, -nb)); psum += p2; pw.z = f2b(p2);
            float p3 = exp2f(fmaf(sc[t][3], CE, -nb)); psum += p3; pw.w = f2b(p3);
            *(ushort4*)&p_s[w][qi * ROWP + t * 16 + gi * 4] = pw;
        }
        psum += __shfl_xor(psum, 16);
        psum += __shfl_xor(psum, 32);
        l_run = l_run * alpha + psum;

        float a0 = __shfl(alpha, gi * 4 + 0);
        float a1 = __shfl(alpha, gi * 4 + 1);
        float a2 = __shfl(alpha, gi * 4 + 2);
        float a3 = __shfl(alpha, gi * 4 + 3);
#pragma unroll
        for (int d = 0; d < 4; ++d) {
            oc[d][0] *= a0; oc[d][1] *= a1; oc[d][2] *= a2; oc[d][3] *= a3;
        }

        const u16* prow = &p_s[w][qi * ROWP];
        bf16x8 pa0 = *(const bf16x8*)(prow + gi * 8);
        bf16x8 pa1 = *(const bf16x8*)(prow + 32 + gi * 8);
#pragma unroll
        for (int d = 0; d < 4; ++d) {
            const u16* vrow = &vt_s[(d * 16 + qi) * ROWP + gi * 8];
            bf16x8 vb0 = *(const bf16x8*)vrow;
            bf16x8 vb1 = *(const bf16x8*)(vrow + 32);
            oc[d] = __builtin_amdgcn_mfma_f32_16x16x32_bf16(pa0, vb0, oc[d], 0, 0, 0);
            oc[d] = __builtin_amdgcn_mfma_f32_16x16x32_bf16(pa1, vb1, oc[d], 0, 0, 0);
        }
        __syncthreads();
    }

    float* opd = op + (size_t)s * N_NODES * 128;
#pragma unroll
    for (int d = 0; d < 4; ++d) {
        size_t cb = h * 64 + d * 16 + qi;
        opd[(size_t)(row0 + w * 16 + gi * 4 + 0) * 128 + cb] = oc[d][0];
        opd[(size_t)(row0 + w * 16 + gi * 4 + 1) * 128 + cb] = oc[d][1];
        opd[(size_t)(row0 + w * 16 + gi * 4 + 2) * 128 + cb] = oc[d][2];
        opd[(size_t)(row0 + w * 16 + gi * 4 + 3) * 128 + cb] = oc[d][3];
    }
    if (gi == 0) {
        size_t mi = (size_t)s * NHEAD * N_NODES + (size_t)h * N_NODES + row0 + w * 16 + qi;
        mlm[mi] = m_run;
        mll[mi] = l_run;
    }
}

// ---------------------------------------------------------------------------
// FUSED: split-K combine -> Wo GEMM -> +bias -> +residual(h) -> LayerNorm ->
// h fp32 + hi/lo planes.  Tile 16 rows x 128 cols, grid N/16 = 256 blocks.
#define ROWA 136
__global__ __launch_bounds__(256) void gemm_wo_ln(const float* __restrict__ op,
                                                  const float* __restrict__ mlm,
                                                  const float* __restrict__ mll,
                                                  const u16* __restrict__ Wp,
                                                  const float* __restrict__ bo,
                                                  float* __restrict__ h,
                                                  const float* __restrict__ g,
                                                  const float* __restrict__ b,
                                                  u16* __restrict__ hh,
                                                  u16* __restrict__ hl) {
    const int K = 128, NC = 128;
    __shared__ __align__(16) u16 a_hi[16 * ROWA];
    __shared__ __align__(16) u16 a_lo[16 * ROWA];
    __shared__ float ws_s[NSPLIT][32];
    __shared__ float Linv_s[32];
    __shared__ float wsum[4][16], wsq[4][16];
    const float CE = 0.18033688011f;
    const int tid = threadIdx.x, w = tid >> 6, lane = tid & 63;
    const int qi = lane & 15, gi = lane >> 4;
    const int row0 = blockIdx.x * 16;
    const u16* Wlo = Wp + (size_t)K * NC;

    if (tid < 32) {
        int r = tid >> 1, hd = tid & 1;
        size_t mb = (size_t)hd * N_NODES + row0 + r;
        float m[NSPLIT], l[NSPLIT], mx = -INFINITY;
#pragma unroll
        for (int s = 0; s < NSPLIT; ++s) {
            m[s] = mlm[mb + (size_t)s * NHEAD * N_NODES];
            l[s] = mll[mb + (size_t)s * NHEAD * N_NODES];
            mx = fmaxf(mx, m[s]);
        }
        float L = 0.f;
#pragma unroll
        for (int s = 0; s < NSPLIT; ++s) {
            float ws = exp2f((m[s] - mx) * CE);
            ws_s[s][tid] = ws;
            L += ws * l[s];
        }
        Linv_s[tid] = 1.f / L;
    }
    __syncthreads();

    for (int e = tid; e < 16 * 128; e += 256) {
        int r = e >> 7, c = e & 127, hd = c >> 6;
        size_t idx = (size_t)(row0 + r) * 128 + c;
        float O = 0.f;
#pragma unroll
        for (int s = 0; s < NSPLIT; ++s)
            O += ws_s[s][r * 2 + hd] * op[(size_t)s * N_NODES * 128 + idx];
        float v = O * Linv_s[r * 2 + hd];
        u16 hi = f2b(v);
        a_hi[r * ROWA + c] = hi;
        a_lo[r * ROWA + c] = f2b(v - b2f_bits(hi));
    }
    __syncthreads();

    f32x4 acc[2];
    acc[0] = (f32x4){0.f, 0.f, 0.f, 0.f};
    acc[1] = (f32x4){0.f, 0.f, 0.f, 0.f};
    const int col0 = w * 32;
#pragma unroll
    for (int kc = 0; kc < 4; ++kc) {
        const int k0 = kc * 32;
        bf16x8 ah = *(const bf16x8*)&a_hi[qi * ROWA + k0 + gi * 8];
        bf16x8 al = *(const bf16x8*)&a_lo[qi * ROWA + k0 + gi * 8];
#pragma unroll
        for (int c = 0; c < 2; ++c) {
            const size_t wo = ((size_t)(k0 / 8 + gi) * NC + col0 + c * 16 + qi) * 8;
            bf16x8 wh = *(const bf16x8*)(Wp + wo);
            bf16x8 wl = *(const bf16x8*)(Wlo + wo);
            acc[c] = __builtin_amdgcn_mfma_f32_16x16x32_bf16(ah, wh, acc[c], 0, 0, 0);
            acc[c] = __builtin_amdgcn_mfma_f32_16x16x32_bf16(al, wh, acc[c], 0, 0, 0);
            acc[c] = __builtin_amdgcn_mfma_f32_16x16x32_bf16(ah, wl, acc[c], 0, 0, 0);
        }
    }

    float y[2][4];
    float rs[4], rq[4];
#pragma unroll
    for (int r = 0; r < 4; ++r) { rs[r] = 0.f; rq[r] = 0.f; }
#pragma unroll
    for (int c = 0; c < 2; ++c) {
        const int col = col0 + c * 16 + qi;
        float bv = bo[col];
#pragma unroll
        for (int r = 0; r < 4; ++r) {
            const int grow = row0 + gi * 4 + r;
            float v = acc[c][r] + bv + h[(size_t)grow * 128 + col];
            y[c][r] = v;
            rs[r] += v;
            rq[r] += v * v;
        }
    }
#pragma unroll
    for (int r = 0; r < 4; ++r) {
        for (int msk = 1; msk < 16; msk <<= 1) {
            rs[r] += __shfl_xor(rs[r], msk);
            rq[r] += __shfl_xor(rq[r], msk);
        }
    }
    if (qi == 0) {
#pragma unroll
        for (int r = 0; r < 4; ++r) { wsum[w][gi * 4 + r] = rs[r]; wsq[w][gi * 4 + r] = rq[r]; }
    }
    __syncthreads();
#pragma unroll
    for (int r = 0; r < 4; ++r) {
        const int lr = gi * 4 + r;
        float ts = wsum[0][lr] + wsum[1][lr] + wsum[2][lr] + wsum[3][lr];
        float tq = wsq[0][lr] + wsq[1][lr] + wsq[2][lr] + wsq[3][lr];
        float mean = ts * (1.f / 128.f);
        float var  = tq * (1.f / 128.f) - mean * mean;
        float rstd = rsqrtf(var + 1e-5f);
        const int grow = row0 + lr;
#pragma unroll
        for (int c = 0; c < 2; ++c) {
            const int col = col0 + c * 16 + qi;
            float yn = (y[c][r] - mean) * rstd * g[col] + b[col];
            size_t idx = (size_t)grow * 128 + col;
            h[idx] = yn;
            u16 hi = f2b(yn);
            hh[idx] = hi;
            hl[idx] = f2b(yn - b2f_bits(hi));
        }
    }
}

// ---------------------------------------------------------------------------
// FUSED FF block: z = sigmoid(h@W1+bf1) [16x256], LDS, y = z@W2+bf2, +res, LN.
// Tile 16 rows, grid 256 blocks, 4 waves (wave w: FF1 cols w*64..+63, FF2 cols w*32..+31).
#define ROWZ 264
__global__ __launch_bounds__(256) void ff_fused(const u16* __restrict__ Ah,
                                                const u16* __restrict__ Al,
                                                const u16* __restrict__ Wp1,
                                                const float* __restrict__ bf1,
                                                const u16* __restrict__ Wp2,
                                                const float* __restrict__ bf2,
                                                float* __restrict__ h,
                                                const float* __restrict__ g,
                                                const float* __restrict__ b,
                                                u16* __restrict__ hh,
                                                u16* __restrict__ hl) {
    __shared__ __align__(16) u16 z_hi[16 * ROWZ];
    __shared__ __align__(16) u16 z_lo[16 * ROWZ];
    __shared__ float wsum[4][16], wsq[4][16];
    const int tid = threadIdx.x, w = tid >> 6, lane = tid & 63;
    const int qi = lane & 15, gi = lane >> 4;
    const int row0 = blockIdx.x * 16;
    const u16* W1lo = Wp1 + (size_t)128 * 256;
    const u16* W2lo = Wp2 + (size_t)256 * 128;

    // FF1: K=128, this wave's 64 output cols
    f32x4 acc1[4];
#pragma unroll
    for (int t = 0; t < 4; ++t) acc1[t] = (f32x4){0.f, 0.f, 0.f, 0.f};
#pragma unroll
    for (int kc = 0; kc < 4; ++kc) {
        const int k0 = kc * 32;
        const size_t ao = (size_t)(row0 + qi) * 128 + k0 + gi * 8;
        bf16x8 ah = *(const bf16x8*)(Ah + ao);
        bf16x8 al = *(const bf16x8*)(Al + ao);
#pragma unroll
        for (int t = 0; t < 4; ++t) {
            const size_t wo = ((size_t)(k0 / 8 + gi) * 256 + w * 64 + t * 16 + qi) * 8;
            bf16x8 wh = *(const bf16x8*)(Wp1 + wo);
            bf16x8 wl = *(const bf16x8*)(W1lo + wo);
            acc1[t] = __builtin_amdgcn_mfma_f32_16x16x32_bf16(ah, wh, acc1[t], 0, 0, 0);
            acc1[t] = __builtin_amdgcn_mfma_f32_16x16x32_bf16(al, wh, acc1[t], 0, 0, 0);
            acc1[t] = __builtin_amdgcn_mfma_f32_16x16x32_bf16(ah, wl, acc1[t], 0, 0, 0);
        }
    }
    // sigmoid + split into LDS z planes (z[row][col], col = FF2's K dim)
#pragma unroll
    for (int t = 0; t < 4; ++t) {
        const int col = w * 64 + t * 16 + qi;
        float bv = bf1[col];
#pragma unroll
        for (int r = 0; r < 4; ++r) {
            float v = acc1[t][r] + bv;
            v = 1.f / (1.f + __expf(-v));
            u16 hi = f2b(v);
            const int zr = gi * 4 + r;
            z_hi[zr * ROWZ + col] = hi;
            z_lo[zr * ROWZ + col] = f2b(v - b2f_bits(hi));
        }
    }
    __syncthreads();

    // FF2: K=256 from LDS, this wave's 32 output cols
    f32x4 acc[2];
    acc[0] = (f32x4){0.f, 0.f, 0.f, 0.f};
    acc[1] = (f32x4){0.f, 0.f, 0.f, 0.f};
    const int col0 = w * 32;
#pragma unroll
    for (int kc = 0; kc < 8; ++kc) {
        const int k0 = kc * 32;
        bf16x8 ah = *(const bf16x8*)&z_hi[qi * ROWZ + k0 + gi * 8];
        bf16x8 al = *(const bf16x8*)&z_lo[qi * ROWZ + k0 + gi * 8];
#pragma unroll
        for (int c = 0; c < 2; ++c) {
            const size_t wo = ((size_t)(k0 / 8 + gi) * 128 + col0 + c * 16 + qi) * 8;
            bf16x8 wh = *(const bf16x8*)(Wp2 + wo);
            bf16x8 wl = *(const bf16x8*)(W2lo + wo);
            acc[c] = __builtin_amdgcn_mfma_f32_16x16x32_bf16(ah, wh, acc[c], 0, 0, 0);
            acc[c] = __builtin_amdgcn_mfma_f32_16x16x32_bf16(al, wh, acc[c], 0, 0, 0);
            acc[c] = __builtin_amdgcn_mfma_f32_16x16x32_bf16(ah, wl, acc[c], 0, 0, 0);
        }
    }

    // +bias +residual, LN
    float y[2][4];
    float rs[4], rq[4];
#pragma unroll
    for (int r = 0; r < 4; ++r) { rs[r] = 0.f; rq[r] = 0.f; }
#pragma unroll
    for (int c = 0; c < 2; ++c) {
        const int col = col0 + c * 16 + qi;
        float bv = bf2[col];
#pragma unroll
        for (int r = 0; r < 4; ++r) {
            const int grow = row0 + gi * 4 + r;
            float v = acc[c][r] + bv + h[(size_t)grow * 128 + col];
            y[c][r] = v;
            rs[r] += v;
            rq[r] += v * v;
        }
    }
#pragma unroll
    for (int r = 0; r < 4; ++r) {
        for (int msk = 1; msk < 16; msk <<= 1) {
            rs[r] += __shfl_xor(rs[r], msk);
            rq[r] += __shfl_xor(rq[r], msk);
        }
    }
    if (qi == 0) {
#pragma unroll
        for (int r = 0; r < 4; ++r) { wsum[w][gi * 4 + r] = rs[r]; wsq[w][gi * 4 + r] = rq[r]; }
    }
    __syncthreads();
#pragma unroll
    for (int r = 0; r < 4; ++r) {
        const int lr = gi * 4 + r;
        float ts = wsum[0][lr] + wsum[1][lr] + wsum[2][lr] + wsum[3][lr];
        float tq = wsq[0][lr] + wsq[1][lr] + wsq[2][lr] + wsq[3][lr];
        float mean = ts * (1.f / 128.f);
        float var  = tq * (1.f / 128.f) - mean * mean;
        float rstd = rsqrtf(var + 1e-5f);
        const int grow = row0 + lr;
#pragma unroll
        for (int c = 0; c < 2; ++c) {
            const int col = col0 + c * 16 + qi;
            float yn = (y[c][r] - mean) * rstd * g[col] + b[col];
            size_t idx = (size_t)grow * 128 + col;
            h[idx] = yn;
            u16 hi = f2b(yn);
            hh[idx] = hi;
            hl[idx] = f2b(yn - b2f_bits(hi));
        }
    }
}

// ---------------------------------------------------------------------------
// Hypergraph (Wh pushed past aggregation: e = (B^-1 H^T h) @ Wh).
__device__ __forceinline__ int probe_is64(const int* edge_raw, int tid) {
    __shared__ int is64_s;
    if (tid < 64) {
        int v = edge_raw[2 * tid + 1];
        unsigned long long bal = __ballot(v != 0);
        if (tid == 0) is64_s = (bal == 0ull) ? 1 : 0;
    }
    __syncthreads();
    return is64_s;
}

// Block 0: histogram+scan of hyperedge ids -> off_e; block 1: node ids -> off_n.
__global__ __launch_bounds__(1024) void count_scan(const int* __restrict__ edge_raw,
                                                   int* __restrict__ off_e,
                                                   int* __restrict__ off_n,
                                                   int* __restrict__ cur_e,
                                                   int* __restrict__ cur_n) {
    __shared__ int s[N_NODES];
    const int is64 = probe_is64(edge_raw, threadIdx.x);
    const int he_side = (blockIdx.x == 0);
    const int n = he_side ? NEDGE : N_NODES;
    int* off = he_side ? off_e : off_n;
    int* cur = he_side ? cur_e : cur_n;
    for (int i = threadIdx.x; i < n; i += 1024) s[i] = 0;
    __syncthreads();
    for (int i = threadIdx.x; i < NNZ_E; i += 1024) {
        int v;
        if (he_side) v = (is64 ? edge_raw[2 * NNZ_E + 2 * i] : edge_raw[NNZ_E + i]) & (NEDGE - 1);
        else         v = (is64 ? edge_raw[2 * i]             : edge_raw[i])         & (N_NODES - 1);
        atomicAdd(&s[v], 1);
    }
    __syncthreads();
    for (int st = 1; st < n; st <<= 1) {
        int v[4]; int nj = 0;
        for (int i = threadIdx.x; i < n; i += 1024) v[nj++] = (i >= st) ? s[i - st] : 0;
        __syncthreads();
        nj = 0;
        for (int i = threadIdx.x; i < n; i += 1024) s[i] += v[nj++];
        __syncthreads();
    }
    for (int i = threadIdx.x; i < n; i += 1024) { off[i + 1] = s[i]; cur[i] = 0; }
    if (threadIdx.x == 0) off[0] = 0;
}

__global__ void fill_csr(const int* __restrict__ edge_raw,
                         const int* __restrict__ off_e, const int* __restrict__ off_n,
                         int* __restrict__ cur_e, int* __restrict__ cur_n,
                         int* __restrict__ csr_e, int* __restrict__ csr_n) {
    const int is64 = probe_is64(edge_raw, threadIdx.x);
    int i = blockIdx.x * 256 + threadIdx.x;
    if (i < NNZ_E) {
        int ni = (is64 ? edge_raw[2 * i]             : edge_raw[i])         & (N_NODES - 1);
        int he = (is64 ? edge_raw[2 * NNZ_E + 2 * i] : edge_raw[NNZ_E + i]) & (NEDGE - 1);
        int p = atomicAdd(&cur_e[he], 1);
        csr_e[off_e[he] + p] = ni;
        int q = atomicAdd(&cur_n[ni], 1);
        csr_n[off_n[ni] + q] = he;
    }
}

// e_agg[he] = binv * sum_members h[member]  -> bf16 hi/lo planes (gemm_e input)
__global__ __launch_bounds__(128) void gather_e(const int* __restrict__ off_e,
                                                const int* __restrict__ csr_e,
                                                const float* __restrict__ h,
                                                u16* __restrict__ ehi,
                                                u16* __restrict__ elo) {
    __shared__ int ms[128];
    const int he = blockIdx.x, d = threadIdx.x;
    const int beg = off_e[he], end = off_e[he + 1];
    float acc = 0.f;
    for (int c = beg; c < end; c += 128) {
        int nl = min(128, end - c);
        if (d < nl) ms[d] = csr_e[c + d];
        __syncthreads();
        for (int j = 0; j < nl; ++j) acc += h[(size_t)ms[j] * 128 + d];
        __syncthreads();
    }
    float binv = (end > beg) ? 1.f / (float)(end - beg) : 0.f;
    float v = acc * binv;
    u16 hi = f2b(v);
    ehi[(size_t)he * 128 + d] = hi;
    elo[(size_t)he * 128 + d] = f2b(v - b2f_bits(hi));
}

// out[n] = relu(dinv * sum_{incident he} e_sc[he] + bh)
__global__ __launch_bounds__(128) void gather_n(const int* __restrict__ off_n,
                                                const int* __restrict__ csr_n,
                                                const float* __restrict__ e_sc,
                                                const float* __restrict__ bh,
                                                float* __restrict__ out) {
    __shared__ int ms[128];
    const int nn = blockIdx.x, d = threadIdx.x;
    const int beg = off_n[nn], end = off_n[nn + 1];
    float acc = 0.f;
    for (int c = beg; c < end; c += 128) {
        int nl = min(128, end - c);
        if (d < nl) ms[d] = csr_n[c + d];
        __syncthreads();
        for (int j = 0; j < nl; ++j) acc += e_sc[(size_t)ms[j] * 128 + d];
        __syncthreads();
    }
    float dinv = (end > beg) ? 1.f / (float)(end - beg) : 0.f;
    float v = acc * dinv + bh[d];
    out[(size_t)nn * 128 + d] = v > 0.f ? v : 0.f;
}

// ---------------------------------------------------------------------------
extern "C" void kernel_launch(void* const* d_in, const int* in_sizes, int n_in,
                              void* d_out, int out_size, void* d_ws, size_t ws_size,
                              hipStream_t stream) {
    (void)in_sizes; (void)n_in; (void)out_size; (void)ws_size;
    const float* x    = (const float*)d_in[0];
    const int*   edge = (const int*)  d_in[1];
    const float* Wq = (const float*)d_in[2];  const float* bq  = (const float*)d_in[3];
    const float* Wk = (const float*)d_in[4];  const float* bk  = (const float*)d_in[5];
    const float* Wv = (const float*)d_in[6];  const float* bv  = (const float*)d_in[7];
    const float* Wo = (const float*)d_in[8];  const float* bo  = (const float*)d_in[9];
    const float* g1 = (const float*)d_in[10]; const float* b1  = (const float*)d_in[11];
    const float* W1 = (const float*)d_in[12]; const float* bf1 = (const float*)d_in[13];
    const float* W2 = (const float*)d_in[14]; const float* bf2 = (const float*)d_in[15];
    const float* g2 = (const float*)d_in[16]; const float* b2  = (const float*)d_in[17];
    const float* Wh = (const float*)d_in[18]; const float* bh  = (const float*)d_in[19];
    float* out = (float*)d_out;

    // ---- workspace layout (fp32-word offsets), all live regions DISJOINT ----
    float* B = (float*)d_ws;
    float* h    = B;                          // [N,128] fp32
    u16*   h_hi = (u16*)(B + 524288);         // [N,128] bf16
    u16*   h_lo = (u16*)(B + 786432);
    u16*   qb   = (u16*)(B + 1048576);        // [H][N][64] bf16
    u16*   kb   = (u16*)(B + 1310720);
    u16*   vtb  = (u16*)(B + 1835008);        // [H][64][N] bf16
    float* op   = B + 2097152;                // [NSPLIT][N][128] fp32 -> end 6291456
    float* mlm  = B + 6291456;                // [NSPLIT][H][N]
    float* mll  = B + 6356992;                // -> end 6422528
    u16*   e_hi = (u16*)(B + 6946816);        // [NE,128] bf16 -> 131072 words
    u16*   e_lo = (u16*)(B + 7077888);
    float* e_sc = B + 7208960;                // [NE,128] fp32 -> end 7471104
    u16*   wp_q = (u16*)(B + 8519680);        // packs: 16384 w each (128x128)
    u16*   wp_k = (u16*)(B + 8536064);
    u16*   wp_v = (u16*)(B + 8552448);
    u16*   wp_o = (u16*)(B + 8568832);
    u16*   wp_h = (u16*)(B + 8585216);
    u16*   wp_1 = (u16*)(B + 8601600);        // 128x256: 32768 w
    u16*   wp_2 = (u16*)(B + 8634368);        // 256x128: 32768 w -> end 8667136
    int*   cur_e = (int*)(B + 9328640);       // [NE]
    int*   cur_n = (int*)(B + 9330688);       // [N]
    int*   off_e = (int*)(B + 9334784);       // [NE+1]
    int*   off_n = (int*)(B + 9336840);       // [N+1]
    int*   csr_e = (int*)(B + 9340944);       // [NNZ]
    int*   csr_n = (int*)(B + 9406480);       // [NNZ] -> end 9472016

    prep<<<2048 + 7 * 128, 256, 0, stream>>>(x, h, h_hi, h_lo,
                                             Wq, Wk, Wv, Wo, Wh, W1, W2,
                                             wp_q, wp_k, wp_v, wp_o, wp_h, wp_1, wp_2);

    for (int layer = 0; layer < 2; ++layer) {
        qkv_mfma<<<dim3(64, 12), 256, 0, stream>>>(h_hi, h_lo, wp_q, wp_k, wp_v,
                                                   bq, bk, bv, qb, kb, vtb);
        attn_mfma<<<dim3(N_NODES / 64, NHEAD, NSPLIT), 256, 0, stream>>>(qb, kb, vtb, op, mlm, mll);
        gemm_wo_ln<<<N_NODES / 16, 256, 0, stream>>>(op, mlm, mll, wp_o, bo,
                                                     h, g1, b1, h_hi, h_lo);
        ff_fused<<<N_NODES / 16, 256, 0, stream>>>(h_hi, h_lo, wp_1, bf1, wp_2, bf2,
                                                   h, g2, b2, h_hi, h_lo);
    }

    // hypergraph: CSR build from edge, aggregate h, then Wh on 2048 rows
    count_scan<<<2, 1024, 0, stream>>>(edge, off_e, off_n, cur_e, cur_n);
    fill_csr<<<NNZ_E / 256, 256, 0, stream>>>(edge, off_e, off_n, cur_e, cur_n, csr_e, csr_n);
    gather_e<<<NEDGE, 128, 0, stream>>>(off_e, csr_e, h, e_hi, e_lo);
    gemm_mfma<128, 128><<<dim3(NEDGE / 64, 4), 256, 0, stream>>>(e_hi, e_lo, wp_h, e_sc);
    gather_n<<<N_NODES, 128, 0, stream>>>(off_n, csr_n, e_sc, bh, out);
}

// Round 10
// 262.088 us; speedup vs baseline: 3.5454x; 1.0227x over previous
//
#include <hip/hip_runtime.h>
#include <hip/hip_bf16.h>
#include <cstddef>

// Problem constants
#define N_NODES 4096
#define DIM     128
#define NHEAD   2
#define DHEAD   64
#define FFDIM   256
#define NEDGE   2048
#define NNZ_E   65536
#define NSPLIT  8

typedef __attribute__((ext_vector_type(8))) short bf16x8;   // 8 bf16 in 4 VGPRs
typedef __attribute__((ext_vector_type(4))) float f32x4;
typedef unsigned short u16;

__device__ __forceinline__ u16 f2b(float f) {               // rne fp32->bf16
    unsigned u = __float_as_uint(f);
    return (u16)((u + 0x7FFFu + ((u >> 16) & 1u)) >> 16);
}
__device__ __forceinline__ float b2f_bits(u16 h) {
    return __uint_as_float(((unsigned)h) << 16);
}

// ---------------------------------------------------------------------------
// prep: blocks [0,2048) split x into h + hi/lo planes; blocks [2048,2944) pack
// the 7 weights into [2 planes][K/8][NC][8] bf16 fragment layout.
__global__ void prep(const float* __restrict__ x, float* __restrict__ h,
                     u16* __restrict__ hh, u16* __restrict__ hl,
                     const float* W0, const float* W1, const float* W2,
                     const float* W3, const float* W4, const float* W5,
                     const float* W6,
                     u16* P0, u16* P1, u16* P2, u16* P3, u16* P4, u16* P5, u16* P6) {
    const int bx = blockIdx.x;
    if (bx < 2048) {
        int i = bx * 256 + threadIdx.x;
        float f = x[i];
        h[i] = f;
        u16 hi = f2b(f);
        hh[i] = hi;
        hl[i] = f2b(f - b2f_bits(hi));
        return;
    }
    const int p = bx - 2048;
    const int sel = p >> 7;
    const float* W; u16* P; int K, NC;
    switch (sel) {
        case 0: W = W0; P = P0; K = 128; NC = 128; break;
        case 1: W = W1; P = P1; K = 128; NC = 128; break;
        case 2: W = W2; P = P2; K = 128; NC = 128; break;
        case 3: W = W3; P = P3; K = 128; NC = 128; break;
        case 4: W = W4; P = P4; K = 128; NC = 128; break;
        case 5: W = W5; P = P5; K = 128; NC = 256; break;
        default: W = W6; P = P6; K = 256; NC = 128; break;
    }
    int i = (p & 127) * 256 + threadIdx.x;
    if (i < K * NC) {
        int k = i / NC, n = i % NC;
        float f = W[i];
        u16 hb = f2b(f);
        size_t o = ((size_t)(k >> 3) * NC + n) * 8 + (k & 7);
        P[o] = hb;
        P[(size_t)K * NC + o] = f2b(f - b2f_bits(hb));
    }
}

// ---------------------------------------------------------------------------
// Generic split-bf16 MFMA GEMM (3-term ~fp32). Block 256 = 4 waves, tile 64x32.
template<int K, int NC>
__global__ __launch_bounds__(256) void gemm_mfma(const u16* __restrict__ Ah,
                                                 const u16* __restrict__ Al,
                                                 const u16* __restrict__ Wp,
                                                 float* __restrict__ C0) {
    const int tid = threadIdx.x, w = tid >> 6, lane = tid & 63;
    const int qi = lane & 15, gi = lane >> 4;
    const int row0 = blockIdx.x * 64 + w * 16;
    const int col0 = blockIdx.y * 32;
    const u16* Wlo = Wp + (size_t)K * NC;

    f32x4 acc[2];
    acc[0] = (f32x4){0.f, 0.f, 0.f, 0.f};
    acc[1] = (f32x4){0.f, 0.f, 0.f, 0.f};

#pragma unroll 4
    for (int kc = 0; kc < K / 32; ++kc) {
        const int k0 = kc * 32;
        const size_t ao = (size_t)(row0 + qi) * K + k0 + gi * 8;
        bf16x8 ah = *(const bf16x8*)(Ah + ao);
        bf16x8 al = *(const bf16x8*)(Al + ao);
#pragma unroll
        for (int c = 0; c < 2; ++c) {
            const size_t wo = ((size_t)(k0 / 8 + gi) * NC + col0 + c * 16 + qi) * 8;
            bf16x8 wh = *(const bf16x8*)(Wp + wo);
            bf16x8 wl = *(const bf16x8*)(Wlo + wo);
            acc[c] = __builtin_amdgcn_mfma_f32_16x16x32_bf16(ah, wh, acc[c], 0, 0, 0);
            acc[c] = __builtin_amdgcn_mfma_f32_16x16x32_bf16(al, wh, acc[c], 0, 0, 0);
            acc[c] = __builtin_amdgcn_mfma_f32_16x16x32_bf16(ah, wl, acc[c], 0, 0, 0);
        }
    }

#pragma unroll
    for (int c = 0; c < 2; ++c) {
        const int col = col0 + c * 16 + qi;
#pragma unroll
        for (int r = 0; r < 4; ++r) {
            const int grow = row0 + gi * 4 + r;
            C0[(size_t)grow * NC + col] = acc[c][r];
        }
    }
}

// ---------------------------------------------------------------------------
// Fused QKV GEMM. Grid (64, 12): sel = y>>2 (0=Q,1=K,2=V), col0 = (y&3)*32.
__global__ __launch_bounds__(256) void qkv_mfma(const u16* __restrict__ Ah,
                                                const u16* __restrict__ Al,
                                                const u16* __restrict__ Wq,
                                                const u16* __restrict__ Wk,
                                                const u16* __restrict__ Wv,
                                                const float* __restrict__ bq,
                                                const float* __restrict__ bk,
                                                const float* __restrict__ bv,
                                                u16* __restrict__ qb,
                                                u16* __restrict__ kb,
                                                u16* __restrict__ vtb) {
    const int K = 128, NC = 128;
    const int tid = threadIdx.x, w = tid >> 6, lane = tid & 63;
    const int qi = lane & 15, gi = lane >> 4;
    const int row0 = blockIdx.x * 64 + w * 16;
    const int sel = blockIdx.y >> 2;
    const int col0 = (blockIdx.y & 3) * 32;
    const u16* Wp = (sel == 0) ? Wq : (sel == 1) ? Wk : Wv;
    const float* bias = (sel == 0) ? bq : (sel == 1) ? bk : bv;
    const u16* Wlo = Wp + (size_t)K * NC;

    f32x4 acc[2];
    acc[0] = (f32x4){0.f, 0.f, 0.f, 0.f};
    acc[1] = (f32x4){0.f, 0.f, 0.f, 0.f};

#pragma unroll 4
    for (int kc = 0; kc < K / 32; ++kc) {
        const int k0 = kc * 32;
        const size_t ao = (size_t)(row0 + qi) * K + k0 + gi * 8;
        bf16x8 ah = *(const bf16x8*)(Ah + ao);
        bf16x8 al = *(const bf16x8*)(Al + ao);
#pragma unroll
        for (int c = 0; c < 2; ++c) {
            const size_t wo = ((size_t)(k0 / 8 + gi) * NC + col0 + c * 16 + qi) * 8;
            bf16x8 wh = *(const bf16x8*)(Wp + wo);
            bf16x8 wl = *(const bf16x8*)(Wlo + wo);
            acc[c] = __builtin_amdgcn_mfma_f32_16x16x32_bf16(ah, wh, acc[c], 0, 0, 0);
            acc[c] = __builtin_amdgcn_mfma_f32_16x16x32_bf16(al, wh, acc[c], 0, 0, 0);
            acc[c] = __builtin_amdgcn_mfma_f32_16x16x32_bf16(ah, wl, acc[c], 0, 0, 0);
        }
    }

#pragma unroll
    for (int c = 0; c < 2; ++c) {
        const int col = col0 + c * 16 + qi;
        const int hh = col >> 6, d = col & 63;
        float bv_ = bias[col];
        if (sel < 2) {                 // Q or K: [H][N][64]
            u16* dst = (sel == 0) ? qb : kb;
#pragma unroll
            for (int r = 0; r < 4; ++r) {
                const int grow = row0 + gi * 4 + r;
                dst[((size_t)hh * N_NODES + grow) * 64 + d] = f2b(acc[c][r] + bv_);
            }
        } else {                       // V: transposed [H][64][N], 4 consecutive n
            const int grow0 = row0 + gi * 4;
            ushort4 pw;
            pw.x = f2b(acc[c][0] + bv_);
            pw.y = f2b(acc[c][1] + bv_);
            pw.z = f2b(acc[c][2] + bv_);
            pw.w = f2b(acc[c][3] + bv_);
            *(ushort4*)&vtb[((size_t)hh * 64 + d) * N_NODES + grow0] = pw;
        }
    }
}

// ---------------------------------------------------------------------------
// Split-K MFMA flash attention. Grid (N/64, H, NSPLIT); block 256 = 4 waves.
#define ROWP 72
__global__ __launch_bounds__(256) void attn_mfma(const u16* __restrict__ qb,
                                                 const u16* __restrict__ kb,
                                                 const u16* __restrict__ vtb,
                                                 float* __restrict__ op,
                                                 float* __restrict__ mlm,
                                                 float* __restrict__ mll) {
    __shared__ __align__(16) u16 k_s[64 * ROWP];
    __shared__ __align__(16) u16 vt_s[64 * ROWP];
    __shared__ __align__(16) u16 p_s[4][16 * ROWP];
    const int h = blockIdx.y;
    const int s = blockIdx.z;
    const int row0 = blockIdx.x * 64;
    const int tid = threadIdx.x;
    const int w = tid >> 6, lane = tid & 63;
    const int qi = lane & 15, gi = lane >> 4;
    const float CE = 0.18033688011f;   // 0.125 * log2(e)

    const u16* qrow = qb + ((size_t)h * N_NODES + row0 + w * 16 + qi) * 64 + gi * 8;
    bf16x8 qf0 = *(const bf16x8*)qrow;
    bf16x8 qf1 = *(const bf16x8*)(qrow + 32);

    f32x4 oc[4];
#pragma unroll
    for (int i = 0; i < 4; ++i) oc[i] = (f32x4){0.f, 0.f, 0.f, 0.f};
    float m_run = -INFINITY, l_run = 0.f;

    const u16* kbh = kb + (size_t)h * N_NODES * 64;
    const u16* vth = vtb + (size_t)h * 64 * N_NODES;

    for (int kt = s * (N_NODES / 64 / NSPLIT); kt < (s + 1) * (N_NODES / 64 / NSPLIT); ++kt) {
        const u16* ksrc = kbh + kt * 64 * 64;
#pragma unroll
        for (int i = 0; i < 2; ++i) {
            int c = tid + i * 256;
            int r = c >> 3, ss = c & 7;
            *(uint4*)&k_s[r * ROWP + ss * 8]  = *(const uint4*)(ksrc + c * 8);
            *(uint4*)&vt_s[r * ROWP + ss * 8] = *(const uint4*)(vth + (size_t)r * N_NODES + kt * 64 + ss * 8);
        }
        __syncthreads();

        f32x4 sc[4];
#pragma unroll
        for (int t = 0; t < 4; ++t) {
            const u16* krow = &k_s[(t * 16 + qi) * ROWP + gi * 8];
            bf16x8 ka0 = *(const bf16x8*)krow;
            bf16x8 ka1 = *(const bf16x8*)(krow + 32);
            f32x4 z = (f32x4){0.f, 0.f, 0.f, 0.f};
            z = __builtin_amdgcn_mfma_f32_16x16x32_bf16(ka0, qf0, z, 0, 0, 0);
            sc[t] = __builtin_amdgcn_mfma_f32_16x16x32_bf16(ka1, qf1, z, 0, 0, 0);
        }

        float smax = -INFINITY;
#pragma unroll
        for (int t = 0; t < 4; ++t)
            smax = fmaxf(smax, fmaxf(fmaxf(sc[t][0], sc[t][1]), fmaxf(sc[t][2], sc[t][3])));
        smax = fmaxf(smax, __shfl_xor(smax, 16));
        smax = fmaxf(smax, __shfl_xor(smax, 32));
        float mn = fmaxf(m_run, smax);
        float alpha = exp2f((m_run - mn) * CE);
        m_run = mn;
        float nb = mn * CE;
        float psum = 0.f;
#pragma unroll
        for (int t = 0; t < 4; ++t) {
            ushort4 pw;
            float p0 = exp2f(fmaf(sc[t][0], CE, -nb)); psum += p0; pw.x = f2b(p0);
            float p1 = exp2f(fmaf(sc[t][1], CE, -nb)); psum += p1; pw.y = f2b(p1);
            float p2 = exp2f(fmaf(sc[t][2], CE, -nb)); psum += p2; pw.z = f2b(p2);
            float p3 = exp2f(fmaf(sc[t][3], CE, -nb)); psum += p3; pw.w = f2b(p3);
            *(ushort4*)&p_s[w][qi * ROWP + t * 16 + gi * 4] = pw;
        }
        psum += __shfl_xor(psum, 16);
        psum += __shfl_xor(psum, 32);
        l_run = l_run * alpha + psum;

        float a0 = __shfl(alpha, gi * 4 + 0);
        float a1 = __shfl(alpha, gi * 4 + 1);
        float a2 = __shfl(alpha, gi * 4 + 2);
        float a3 = __shfl(alpha, gi * 4 + 3);
#pragma unroll
        for (int d = 0; d < 4; ++d) {
            oc[d][0] *= a0; oc[d][1] *= a1; oc[d][2] *= a2; oc[d][3] *= a3;
        }

        const u16* prow = &p_s[w][qi * ROWP];
        bf16x8 pa0 = *(const bf16x8*)(prow + gi * 8);
        bf16x8 pa1 = *(const bf16x8*)(prow + 32 + gi * 8);
#pragma unroll
        for (int d = 0; d < 4; ++d) {
            const u16* vrow = &vt_s[(d * 16 + qi) * ROWP + gi * 8];
            bf16x8 vb0 = *(const bf16x8*)vrow;
            bf16x8 vb1 = *(const bf16x8*)(vrow + 32);
            oc[d] = __builtin_amdgcn_mfma_f32_16x16x32_bf16(pa0, vb0, oc[d], 0, 0, 0);
            oc[d] = __builtin_amdgcn_mfma_f32_16x16x32_bf16(pa1, vb1, oc[d], 0, 0, 0);
        }
        __syncthreads();
    }

    float* opd = op + (size_t)s * N_NODES * 128;
#pragma unroll
    for (int d = 0; d < 4; ++d) {
        size_t cb = h * 64 + d * 16 + qi;
        opd[(size_t)(row0 + w * 16 + gi * 4 + 0) * 128 + cb] = oc[d][0];
        opd[(size_t)(row0 + w * 16 + gi * 4 + 1) * 128 + cb] = oc[d][1];
        opd[(size_t)(row0 + w * 16 + gi * 4 + 2) * 128 + cb] = oc[d][2];
        opd[(size_t)(row0 + w * 16 + gi * 4 + 3) * 128 + cb] = oc[d][3];
    }
    if (gi == 0) {
        size_t mi = (size_t)s * NHEAD * N_NODES + (size_t)h * N_NODES + row0 + w * 16 + qi;
        mlm[mi] = m_run;
        mll[mi] = l_run;
    }
}

// ---------------------------------------------------------------------------
// FUSED: split-K combine -> Wo GEMM -> +bias -> +residual(h) -> LayerNorm ->
// h fp32 + hi/lo planes.  Tile 16 rows x 128 cols, grid N/16 = 256 blocks.
#define ROWA 136
__global__ __launch_bounds__(256) void gemm_wo_ln(const float* __restrict__ op,
                                                  const float* __restrict__ mlm,
                                                  const float* __restrict__ mll,
                                                  const u16* __restrict__ Wp,
                                                  const float* __restrict__ bo,
                                                  float* __restrict__ h,
                                                  const float* __restrict__ g,
                                                  const float* __restrict__ b,
                                                  u16* __restrict__ hh,
                                                  u16* __restrict__ hl) {
    const int K = 128, NC = 128;
    __shared__ __align__(16) u16 a_hi[16 * ROWA];
    __shared__ __align__(16) u16 a_lo[16 * ROWA];
    __shared__ float ws_s[NSPLIT][32];
    __shared__ float Linv_s[32];
    __shared__ float wsum[4][16], wsq[4][16];
    const float CE = 0.18033688011f;
    const int tid = threadIdx.x, w = tid >> 6, lane = tid & 63;
    const int qi = lane & 15, gi = lane >> 4;
    const int row0 = blockIdx.x * 16;
    const u16* Wlo = Wp + (size_t)K * NC;

    if (tid < 32) {
        int r = tid >> 1, hd = tid & 1;
        size_t mb = (size_t)hd * N_NODES + row0 + r;
        float m[NSPLIT], l[NSPLIT], mx = -INFINITY;
#pragma unroll
        for (int s = 0; s < NSPLIT; ++s) {
            m[s] = mlm[mb + (size_t)s * NHEAD * N_NODES];
            l[s] = mll[mb + (size_t)s * NHEAD * N_NODES];
            mx = fmaxf(mx, m[s]);
        }
        float L = 0.f;
#pragma unroll
        for (int s = 0; s < NSPLIT; ++s) {
            float ws = exp2f((m[s] - mx) * CE);
            ws_s[s][tid] = ws;
            L += ws * l[s];
        }
        Linv_s[tid] = 1.f / L;
    }
    __syncthreads();

    for (int e = tid; e < 16 * 128; e += 256) {
        int r = e >> 7, c = e & 127, hd = c >> 6;
        size_t idx = (size_t)(row0 + r) * 128 + c;
        float O = 0.f;
#pragma unroll
        for (int s = 0; s < NSPLIT; ++s)
            O += ws_s[s][r * 2 + hd] * op[(size_t)s * N_NODES * 128 + idx];
        float v = O * Linv_s[r * 2 + hd];
        u16 hi = f2b(v);
        a_hi[r * ROWA + c] = hi;
        a_lo[r * ROWA + c] = f2b(v - b2f_bits(hi));
    }
    __syncthreads();

    f32x4 acc[2];
    acc[0] = (f32x4){0.f, 0.f, 0.f, 0.f};
    acc[1] = (f32x4){0.f, 0.f, 0.f, 0.f};
    const int col0 = w * 32;
#pragma unroll
    for (int kc = 0; kc < 4; ++kc) {
        const int k0 = kc * 32;
        bf16x8 ah = *(const bf16x8*)&a_hi[qi * ROWA + k0 + gi * 8];
        bf16x8 al = *(const bf16x8*)&a_lo[qi * ROWA + k0 + gi * 8];
#pragma unroll
        for (int c = 0; c < 2; ++c) {
            const size_t wo = ((size_t)(k0 / 8 + gi) * NC + col0 + c * 16 + qi) * 8;
            bf16x8 wh = *(const bf16x8*)(Wp + wo);
            bf16x8 wl = *(const bf16x8*)(Wlo + wo);
            acc[c] = __builtin_amdgcn_mfma_f32_16x16x32_bf16(ah, wh, acc[c], 0, 0, 0);
            acc[c] = __builtin_amdgcn_mfma_f32_16x16x32_bf16(al, wh, acc[c], 0, 0, 0);
            acc[c] = __builtin_amdgcn_mfma_f32_16x16x32_bf16(ah, wl, acc[c], 0, 0, 0);
        }
    }

    float y[2][4];
    float rs[4], rq[4];
#pragma unroll
    for (int r = 0; r < 4; ++r) { rs[r] = 0.f; rq[r] = 0.f; }
#pragma unroll
    for (int c = 0; c < 2; ++c) {
        const int col = col0 + c * 16 + qi;
        float bv = bo[col];
#pragma unroll
        for (int r = 0; r < 4; ++r) {
            const int grow = row0 + gi * 4 + r;
            float v = acc[c][r] + bv + h[(size_t)grow * 128 + col];
            y[c][r] = v;
            rs[r] += v;
            rq[r] += v * v;
        }
    }
#pragma unroll
    for (int r = 0; r < 4; ++r) {
        for (int msk = 1; msk < 16; msk <<= 1) {
            rs[r] += __shfl_xor(rs[r], msk);
            rq[r] += __shfl_xor(rq[r], msk);
        }
    }
    if (qi == 0) {
#pragma unroll
        for (int r = 0; r < 4; ++r) { wsum[w][gi * 4 + r] = rs[r]; wsq[w][gi * 4 + r] = rq[r]; }
    }
    __syncthreads();
#pragma unroll
    for (int r = 0; r < 4; ++r) {
        const int lr = gi * 4 + r;
        float ts = wsum[0][lr] + wsum[1][lr] + wsum[2][lr] + wsum[3][lr];
        float tq = wsq[0][lr] + wsq[1][lr] + wsq[2][lr] + wsq[3][lr];
        float mean = ts * (1.f / 128.f);
        float var  = tq * (1.f / 128.f) - mean * mean;
        float rstd = rsqrtf(var + 1e-5f);
        const int grow = row0 + lr;
#pragma unroll
        for (int c = 0; c < 2; ++c) {
            const int col = col0 + c * 16 + qi;
            float yn = (y[c][r] - mean) * rstd * g[col] + b[col];
            size_t idx = (size_t)grow * 128 + col;
            h[idx] = yn;
            u16 hi = f2b(yn);
            hh[idx] = hi;
            hl[idx] = f2b(yn - b2f_bits(hi));
        }
    }
}

// ---------------------------------------------------------------------------
// FUSED FF block: z = sigmoid(h@W1+bf1) [16x256], LDS, y = z@W2+bf2, +res, LN.
#define ROWZ 264
__global__ __launch_bounds__(256) void ff_fused(const u16* __restrict__ Ah,
                                                const u16* __restrict__ Al,
                                                const u16* __restrict__ Wp1,
                                                const float* __restrict__ bf1,
                                                const u16* __restrict__ Wp2,
                                                const float* __restrict__ bf2,
                                                float* __restrict__ h,
                                                const float* __restrict__ g,
                                                const float* __restrict__ b,
                                                u16* __restrict__ hh,
                                                u16* __restrict__ hl) {
    __shared__ __align__(16) u16 z_hi[16 * ROWZ];
    __shared__ __align__(16) u16 z_lo[16 * ROWZ];
    __shared__ float wsum[4][16], wsq[4][16];
    const int tid = threadIdx.x, w = tid >> 6, lane = tid & 63;
    const int qi = lane & 15, gi = lane >> 4;
    const int row0 = blockIdx.x * 16;
    const u16* W1lo = Wp1 + (size_t)128 * 256;
    const u16* W2lo = Wp2 + (size_t)256 * 128;

    f32x4 acc1[4];
#pragma unroll
    for (int t = 0; t < 4; ++t) acc1[t] = (f32x4){0.f, 0.f, 0.f, 0.f};
#pragma unroll
    for (int kc = 0; kc < 4; ++kc) {
        const int k0 = kc * 32;
        const size_t ao = (size_t)(row0 + qi) * 128 + k0 + gi * 8;
        bf16x8 ah = *(const bf16x8*)(Ah + ao);
        bf16x8 al = *(const bf16x8*)(Al + ao);
#pragma unroll
        for (int t = 0; t < 4; ++t) {
            const size_t wo = ((size_t)(k0 / 8 + gi) * 256 + w * 64 + t * 16 + qi) * 8;
            bf16x8 wh = *(const bf16x8*)(Wp1 + wo);
            bf16x8 wl = *(const bf16x8*)(W1lo + wo);
            acc1[t] = __builtin_amdgcn_mfma_f32_16x16x32_bf16(ah, wh, acc1[t], 0, 0, 0);
            acc1[t] = __builtin_amdgcn_mfma_f32_16x16x32_bf16(al, wh, acc1[t], 0, 0, 0);
            acc1[t] = __builtin_amdgcn_mfma_f32_16x16x32_bf16(ah, wl, acc1[t], 0, 0, 0);
        }
    }
#pragma unroll
    for (int t = 0; t < 4; ++t) {
        const int col = w * 64 + t * 16 + qi;
        float bv = bf1[col];
#pragma unroll
        for (int r = 0; r < 4; ++r) {
            float v = acc1[t][r] + bv;
            v = 1.f / (1.f + __expf(-v));
            u16 hi = f2b(v);
            const int zr = gi * 4 + r;
            z_hi[zr * ROWZ + col] = hi;
            z_lo[zr * ROWZ + col] = f2b(v - b2f_bits(hi));
        }
    }
    __syncthreads();

    f32x4 acc[2];
    acc[0] = (f32x4){0.f, 0.f, 0.f, 0.f};
    acc[1] = (f32x4){0.f, 0.f, 0.f, 0.f};
    const int col0 = w * 32;
#pragma unroll
    for (int kc = 0; kc < 8; ++kc) {
        const int k0 = kc * 32;
        bf16x8 ah = *(const bf16x8*)&z_hi[qi * ROWZ + k0 + gi * 8];
        bf16x8 al = *(const bf16x8*)&z_lo[qi * ROWZ + k0 + gi * 8];
#pragma unroll
        for (int c = 0; c < 2; ++c) {
            const size_t wo = ((size_t)(k0 / 8 + gi) * 128 + col0 + c * 16 + qi) * 8;
            bf16x8 wh = *(const bf16x8*)(Wp2 + wo);
            bf16x8 wl = *(const bf16x8*)(W2lo + wo);
            acc[c] = __builtin_amdgcn_mfma_f32_16x16x32_bf16(ah, wh, acc[c], 0, 0, 0);
            acc[c] = __builtin_amdgcn_mfma_f32_16x16x32_bf16(al, wh, acc[c], 0, 0, 0);
            acc[c] = __builtin_amdgcn_mfma_f32_16x16x32_bf16(ah, wl, acc[c], 0, 0, 0);
        }
    }

    float y[2][4];
    float rs[4], rq[4];
#pragma unroll
    for (int r = 0; r < 4; ++r) { rs[r] = 0.f; rq[r] = 0.f; }
#pragma unroll
    for (int c = 0; c < 2; ++c) {
        const int col = col0 + c * 16 + qi;
        float bv = bf2[col];
#pragma unroll
        for (int r = 0; r < 4; ++r) {
            const int grow = row0 + gi * 4 + r;
            float v = acc[c][r] + bv + h[(size_t)grow * 128 + col];
            y[c][r] = v;
            rs[r] += v;
            rq[r] += v * v;
        }
    }
#pragma unroll
    for (int r = 0; r < 4; ++r) {
        for (int msk = 1; msk < 16; msk <<= 1) {
            rs[r] += __shfl_xor(rs[r], msk);
            rq[r] += __shfl_xor(rq[r], msk);
        }
    }
    if (qi == 0) {
#pragma unroll
        for (int r = 0; r < 4; ++r) { wsum[w][gi * 4 + r] = rs[r]; wsq[w][gi * 4 + r] = rq[r]; }
    }
    __syncthreads();
#pragma unroll
    for (int r = 0; r < 4; ++r) {
        const int lr = gi * 4 + r;
        float ts = wsum[0][lr] + wsum[1][lr] + wsum[2][lr] + wsum[3][lr];
        float tq = wsq[0][lr] + wsq[1][lr] + wsq[2][lr] + wsq[3][lr];
        float mean = ts * (1.f / 128.f);
        float var  = tq * (1.f / 128.f) - mean * mean;
        float rstd = rsqrtf(var + 1e-5f);
        const int grow = row0 + lr;
#pragma unroll
        for (int c = 0; c < 2; ++c) {
            const int col = col0 + c * 16 + qi;
            float yn = (y[c][r] - mean) * rstd * g[col] + b[col];
            size_t idx = (size_t)grow * 128 + col;
            h[idx] = yn;
            u16 hi = f2b(yn);
            hh[idx] = hi;
            hl[idx] = f2b(yn - b2f_bits(hi));
        }
    }
}

// ---------------------------------------------------------------------------
// Hypergraph CSR build: decode + global-atomic histogram (full-device parallel),
// then a tiny 2-block scan, then fill.
__global__ void hist_kernel(const int* __restrict__ edge_raw,
                            int* __restrict__ nidx, int* __restrict__ hidx,
                            int* __restrict__ cnt_e, int* __restrict__ cnt_n) {
    __shared__ int is64_s;
    if (threadIdx.x < 64) {
        int v = edge_raw[2 * threadIdx.x + 1];
        unsigned long long bal = __ballot(v != 0);
        if (threadIdx.x == 0) is64_s = (bal == 0ull) ? 1 : 0;
    }
    __syncthreads();
    const int is64 = is64_s;
    int i = blockIdx.x * 256 + threadIdx.x;
    if (i < NNZ_E) {
        int ni = (is64 ? edge_raw[2 * i]             : edge_raw[i])         & (N_NODES - 1);
        int he = (is64 ? edge_raw[2 * NNZ_E + 2 * i] : edge_raw[NNZ_E + i]) & (NEDGE - 1);
        nidx[i] = ni;
        hidx[i] = he;
        atomicAdd(&cnt_n[ni], 1);
        atomicAdd(&cnt_e[he], 1);
    }
}

// Block 0: scan cnt_e (NE bins) -> off_e, zero cur_e; block 1: cnt_n -> off_n.
__global__ __launch_bounds__(1024) void scan_only(const int* __restrict__ cnt_e,
                                                  const int* __restrict__ cnt_n,
                                                  int* __restrict__ off_e,
                                                  int* __restrict__ off_n,
                                                  int* __restrict__ cur_e,
                                                  int* __restrict__ cur_n) {
    __shared__ int s[N_NODES];
    const int he_side = (blockIdx.x == 0);
    const int n = he_side ? NEDGE : N_NODES;
    const int* cnt = he_side ? cnt_e : cnt_n;
    int* off = he_side ? off_e : off_n;
    int* cur = he_side ? cur_e : cur_n;
    for (int i = threadIdx.x; i < n; i += 1024) s[i] = cnt[i];
    __syncthreads();
    for (int st = 1; st < n; st <<= 1) {
        int v[4]; int nj = 0;
        for (int i = threadIdx.x; i < n; i += 1024) v[nj++] = (i >= st) ? s[i - st] : 0;
        __syncthreads();
        nj = 0;
        for (int i = threadIdx.x; i < n; i += 1024) s[i] += v[nj++];
        __syncthreads();
    }
    for (int i = threadIdx.x; i < n; i += 1024) { off[i + 1] = s[i]; cur[i] = 0; }
    if (threadIdx.x == 0) off[0] = 0;
}

__global__ void fill_csr(const int* __restrict__ nidx, const int* __restrict__ hidx,
                         const int* __restrict__ off_e, const int* __restrict__ off_n,
                         int* __restrict__ cur_e, int* __restrict__ cur_n,
                         int* __restrict__ csr_e, int* __restrict__ csr_n) {
    int i = blockIdx.x * 256 + threadIdx.x;
    if (i < NNZ_E) {
        int ni = nidx[i], he = hidx[i];
        int p = atomicAdd(&cur_e[he], 1);
        csr_e[off_e[he] + p] = ni;
        int q = atomicAdd(&cur_n[ni], 1);
        csr_n[off_n[ni] + q] = he;
    }
}

// e_agg[he] = binv * sum_members h[member]  -> bf16 hi/lo planes (gemm_e input)
__global__ __launch_bounds__(128) void gather_e(const int* __restrict__ off_e,
                                                const int* __restrict__ csr_e,
                                                const float* __restrict__ h,
                                                u16* __restrict__ ehi,
                                                u16* __restrict__ elo) {
    __shared__ int ms[128];
    const int he = blockIdx.x, d = threadIdx.x;
    const int beg = off_e[he], end = off_e[he + 1];
    float acc = 0.f;
    for (int c = beg; c < end; c += 128) {
        int nl = min(128, end - c);
        if (d < nl) ms[d] = csr_e[c + d];
        __syncthreads();
        for (int j = 0; j < nl; ++j) acc += h[(size_t)ms[j] * 128 + d];
        __syncthreads();
    }
    float binv = (end > beg) ? 1.f / (float)(end - beg) : 0.f;
    float v = acc * binv;
    u16 hi = f2b(v);
    ehi[(size_t)he * 128 + d] = hi;
    elo[(size_t)he * 128 + d] = f2b(v - b2f_bits(hi));
}

// out[n] = relu(dinv * sum_{incident he} e_sc[he] + bh)
__global__ __launch_bounds__(128) void gather_n(const int* __restrict__ off_n,
                                                const int* __restrict__ csr_n,
                                                const float* __restrict__ e_sc,
                                                const float* __restrict__ bh,
                                                float* __restrict__ out) {
    __shared__ int ms[128];
    const int nn = blockIdx.x, d = threadIdx.x;
    const int beg = off_n[nn], end = off_n[nn + 1];
    float acc = 0.f;
    for (int c = beg; c < end; c += 128) {
        int nl = min(128, end - c);
        if (d < nl) ms[d] = csr_n[c + d];
        __syncthreads();
        for (int j = 0; j < nl; ++j) acc += e_sc[(size_t)ms[j] * 128 + d];
        __syncthreads();
    }
    float dinv = (end > beg) ? 1.f / (float)(end - beg) : 0.f;
    float v = acc * dinv + bh[d];
    out[(size_t)nn * 128 + d] = v > 0.f ? v : 0.f;
}

// ---------------------------------------------------------------------------
extern "C" void kernel_launch(void* const* d_in, const int* in_sizes, int n_in,
                              void* d_out, int out_size, void* d_ws, size_t ws_size,
                              hipStream_t stream) {
    (void)in_sizes; (void)n_in; (void)out_size; (void)ws_size;
    const float* x    = (const float*)d_in[0];
    const int*   edge = (const int*)  d_in[1];
    const float* Wq = (const float*)d_in[2];  const float* bq  = (const float*)d_in[3];
    const float* Wk = (const float*)d_in[4];  const float* bk  = (const float*)d_in[5];
    const float* Wv = (const float*)d_in[6];  const float* bv  = (const float*)d_in[7];
    const float* Wo = (const float*)d_in[8];  const float* bo  = (const float*)d_in[9];
    const float* g1 = (const float*)d_in[10]; const float* b1  = (const float*)d_in[11];
    const float* W1 = (const float*)d_in[12]; const float* bf1 = (const float*)d_in[13];
    const float* W2 = (const float*)d_in[14]; const float* bf2 = (const float*)d_in[15];
    const float* g2 = (const float*)d_in[16]; const float* b2  = (const float*)d_in[17];
    const float* Wh = (const float*)d_in[18]; const float* bh  = (const float*)d_in[19];
    float* out = (float*)d_out;

    // ---- workspace layout (fp32-word offsets), all live regions DISJOINT ----
    float* B = (float*)d_ws;
    float* h    = B;                          // [N,128] fp32
    u16*   h_hi = (u16*)(B + 524288);         // [N,128] bf16
    u16*   h_lo = (u16*)(B + 786432);
    u16*   qb   = (u16*)(B + 1048576);        // [H][N][64] bf16
    u16*   kb   = (u16*)(B + 1310720);
    u16*   vtb  = (u16*)(B + 1835008);        // [H][64][N] bf16
    float* op   = B + 2097152;                // [NSPLIT][N][128] fp32 -> end 6291456
    float* mlm  = B + 6291456;                // [NSPLIT][H][N]
    float* mll  = B + 6356992;                // -> end 6422528
    u16*   e_hi = (u16*)(B + 6946816);        // [NE,128] bf16 -> 131072 words
    u16*   e_lo = (u16*)(B + 7077888);
    float* e_sc = B + 7208960;                // [NE,128] fp32 -> end 7471104
    u16*   wp_q = (u16*)(B + 8519680);        // packs: 16384 w each (128x128)
    u16*   wp_k = (u16*)(B + 8536064);
    u16*   wp_v = (u16*)(B + 8552448);
    u16*   wp_o = (u16*)(B + 8568832);
    u16*   wp_h = (u16*)(B + 8585216);
    u16*   wp_1 = (u16*)(B + 8601600);        // 128x256: 32768 w
    u16*   wp_2 = (u16*)(B + 8634368);        // 256x128: 32768 w -> end 8667136
    int*   cur_e = (int*)(B + 9328640);       // [NE]
    int*   cur_n = (int*)(B + 9330688);       // [N]
    int*   off_e = (int*)(B + 9334784);       // [NE+1]
    int*   off_n = (int*)(B + 9336840);       // [N+1]
    int*   csr_e = (int*)(B + 9340944);       // [NNZ]
    int*   csr_n = (int*)(B + 9406480);       // [NNZ] -> end 9472016
    int*   cnt_e = (int*)(B + 9472016);       // [NE]
    int*   cnt_n = (int*)(B + 9474064);       // [N]  -> end 9478160
    int*   nidx  = (int*)(B + 9478160);       // [NNZ]
    int*   hidx  = (int*)(B + 9543696);       // [NNZ] -> end 9609232 (~38.4 MB)

    prep<<<2048 + 7 * 128, 256, 0, stream>>>(x, h, h_hi, h_lo,
                                             Wq, Wk, Wv, Wo, Wh, W1, W2,
                                             wp_q, wp_k, wp_v, wp_o, wp_h, wp_1, wp_2);

    for (int layer = 0; layer < 2; ++layer) {
        qkv_mfma<<<dim3(64, 12), 256, 0, stream>>>(h_hi, h_lo, wp_q, wp_k, wp_v,
                                                   bq, bk, bv, qb, kb, vtb);
        attn_mfma<<<dim3(N_NODES / 64, NHEAD, NSPLIT), 256, 0, stream>>>(qb, kb, vtb, op, mlm, mll);
        gemm_wo_ln<<<N_NODES / 16, 256, 0, stream>>>(op, mlm, mll, wp_o, bo,
                                                     h, g1, b1, h_hi, h_lo);
        ff_fused<<<N_NODES / 16, 256, 0, stream>>>(h_hi, h_lo, wp_1, bf1, wp_2, bf2,
                                                   h, g2, b2, h_hi, h_lo);
    }

    // hypergraph: parallel histogram -> tiny scan -> CSR fill -> gathers + Wh GEMM
    hipMemsetAsync(cnt_e, 0, (NEDGE + N_NODES) * sizeof(int), stream);
    hist_kernel<<<NNZ_E / 256, 256, 0, stream>>>(edge, nidx, hidx, cnt_e, cnt_n);
    scan_only<<<2, 1024, 0, stream>>>(cnt_e, cnt_n, off_e, off_n, cur_e, cur_n);
    fill_csr<<<NNZ_E / 256, 256, 0, stream>>>(nidx, hidx, off_e, off_n, cur_e, cur_n, csr_e, csr_n);
    gather_e<<<NEDGE, 128, 0, stream>>>(off_e, csr_e, h, e_hi, e_lo);
    gemm_mfma<128, 128><<<dim3(NEDGE / 64, 4), 256, 0, stream>>>(e_hi, e_lo, wp_h, e_sc);
    gather_n<<<N_NODES, 128, 0, stream>>>(off_n, csr_n, e_sc, bh, out);
}

// Round 11
// 256.141 us; speedup vs baseline: 3.6277x; 1.0232x over previous
//
#include <hip/hip_runtime.h>
#include <hip/hip_bf16.h>
#include <cstddef>

// Problem constants
#define N_NODES 4096
#define DIM     128
#define NHEAD   2
#define DHEAD   64
#define FFDIM   256
#define NEDGE   2048
#define NNZ_E   65536
#define NSPLIT  8

typedef __attribute__((ext_vector_type(8))) short bf16x8;   // 8 bf16 in 4 VGPRs
typedef __attribute__((ext_vector_type(4))) float f32x4;
typedef unsigned short u16;

__device__ __forceinline__ u16 f2b(float f) {               // rne fp32->bf16
    unsigned u = __float_as_uint(f);
    return (u16)((u + 0x7FFFu + ((u >> 16) & 1u)) >> 16);
}
__device__ __forceinline__ float b2f_bits(u16 h) {
    return __uint_as_float(((unsigned)h) << 16);
}

// ---------------------------------------------------------------------------
// prep: blocks [0,2048) split x; [2048,2944) pack weights; [2944,2968) zero cnt.
__global__ void prep(const float* __restrict__ x, float* __restrict__ h,
                     u16* __restrict__ hh, u16* __restrict__ hl,
                     const float* W0, const float* W1, const float* W2,
                     const float* W3, const float* W4, const float* W5,
                     const float* W6,
                     u16* P0, u16* P1, u16* P2, u16* P3, u16* P4, u16* P5, u16* P6,
                     int* __restrict__ cnt) {
    const int bx = blockIdx.x;
    if (bx < 2048) {
        int i = bx * 256 + threadIdx.x;
        float f = x[i];
        h[i] = f;
        u16 hi = f2b(f);
        hh[i] = hi;
        hl[i] = f2b(f - b2f_bits(hi));
        return;
    }
    if (bx >= 2944) {                 // zero cnt_e+cnt_n (6144 ints)
        int i = (bx - 2944) * 256 + threadIdx.x;
        if (i < NEDGE + N_NODES) cnt[i] = 0;
        return;
    }
    const int p = bx - 2048;
    const int sel = p >> 7;
    const float* W; u16* P; int K, NC;
    switch (sel) {
        case 0: W = W0; P = P0; K = 128; NC = 128; break;
        case 1: W = W1; P = P1; K = 128; NC = 128; break;
        case 2: W = W2; P = P2; K = 128; NC = 128; break;
        case 3: W = W3; P = P3; K = 128; NC = 128; break;
        case 4: W = W4; P = P4; K = 128; NC = 128; break;
        case 5: W = W5; P = P5; K = 128; NC = 256; break;
        default: W = W6; P = P6; K = 256; NC = 128; break;
    }
    int i = (p & 127) * 256 + threadIdx.x;
    if (i < K * NC) {
        int k = i / NC, n = i % NC;
        float f = W[i];
        u16 hb = f2b(f);
        size_t o = ((size_t)(k >> 3) * NC + n) * 8 + (k & 7);
        P[o] = hb;
        P[(size_t)K * NC + o] = f2b(f - b2f_bits(hb));
    }
}

// ---------------------------------------------------------------------------
// Generic split-bf16 MFMA GEMM (3-term ~fp32). Block 256 = 4 waves, tile 64x32.
template<int K, int NC>
__global__ __launch_bounds__(256) void gemm_mfma(const u16* __restrict__ Ah,
                                                 const u16* __restrict__ Al,
                                                 const u16* __restrict__ Wp,
                                                 float* __restrict__ C0) {
    const int tid = threadIdx.x, w = tid >> 6, lane = tid & 63;
    const int qi = lane & 15, gi = lane >> 4;
    const int row0 = blockIdx.x * 64 + w * 16;
    const int col0 = blockIdx.y * 32;
    const u16* Wlo = Wp + (size_t)K * NC;

    f32x4 acc[2];
    acc[0] = (f32x4){0.f, 0.f, 0.f, 0.f};
    acc[1] = (f32x4){0.f, 0.f, 0.f, 0.f};

#pragma unroll 4
    for (int kc = 0; kc < K / 32; ++kc) {
        const int k0 = kc * 32;
        const size_t ao = (size_t)(row0 + qi) * K + k0 + gi * 8;
        bf16x8 ah = *(const bf16x8*)(Ah + ao);
        bf16x8 al = *(const bf16x8*)(Al + ao);
#pragma unroll
        for (int c = 0; c < 2; ++c) {
            const size_t wo = ((size_t)(k0 / 8 + gi) * NC + col0 + c * 16 + qi) * 8;
            bf16x8 wh = *(const bf16x8*)(Wp + wo);
            bf16x8 wl = *(const bf16x8*)(Wlo + wo);
            acc[c] = __builtin_amdgcn_mfma_f32_16x16x32_bf16(ah, wh, acc[c], 0, 0, 0);
            acc[c] = __builtin_amdgcn_mfma_f32_16x16x32_bf16(al, wh, acc[c], 0, 0, 0);
            acc[c] = __builtin_amdgcn_mfma_f32_16x16x32_bf16(ah, wl, acc[c], 0, 0, 0);
        }
    }

#pragma unroll
    for (int c = 0; c < 2; ++c) {
        const int col = col0 + c * 16 + qi;
#pragma unroll
        for (int r = 0; r < 4; ++r) {
            const int grow = row0 + gi * 4 + r;
            C0[(size_t)grow * NC + col] = acc[c][r];
        }
    }
}

// ---------------------------------------------------------------------------
// Fused QKV GEMM (layer 1 only). Grid (64, 12): sel = y>>2, col0 = (y&3)*32.
__global__ __launch_bounds__(256) void qkv_mfma(const u16* __restrict__ Ah,
                                                const u16* __restrict__ Al,
                                                const u16* __restrict__ Wq,
                                                const u16* __restrict__ Wk,
                                                const u16* __restrict__ Wv,
                                                const float* __restrict__ bq,
                                                const float* __restrict__ bk,
                                                const float* __restrict__ bv,
                                                u16* __restrict__ qb,
                                                u16* __restrict__ kb,
                                                u16* __restrict__ vtb) {
    const int K = 128, NC = 128;
    const int tid = threadIdx.x, w = tid >> 6, lane = tid & 63;
    const int qi = lane & 15, gi = lane >> 4;
    const int row0 = blockIdx.x * 64 + w * 16;
    const int sel = blockIdx.y >> 2;
    const int col0 = (blockIdx.y & 3) * 32;
    const u16* Wp = (sel == 0) ? Wq : (sel == 1) ? Wk : Wv;
    const float* bias = (sel == 0) ? bq : (sel == 1) ? bk : bv;
    const u16* Wlo = Wp + (size_t)K * NC;

    f32x4 acc[2];
    acc[0] = (f32x4){0.f, 0.f, 0.f, 0.f};
    acc[1] = (f32x4){0.f, 0.f, 0.f, 0.f};

#pragma unroll 4
    for (int kc = 0; kc < K / 32; ++kc) {
        const int k0 = kc * 32;
        const size_t ao = (size_t)(row0 + qi) * K + k0 + gi * 8;
        bf16x8 ah = *(const bf16x8*)(Ah + ao);
        bf16x8 al = *(const bf16x8*)(Al + ao);
#pragma unroll
        for (int c = 0; c < 2; ++c) {
            const size_t wo = ((size_t)(k0 / 8 + gi) * NC + col0 + c * 16 + qi) * 8;
            bf16x8 wh = *(const bf16x8*)(Wp + wo);
            bf16x8 wl = *(const bf16x8*)(Wlo + wo);
            acc[c] = __builtin_amdgcn_mfma_f32_16x16x32_bf16(ah, wh, acc[c], 0, 0, 0);
            acc[c] = __builtin_amdgcn_mfma_f32_16x16x32_bf16(al, wh, acc[c], 0, 0, 0);
            acc[c] = __builtin_amdgcn_mfma_f32_16x16x32_bf16(ah, wl, acc[c], 0, 0, 0);
        }
    }

#pragma unroll
    for (int c = 0; c < 2; ++c) {
        const int col = col0 + c * 16 + qi;
        const int hh = col >> 6, d = col & 63;
        float bv_ = bias[col];
        if (sel < 2) {
            u16* dst = (sel == 0) ? qb : kb;
#pragma unroll
            for (int r = 0; r < 4; ++r) {
                const int grow = row0 + gi * 4 + r;
                dst[((size_t)hh * N_NODES + grow) * 64 + d] = f2b(acc[c][r] + bv_);
            }
        } else {
            const int grow0 = row0 + gi * 4;
            ushort4 pw;
            pw.x = f2b(acc[c][0] + bv_);
            pw.y = f2b(acc[c][1] + bv_);
            pw.z = f2b(acc[c][2] + bv_);
            pw.w = f2b(acc[c][3] + bv_);
            *(ushort4*)&vtb[((size_t)hh * 64 + d) * N_NODES + grow0] = pw;
        }
    }
}

// ---------------------------------------------------------------------------
// Split-K MFMA flash attention. Grid (N/64, H, NSPLIT); block 256 = 4 waves.
#define ROWP 72
__global__ __launch_bounds__(256) void attn_mfma(const u16* __restrict__ qb,
                                                 const u16* __restrict__ kb,
                                                 const u16* __restrict__ vtb,
                                                 float* __restrict__ op,
                                                 float* __restrict__ mlm,
                                                 float* __restrict__ mll) {
    __shared__ __align__(16) u16 k_s[64 * ROWP];
    __shared__ __align__(16) u16 vt_s[64 * ROWP];
    __shared__ __align__(16) u16 p_s[4][16 * ROWP];
    const int h = blockIdx.y;
    const int s = blockIdx.z;
    const int row0 = blockIdx.x * 64;
    const int tid = threadIdx.x;
    const int w = tid >> 6, lane = tid & 63;
    const int qi = lane & 15, gi = lane >> 4;
    const float CE = 0.18033688011f;   // 0.125 * log2(e)

    const u16* qrow = qb + ((size_t)h * N_NODES + row0 + w * 16 + qi) * 64 + gi * 8;
    bf16x8 qf0 = *(const bf16x8*)qrow;
    bf16x8 qf1 = *(const bf16x8*)(qrow + 32);

    f32x4 oc[4];
#pragma unroll
    for (int i = 0; i < 4; ++i) oc[i] = (f32x4){0.f, 0.f, 0.f, 0.f};
    float m_run = -INFINITY, l_run = 0.f;

    const u16* kbh = kb + (size_t)h * N_NODES * 64;
    const u16* vth = vtb + (size_t)h * 64 * N_NODES;

    for (int kt = s * (N_NODES / 64 / NSPLIT); kt < (s + 1) * (N_NODES / 64 / NSPLIT); ++kt) {
        const u16* ksrc = kbh + kt * 64 * 64;
#pragma unroll
        for (int i = 0; i < 2; ++i) {
            int c = tid + i * 256;
            int r = c >> 3, ss = c & 7;
            *(uint4*)&k_s[r * ROWP + ss * 8]  = *(const uint4*)(ksrc + c * 8);
            *(uint4*)&vt_s[r * ROWP + ss * 8] = *(const uint4*)(vth + (size_t)r * N_NODES + kt * 64 + ss * 8);
        }
        __syncthreads();

        f32x4 sc[4];
#pragma unroll
        for (int t = 0; t < 4; ++t) {
            const u16* krow = &k_s[(t * 16 + qi) * ROWP + gi * 8];
            bf16x8 ka0 = *(const bf16x8*)krow;
            bf16x8 ka1 = *(const bf16x8*)(krow + 32);
            f32x4 z = (f32x4){0.f, 0.f, 0.f, 0.f};
            z = __builtin_amdgcn_mfma_f32_16x16x32_bf16(ka0, qf0, z, 0, 0, 0);
            sc[t] = __builtin_amdgcn_mfma_f32_16x16x32_bf16(ka1, qf1, z, 0, 0, 0);
        }

        float smax = -INFINITY;
#pragma unroll
        for (int t = 0; t < 4; ++t)
            smax = fmaxf(smax, fmaxf(fmaxf(sc[t][0], sc[t][1]), fmaxf(sc[t][2], sc[t][3])));
        smax = fmaxf(smax, __shfl_xor(smax, 16));
        smax = fmaxf(smax, __shfl_xor(smax, 32));
        float mn = fmaxf(m_run, smax);
        float alpha = exp2f((m_run - mn) * CE);
        m_run = mn;
        float nb = mn * CE;
        float psum = 0.f;
#pragma unroll
        for (int t = 0; t < 4; ++t) {
            ushort4 pw;
            float p0 = exp2f(fmaf(sc[t][0], CE, -nb)); psum += p0; pw.x = f2b(p0);
            float p1 = exp2f(fmaf(sc[t][1], CE, -nb)); psum += p1; pw.y = f2b(p1);
            float p2 = exp2f(fmaf(sc[t][2], CE, -nb)); psum += p2; pw.z = f2b(p2);
            float p3 = exp2f(fmaf(sc[t][3], CE, -nb)); psum += p3; pw.w = f2b(p3);
            *(ushort4*)&p_s[w][qi * ROWP + t * 16 + gi * 4] = pw;
        }
        psum += __shfl_xor(psum, 16);
        psum += __shfl_xor(psum, 32);
        l_run = l_run * alpha + psum;

        float a0 = __shfl(alpha, gi * 4 + 0);
        float a1 = __shfl(alpha, gi * 4 + 1);
        float a2 = __shfl(alpha, gi * 4 + 2);
        float a3 = __shfl(alpha, gi * 4 + 3);
#pragma unroll
        for (int d = 0; d < 4; ++d) {
            oc[d][0] *= a0; oc[d][1] *= a1; oc[d][2] *= a2; oc[d][3] *= a3;
        }

        const u16* prow = &p_s[w][qi * ROWP];
        bf16x8 pa0 = *(const bf16x8*)(prow + gi * 8);
        bf16x8 pa1 = *(const bf16x8*)(prow + 32 + gi * 8);
#pragma unroll
        for (int d = 0; d < 4; ++d) {
            const u16* vrow = &vt_s[(d * 16 + qi) * ROWP + gi * 8];
            bf16x8 vb0 = *(const bf16x8*)vrow;
            bf16x8 vb1 = *(const bf16x8*)(vrow + 32);
            oc[d] = __builtin_amdgcn_mfma_f32_16x16x32_bf16(pa0, vb0, oc[d], 0, 0, 0);
            oc[d] = __builtin_amdgcn_mfma_f32_16x16x32_bf16(pa1, vb1, oc[d], 0, 0, 0);
        }
        __syncthreads();
    }

    float* opd = op + (size_t)s * N_NODES * 128;
#pragma unroll
    for (int d = 0; d < 4; ++d) {
        size_t cb = h * 64 + d * 16 + qi;
        opd[(size_t)(row0 + w * 16 + gi * 4 + 0) * 128 + cb] = oc[d][0];
        opd[(size_t)(row0 + w * 16 + gi * 4 + 1) * 128 + cb] = oc[d][1];
        opd[(size_t)(row0 + w * 16 + gi * 4 + 2) * 128 + cb] = oc[d][2];
        opd[(size_t)(row0 + w * 16 + gi * 4 + 3) * 128 + cb] = oc[d][3];
    }
    if (gi == 0) {
        size_t mi = (size_t)s * NHEAD * N_NODES + (size_t)h * N_NODES + row0 + w * 16 + qi;
        mlm[mi] = m_run;
        mll[mi] = l_run;
    }
}

// ---------------------------------------------------------------------------
// MEGA layer tail: combine -> Wo GEMM -> +res -> LN1 -> FF1+sigmoid -> FF2 ->
// +res -> LN2 -> h (global); DO_QKV: next layer's Q/K/V GEMMs from LDS planes.
// 16 rows per block, grid N/16 = 256, 4 waves. All intermediates in LDS.
#define ROWA 136   // u16 plane row pad
#define ROWZ 264   // FF z plane row pad
#define ROWH 132   // fp32 hln row pad
template<int DO_QKV>
__global__ __launch_bounds__(256) void mega_layer(
        const float* __restrict__ op, const float* __restrict__ mlm,
        const float* __restrict__ mll,
        const u16* __restrict__ wp_o, const float* __restrict__ bo,
        float* __restrict__ h,
        const float* __restrict__ g1, const float* __restrict__ b1,
        const u16* __restrict__ wp_1, const float* __restrict__ bf1,
        const u16* __restrict__ wp_2, const float* __restrict__ bf2,
        const float* __restrict__ g2, const float* __restrict__ b2,
        const u16* __restrict__ wp_q, const u16* __restrict__ wp_k,
        const u16* __restrict__ wp_v,
        const float* __restrict__ bq, const float* __restrict__ bk,
        const float* __restrict__ bv,
        u16* __restrict__ qb, u16* __restrict__ kb, u16* __restrict__ vtb) {
    __shared__ __align__(16) u16 zbuf[16 * ROWZ * 2];   // hosts a-planes then z-planes
    __shared__ __align__(16) u16 hp_hi[16 * ROWA];      // h bf16 planes (LN1 out, later LN2 out)
    __shared__ __align__(16) u16 hp_lo[16 * ROWA];
    __shared__ float hln[16 * ROWH];                    // fp32 LN1 output (FF residual)
    __shared__ float ws_s[NSPLIT][32];
    __shared__ float Linv_s[32];
    __shared__ float wsum[4][16], wsq[4][16];
    const float CE = 0.18033688011f;
    const int tid = threadIdx.x, w = tid >> 6, lane = tid & 63;
    const int qi = lane & 15, gi = lane >> 4;
    const int row0 = blockIdx.x * 16;
    u16* a_hi = zbuf;                  // phase A-C alias (8704 B <= zbuf)
    u16* a_lo = zbuf + 16 * ROWA;
    u16* z_hi = zbuf;                  // phase D-E alias
    u16* z_lo = zbuf + 16 * ROWZ;

    // --- phase A: split-K combine weights per (row, head)
    if (tid < 32) {
        int r = tid >> 1, hd = tid & 1;
        size_t mb = (size_t)hd * N_NODES + row0 + r;
        float m[NSPLIT], l[NSPLIT], mx = -INFINITY;
#pragma unroll
        for (int s = 0; s < NSPLIT; ++s) {
            m[s] = mlm[mb + (size_t)s * NHEAD * N_NODES];
            l[s] = mll[mb + (size_t)s * NHEAD * N_NODES];
            mx = fmaxf(mx, m[s]);
        }
        float L = 0.f;
#pragma unroll
        for (int s = 0; s < NSPLIT; ++s) {
            float ws = exp2f((m[s] - mx) * CE);
            ws_s[s][tid] = ws;
            L += ws * l[s];
        }
        Linv_s[tid] = 1.f / L;
    }
    __syncthreads();

    // --- phase B: combine partial O -> LDS a-planes
    for (int e = tid; e < 16 * 128; e += 256) {
        int r = e >> 7, c = e & 127, hd = c >> 6;
        size_t idx = (size_t)(row0 + r) * 128 + c;
        float O = 0.f;
#pragma unroll
        for (int s = 0; s < NSPLIT; ++s)
            O += ws_s[s][r * 2 + hd] * op[(size_t)s * N_NODES * 128 + idx];
        float v = O * Linv_s[r * 2 + hd];
        u16 hi = f2b(v);
        a_hi[r * ROWA + c] = hi;
        a_lo[r * ROWA + c] = f2b(v - b2f_bits(hi));
    }
    __syncthreads();

    // --- phase C: Wo GEMM + bias + residual(global h) + LN1 -> hln + hp planes
    {
        const u16* Wlo = wp_o + (size_t)128 * 128;
        f32x4 acc[2];
        acc[0] = (f32x4){0.f, 0.f, 0.f, 0.f};
        acc[1] = (f32x4){0.f, 0.f, 0.f, 0.f};
        const int col0 = w * 32;
#pragma unroll
        for (int kc = 0; kc < 4; ++kc) {
            const int k0 = kc * 32;
            bf16x8 ah = *(const bf16x8*)&a_hi[qi * ROWA + k0 + gi * 8];
            bf16x8 al = *(const bf16x8*)&a_lo[qi * ROWA + k0 + gi * 8];
#pragma unroll
            for (int c = 0; c < 2; ++c) {
                const size_t wo = ((size_t)(k0 / 8 + gi) * 128 + col0 + c * 16 + qi) * 8;
                bf16x8 wh = *(const bf16x8*)(wp_o + wo);
                bf16x8 wl = *(const bf16x8*)(Wlo + wo);
                acc[c] = __builtin_amdgcn_mfma_f32_16x16x32_bf16(ah, wh, acc[c], 0, 0, 0);
                acc[c] = __builtin_amdgcn_mfma_f32_16x16x32_bf16(al, wh, acc[c], 0, 0, 0);
                acc[c] = __builtin_amdgcn_mfma_f32_16x16x32_bf16(ah, wl, acc[c], 0, 0, 0);
            }
        }
        float y[2][4], rs[4], rq[4];
#pragma unroll
        for (int r = 0; r < 4; ++r) { rs[r] = 0.f; rq[r] = 0.f; }
#pragma unroll
        for (int c = 0; c < 2; ++c) {
            const int col = col0 + c * 16 + qi;
            float bv = bo[col];
#pragma unroll
            for (int r = 0; r < 4; ++r) {
                float v = acc[c][r] + bv + h[(size_t)(row0 + gi * 4 + r) * 128 + col];
                y[c][r] = v;
                rs[r] += v; rq[r] += v * v;
            }
        }
#pragma unroll
        for (int r = 0; r < 4; ++r)
            for (int msk = 1; msk < 16; msk <<= 1) {
                rs[r] += __shfl_xor(rs[r], msk);
                rq[r] += __shfl_xor(rq[r], msk);
            }
        if (qi == 0) {
#pragma unroll
            for (int r = 0; r < 4; ++r) { wsum[w][gi * 4 + r] = rs[r]; wsq[w][gi * 4 + r] = rq[r]; }
        }
        __syncthreads();
#pragma unroll
        for (int r = 0; r < 4; ++r) {
            const int lr = gi * 4 + r;
            float ts = wsum[0][lr] + wsum[1][lr] + wsum[2][lr] + wsum[3][lr];
            float tq = wsq[0][lr] + wsq[1][lr] + wsq[2][lr] + wsq[3][lr];
            float mean = ts * (1.f / 128.f);
            float var  = tq * (1.f / 128.f) - mean * mean;
            float rstd = rsqrtf(var + 1e-5f);
#pragma unroll
            for (int c = 0; c < 2; ++c) {
                const int col = col0 + c * 16 + qi;
                float yn = (y[c][r] - mean) * rstd * g1[col] + b1[col];
                hln[lr * ROWH + col] = yn;
                u16 hi = f2b(yn);
                hp_hi[lr * ROWA + col] = hi;
                hp_lo[lr * ROWA + col] = f2b(yn - b2f_bits(hi));
            }
        }
    }
    __syncthreads();   // hln/hp visible; a-planes dead

    // --- phase D: FF1 (K=128) from hp planes -> sigmoid -> z planes
    {
        const u16* W1lo = wp_1 + (size_t)128 * 256;
        f32x4 acc1[4];
#pragma unroll
        for (int t = 0; t < 4; ++t) acc1[t] = (f32x4){0.f, 0.f, 0.f, 0.f};
#pragma unroll
        for (int kc = 0; kc < 4; ++kc) {
            const int k0 = kc * 32;
            bf16x8 ah = *(const bf16x8*)&hp_hi[qi * ROWA + k0 + gi * 8];
            bf16x8 al = *(const bf16x8*)&hp_lo[qi * ROWA + k0 + gi * 8];
#pragma unroll
            for (int t = 0; t < 4; ++t) {
                const size_t wo = ((size_t)(k0 / 8 + gi) * 256 + w * 64 + t * 16 + qi) * 8;
                bf16x8 wh = *(const bf16x8*)(wp_1 + wo);
                bf16x8 wl = *(const bf16x8*)(W1lo + wo);
                acc1[t] = __builtin_amdgcn_mfma_f32_16x16x32_bf16(ah, wh, acc1[t], 0, 0, 0);
                acc1[t] = __builtin_amdgcn_mfma_f32_16x16x32_bf16(al, wh, acc1[t], 0, 0, 0);
                acc1[t] = __builtin_amdgcn_mfma_f32_16x16x32_bf16(ah, wl, acc1[t], 0, 0, 0);
            }
        }
        __syncthreads();   // all hp/a reads done before z overwrites zbuf
#pragma unroll
        for (int t = 0; t < 4; ++t) {
            const int col = w * 64 + t * 16 + qi;
            float bv = bf1[col];
#pragma unroll
            for (int r = 0; r < 4; ++r) {
                float v = acc1[t][r] + bv;
                v = 1.f / (1.f + __expf(-v));
                u16 hi = f2b(v);
                const int zr = gi * 4 + r;
                z_hi[zr * ROWZ + col] = hi;
                z_lo[zr * ROWZ + col] = f2b(v - b2f_bits(hi));
            }
        }
    }
    __syncthreads();

    // --- phase E: FF2 (K=256) + bias + residual(hln) + LN2 -> global h (+ hp planes)
    {
        const u16* W2lo = wp_2 + (size_t)256 * 128;
        f32x4 acc[2];
        acc[0] = (f32x4){0.f, 0.f, 0.f, 0.f};
        acc[1] = (f32x4){0.f, 0.f, 0.f, 0.f};
        const int col0 = w * 32;
#pragma unroll
        for (int kc = 0; kc < 8; ++kc) {
            const int k0 = kc * 32;
            bf16x8 ah = *(const bf16x8*)&z_hi[qi * ROWZ + k0 + gi * 8];
            bf16x8 al = *(const bf16x8*)&z_lo[qi * ROWZ + k0 + gi * 8];
#pragma unroll
            for (int c = 0; c < 2; ++c) {
                const size_t wo = ((size_t)(k0 / 8 + gi) * 128 + col0 + c * 16 + qi) * 8;
                bf16x8 wh = *(const bf16x8*)(wp_2 + wo);
                bf16x8 wl = *(const bf16x8*)(W2lo + wo);
                acc[c] = __builtin_amdgcn_mfma_f32_16x16x32_bf16(ah, wh, acc[c], 0, 0, 0);
                acc[c] = __builtin_amdgcn_mfma_f32_16x16x32_bf16(al, wh, acc[c], 0, 0, 0);
                acc[c] = __builtin_amdgcn_mfma_f32_16x16x32_bf16(ah, wl, acc[c], 0, 0, 0);
            }
        }
        float y[2][4], rs[4], rq[4];
#pragma unroll
        for (int r = 0; r < 4; ++r) { rs[r] = 0.f; rq[r] = 0.f; }
#pragma unroll
        for (int c = 0; c < 2; ++c) {
            const int col = col0 + c * 16 + qi;
            float bv = bf2[col];
#pragma unroll
            for (int r = 0; r < 4; ++r) {
                float v = acc[c][r] + bv + hln[(gi * 4 + r) * ROWH + col];
                y[c][r] = v;
                rs[r] += v; rq[r] += v * v;
            }
        }
#pragma unroll
        for (int r = 0; r < 4; ++r)
            for (int msk = 1; msk < 16; msk <<= 1) {
                rs[r] += __shfl_xor(rs[r], msk);
                rq[r] += __shfl_xor(rq[r], msk);
            }
        if (qi == 0) {
#pragma unroll
            for (int r = 0; r < 4; ++r) { wsum[w][gi * 4 + r] = rs[r]; wsq[w][gi * 4 + r] = rq[r]; }
        }
        __syncthreads();
#pragma unroll
        for (int r = 0; r < 4; ++r) {
            const int lr = gi * 4 + r;
            float ts = wsum[0][lr] + wsum[1][lr] + wsum[2][lr] + wsum[3][lr];
            float tq = wsq[0][lr] + wsq[1][lr] + wsq[2][lr] + wsq[3][lr];
            float mean = ts * (1.f / 128.f);
            float var  = tq * (1.f / 128.f) - mean * mean;
            float rstd = rsqrtf(var + 1e-5f);
#pragma unroll
            for (int c = 0; c < 2; ++c) {
                const int col = col0 + c * 16 + qi;
                float yn = (y[c][r] - mean) * rstd * g2[col] + b2[col];
                h[(size_t)(row0 + lr) * 128 + col] = yn;
                if (DO_QKV) {
                    u16 hi = f2b(yn);
                    hp_hi[lr * ROWA + col] = hi;      // hp reads finished in phase D
                    hp_lo[lr * ROWA + col] = f2b(yn - b2f_bits(hi));
                }
            }
        }
    }

    // --- phase F: next layer's QKV from hp planes
    if (DO_QKV) {
        __syncthreads();
        const int col0 = w * 32;
#pragma unroll
        for (int sel = 0; sel < 3; ++sel) {
            const u16* Wp = (sel == 0) ? wp_q : (sel == 1) ? wp_k : wp_v;
            const float* bias = (sel == 0) ? bq : (sel == 1) ? bk : bv;
            const u16* Wlo = Wp + (size_t)128 * 128;
            f32x4 acc[2];
            acc[0] = (f32x4){0.f, 0.f, 0.f, 0.f};
            acc[1] = (f32x4){0.f, 0.f, 0.f, 0.f};
#pragma unroll
            for (int kc = 0; kc < 4; ++kc) {
                const int k0 = kc * 32;
                bf16x8 ah = *(const bf16x8*)&hp_hi[qi * ROWA + k0 + gi * 8];
                bf16x8 al = *(const bf16x8*)&hp_lo[qi * ROWA + k0 + gi * 8];
#pragma unroll
                for (int c = 0; c < 2; ++c) {
                    const size_t wo = ((size_t)(k0 / 8 + gi) * 128 + col0 + c * 16 + qi) * 8;
                    bf16x8 wh = *(const bf16x8*)(Wp + wo);
                    bf16x8 wl = *(const bf16x8*)(Wlo + wo);
                    acc[c] = __builtin_amdgcn_mfma_f32_16x16x32_bf16(ah, wh, acc[c], 0, 0, 0);
                    acc[c] = __builtin_amdgcn_mfma_f32_16x16x32_bf16(al, wh, acc[c], 0, 0, 0);
                    acc[c] = __builtin_amdgcn_mfma_f32_16x16x32_bf16(ah, wl, acc[c], 0, 0, 0);
                }
            }
#pragma unroll
            for (int c = 0; c < 2; ++c) {
                const int col = col0 + c * 16 + qi;
                const int hh = col >> 6, d = col & 63;
                float bv_ = bias[col];
                if (sel < 2) {
                    u16* dst = (sel == 0) ? qb : kb;
#pragma unroll
                    for (int r = 0; r < 4; ++r) {
                        const int grow = row0 + gi * 4 + r;
                        dst[((size_t)hh * N_NODES + grow) * 64 + d] = f2b(acc[c][r] + bv_);
                    }
                } else {
                    const int grow0 = row0 + gi * 4;
                    ushort4 pw;
                    pw.x = f2b(acc[c][0] + bv_);
                    pw.y = f2b(acc[c][1] + bv_);
                    pw.z = f2b(acc[c][2] + bv_);
                    pw.w = f2b(acc[c][3] + bv_);
                    *(ushort4*)&vtb[((size_t)hh * 64 + d) * N_NODES + grow0] = pw;
                }
            }
        }
    }
}

// ---------------------------------------------------------------------------
// Hypergraph CSR build + atomic-free gathers.
__global__ void hist_kernel(const int* __restrict__ edge_raw,
                            int* __restrict__ nidx, int* __restrict__ hidx,
                            int* __restrict__ cnt_e, int* __restrict__ cnt_n) {
    __shared__ int is64_s;
    if (threadIdx.x < 64) {
        int v = edge_raw[2 * threadIdx.x + 1];
        unsigned long long bal = __ballot(v != 0);
        if (threadIdx.x == 0) is64_s = (bal == 0ull) ? 1 : 0;
    }
    __syncthreads();
    const int is64 = is64_s;
    int i = blockIdx.x * 256 + threadIdx.x;
    if (i < NNZ_E) {
        int ni = (is64 ? edge_raw[2 * i]             : edge_raw[i])         & (N_NODES - 1);
        int he = (is64 ? edge_raw[2 * NNZ_E + 2 * i] : edge_raw[NNZ_E + i]) & (NEDGE - 1);
        nidx[i] = ni;
        hidx[i] = he;
        atomicAdd(&cnt_n[ni], 1);
        atomicAdd(&cnt_e[he], 1);
    }
}

__global__ __launch_bounds__(1024) void scan_only(const int* __restrict__ cnt_e,
                                                  const int* __restrict__ cnt_n,
                                                  int* __restrict__ off_e,
                                                  int* __restrict__ off_n,
                                                  int* __restrict__ cur_e,
                                                  int* __restrict__ cur_n) {
    __shared__ int s[N_NODES];
    const int he_side = (blockIdx.x == 0);
    const int n = he_side ? NEDGE : N_NODES;
    const int* cnt = he_side ? cnt_e : cnt_n;
    int* off = he_side ? off_e : off_n;
    int* cur = he_side ? cur_e : cur_n;
    for (int i = threadIdx.x; i < n; i += 1024) s[i] = cnt[i];
    __syncthreads();
    for (int st = 1; st < n; st <<= 1) {
        int v[4]; int nj = 0;
        for (int i = threadIdx.x; i < n; i += 1024) v[nj++] = (i >= st) ? s[i - st] : 0;
        __syncthreads();
        nj = 0;
        for (int i = threadIdx.x; i < n; i += 1024) s[i] += v[nj++];
        __syncthreads();
    }
    for (int i = threadIdx.x; i < n; i += 1024) { off[i + 1] = s[i]; cur[i] = 0; }
    if (threadIdx.x == 0) off[0] = 0;
}

__global__ void fill_csr(const int* __restrict__ nidx, const int* __restrict__ hidx,
                         const int* __restrict__ off_e, const int* __restrict__ off_n,
                         int* __restrict__ cur_e, int* __restrict__ cur_n,
                         int* __restrict__ csr_e, int* __restrict__ csr_n) {
    int i = blockIdx.x * 256 + threadIdx.x;
    if (i < NNZ_E) {
        int ni = nidx[i], he = hidx[i];
        int p = atomicAdd(&cur_e[he], 1);
        csr_e[off_e[he] + p] = ni;
        int q = atomicAdd(&cur_n[ni], 1);
        csr_n[off_n[ni] + q] = he;
    }
}

__global__ __launch_bounds__(128) void gather_e(const int* __restrict__ off_e,
                                                const int* __restrict__ csr_e,
                                                const float* __restrict__ h,
                                                u16* __restrict__ ehi,
                                                u16* __restrict__ elo) {
    __shared__ int ms[128];
    const int he = blockIdx.x, d = threadIdx.x;
    const int beg = off_e[he], end = off_e[he + 1];
    float acc = 0.f;
    for (int c = beg; c < end; c += 128) {
        int nl = min(128, end - c);
        if (d < nl) ms[d] = csr_e[c + d];
        __syncthreads();
        for (int j = 0; j < nl; ++j) acc += h[(size_t)ms[j] * 128 + d];
        __syncthreads();
    }
    float binv = (end > beg) ? 1.f / (float)(end - beg) : 0.f;
    float v = acc * binv;
    u16 hi = f2b(v);
    ehi[(size_t)he * 128 + d] = hi;
    elo[(size_t)he * 128 + d] = f2b(v - b2f_bits(hi));
}

__global__ __launch_bounds__(128) void gather_n(const int* __restrict__ off_n,
                                                const int* __restrict__ csr_n,
                                                const float* __restrict__ e_sc,
                                                const float* __restrict__ bh,
                                                float* __restrict__ out) {
    __shared__ int ms[128];
    const int nn = blockIdx.x, d = threadIdx.x;
    const int beg = off_n[nn], end = off_n[nn + 1];
    float acc = 0.f;
    for (int c = beg; c < end; c += 128) {
        int nl = min(128, end - c);
        if (d < nl) ms[d] = csr_n[c + d];
        __syncthreads();
        for (int j = 0; j < nl; ++j) acc += e_sc[(size_t)ms[j] * 128 + d];
        __syncthreads();
    }
    float dinv = (end > beg) ? 1.f / (float)(end - beg) : 0.f;
    float v = acc * dinv + bh[d];
    out[(size_t)nn * 128 + d] = v > 0.f ? v : 0.f;
}

// ---------------------------------------------------------------------------
extern "C" void kernel_launch(void* const* d_in, const int* in_sizes, int n_in,
                              void* d_out, int out_size, void* d_ws, size_t ws_size,
                              hipStream_t stream) {
    (void)in_sizes; (void)n_in; (void)out_size; (void)ws_size;
    const float* x    = (const float*)d_in[0];
    const int*   edge = (const int*)  d_in[1];
    const float* Wq = (const float*)d_in[2];  const float* bq  = (const float*)d_in[3];
    const float* Wk = (const float*)d_in[4];  const float* bk  = (const float*)d_in[5];
    const float* Wv = (const float*)d_in[6];  const float* bv  = (const float*)d_in[7];
    const float* Wo = (const float*)d_in[8];  const float* bo  = (const float*)d_in[9];
    const float* g1 = (const float*)d_in[10]; const float* b1  = (const float*)d_in[11];
    const float* W1 = (const float*)d_in[12]; const float* bf1 = (const float*)d_in[13];
    const float* W2 = (const float*)d_in[14]; const float* bf2 = (const float*)d_in[15];
    const float* g2 = (const float*)d_in[16]; const float* b2  = (const float*)d_in[17];
    const float* Wh = (const float*)d_in[18]; const float* bh  = (const float*)d_in[19];
    float* out = (float*)d_out;

    // ---- workspace layout (fp32-word offsets), all live regions DISJOINT ----
    float* B = (float*)d_ws;
    float* h    = B;                          // [N,128] fp32
    u16*   h_hi = (u16*)(B + 524288);         // [N,128] bf16 (prep -> qkv L1 only)
    u16*   h_lo = (u16*)(B + 786432);
    u16*   qb   = (u16*)(B + 1048576);        // [H][N][64] bf16
    u16*   kb   = (u16*)(B + 1310720);
    u16*   vtb  = (u16*)(B + 1835008);        // [H][64][N] bf16
    float* op   = B + 2097152;                // [NSPLIT][N][128] fp32 -> end 6291456
    float* mlm  = B + 6291456;                // [NSPLIT][H][N]
    float* mll  = B + 6356992;                // -> end 6422528
    u16*   e_hi = (u16*)(B + 6946816);        // [NE,128] bf16
    u16*   e_lo = (u16*)(B + 7077888);
    float* e_sc = B + 7208960;                // [NE,128] fp32 -> end 7471104
    u16*   wp_q = (u16*)(B + 8519680);        // packs: 16384 w each (128x128)
    u16*   wp_k = (u16*)(B + 8536064);
    u16*   wp_v = (u16*)(B + 8552448);
    u16*   wp_o = (u16*)(B + 8568832);
    u16*   wp_h = (u16*)(B + 8585216);
    u16*   wp_1 = (u16*)(B + 8601600);        // 128x256: 32768 w
    u16*   wp_2 = (u16*)(B + 8634368);        // 256x128: 32768 w -> end 8667136
    int*   cur_e = (int*)(B + 9328640);       // [NE]
    int*   cur_n = (int*)(B + 9330688);       // [N]
    int*   off_e = (int*)(B + 9334784);       // [NE+1]
    int*   off_n = (int*)(B + 9336840);       // [N+1]
    int*   csr_e = (int*)(B + 9340944);       // [NNZ]
    int*   csr_n = (int*)(B + 9406480);       // [NNZ] -> end 9472016
    int*   cnt_e = (int*)(B + 9472016);       // [NE]  (cnt_e+cnt_n contiguous)
    int*   cnt_n = (int*)(B + 9474064);       // [N]   -> end 9478160
    int*   nidx  = (int*)(B + 9478160);       // [NNZ]
    int*   hidx  = (int*)(B + 9543696);       // [NNZ] -> end 9609232 (~38.4 MB)

    prep<<<2968, 256, 0, stream>>>(x, h, h_hi, h_lo,
                                   Wq, Wk, Wv, Wo, Wh, W1, W2,
                                   wp_q, wp_k, wp_v, wp_o, wp_h, wp_1, wp_2, cnt_e);

    qkv_mfma<<<dim3(64, 12), 256, 0, stream>>>(h_hi, h_lo, wp_q, wp_k, wp_v,
                                               bq, bk, bv, qb, kb, vtb);
    attn_mfma<<<dim3(N_NODES / 64, NHEAD, NSPLIT), 256, 0, stream>>>(qb, kb, vtb, op, mlm, mll);
    mega_layer<1><<<N_NODES / 16, 256, 0, stream>>>(op, mlm, mll, wp_o, bo, h, g1, b1,
                                                    wp_1, bf1, wp_2, bf2, g2, b2,
                                                    wp_q, wp_k, wp_v, bq, bk, bv,
                                                    qb, kb, vtb);
    attn_mfma<<<dim3(N_NODES / 64, NHEAD, NSPLIT), 256, 0, stream>>>(qb, kb, vtb, op, mlm, mll);
    mega_layer<0><<<N_NODES / 16, 256, 0, stream>>>(op, mlm, mll, wp_o, bo, h, g1, b1,
                                                    wp_1, bf1, wp_2, bf2, g2, b2,
                                                    nullptr, nullptr, nullptr,
                                                    nullptr, nullptr, nullptr,
                                                    nullptr, nullptr, nullptr);

    // hypergraph: histogram -> scan -> CSR fill -> gather_e -> Wh GEMM -> gather_n
    hist_kernel<<<NNZ_E / 256, 256, 0, stream>>>(edge, nidx, hidx, cnt_e, cnt_n);
    scan_only<<<2, 1024, 0, stream>>>(cnt_e, cnt_n, off_e, off_n, cur_e, cur_n);
    fill_csr<<<NNZ_E / 256, 256, 0, stream>>>(nidx, hidx, off_e, off_n, cur_e, cur_n, csr_e, csr_n);
    gather_e<<<NEDGE, 128, 0, stream>>>(off_e, csr_e, h, e_hi, e_lo);
    gemm_mfma<128, 128><<<dim3(NEDGE / 64, 4), 256, 0, stream>>>(e_hi, e_lo, wp_h, e_sc);
    gather_n<<<N_NODES, 128, 0, stream>>>(off_n, csr_n, e_sc, bh, out);
}